// Round 8
// baseline (1337.302 us; speedup 1.0000x reference)
//
#include <hip/hip_runtime.h>
#include <hip/hip_fp16.h>

#define NB 2048
#define NT 60
#define NDL 100
#define ND 512
#define NH 256
#define NG 768

typedef const float* __restrict__ fpp;
typedef _Float16 half8 __attribute__((ext_vector_type(8)));
typedef float floatx4 __attribute__((ext_vector_type(4)));

__device__ __forceinline__ float fast_sig(float x) {
  return 1.f / (1.f + __expf(-x));
}
__device__ __forceinline__ float fast_tanh(float x) {
  float t = __expf(2.f * x);
  return (t - 1.f) / (t + 1.f);
}

// ---------------------------------------------------------------------------
// fp32 tiled GEMM (fc layer only, K=100): C = A*B^T + bias
// ---------------------------------------------------------------------------
__global__ __launch_bounds__(256) void gemm_fc(
    fpp A, fpp Bm, fpp bias, float* __restrict__ C,
    int M, int N, int K, int lda, int ldb, int ldc)
{
  __shared__ float As[16][68];
  __shared__ float Bs[16][68];
  const int bm = blockIdx.x * 64, bn = blockIdx.y * 64;
  const int tid = threadIdx.x;
  const int tx = tid & 15, ty = tid >> 4;
  float acc[4][4] = {};
  for (int k0 = 0; k0 < K; k0 += 16) {
#pragma unroll
    for (int i = 0; i < 4; i++) {
      int e = tid + i * 256;
      int m = e >> 4, k = e & 15;
      As[k][m] = (k0 + k < K) ? A[(size_t)(bm + m) * lda + k0 + k] : 0.f;
      Bs[k][m] = (k0 + k < K) ? Bm[(size_t)(bn + m) * ldb + k0 + k] : 0.f;
    }
    __syncthreads();
#pragma unroll
    for (int kk = 0; kk < 16; kk++) {
      float4 av = *(const float4*)&As[kk][ty * 4];
      float4 bv = *(const float4*)&Bs[kk][tx * 4];
      float a_[4] = {av.x, av.y, av.z, av.w};
      float b_[4] = {bv.x, bv.y, bv.z, bv.w};
#pragma unroll
      for (int i = 0; i < 4; i++)
#pragma unroll
        for (int j = 0; j < 4; j++)
          acc[i][j] = fmaf(a_[i], b_[j], acc[i][j]);
    }
    __syncthreads();
  }
#pragma unroll
  for (int i = 0; i < 4; i++) {
    int m = bm + ty * 4 + i;
#pragma unroll
    for (int j = 0; j < 4; j++) {
      int n = bn + tx * 4 + j;
      C[(size_t)m * ldc + n] = acc[i][j] + bias[n];
    }
  }
}

// ---------------------------------------------------------------------------
// BatchNorm batch statistics -> per-column scale/shift
// ---------------------------------------------------------------------------
__global__ __launch_bounds__(256) void bn_stats(
    const float* __restrict__ h0, fpp g, fpp b,
    float* __restrict__ scale, float* __restrict__ shift)
{
  const int cl = threadIdx.x & 31;
  const int col = blockIdx.x * 32 + cl;
  const int row0 = threadIdx.x >> 5;
  float s1 = 0.f, s2 = 0.f;
  for (int r = row0; r < NB; r += 8) {
    float v = h0[(size_t)r * ND + col];
    s1 += v; s2 += v * v;
  }
  __shared__ float l1[8][33], l2[8][33];
  l1[row0][cl] = s1;
  l2[row0][cl] = s2;
  __syncthreads();
  if (row0 == 0) {
#pragma unroll
    for (int r = 1; r < 8; r++) { s1 += l1[r][cl]; s2 += l2[r][cl]; }
    float mu = s1 / NB;
    float var = s2 / NB - mu * mu;
    float sc = g[col] * rsqrtf(var + 1e-5f);
    scale[col] = sc;
    shift[col] = b[col] - mu * sc;
  }
}

__global__ void bn_lrelu_h16(const float* __restrict__ h0,
                             const float* __restrict__ scale,
                             const float* __restrict__ shift,
                             __half* __restrict__ h16g)
{
  int idx = blockIdx.x * 256 + threadIdx.x;
  int d = idx & (ND - 1);
  float v = h0[idx] * scale[d] + shift[d];
  h16g[idx] = __float2half(v >= 0.f ? v : 0.2f * v);
}

// ---------------------------------------------------------------------------
// One-time weight conversions fp32 -> fp16
// ---------------------------------------------------------------------------
__global__ void convert_w(fpp whf, fpp whb, fpp w1, fpp wif, fpp wib,
                          __half* __restrict__ o_whf, __half* __restrict__ o_whb,
                          __half* __restrict__ o_w1, __half* __restrict__ o_wif,
                          __half* __restrict__ o_wib)
{
  int idx = blockIdx.x * 256 + threadIdx.x;  // 0 .. 1310719
  if (idx < 196608) o_whf[idx] = __float2half(whf[idx]);
  else if (idx < 393216) o_whb[idx - 196608] = __float2half(whb[idx - 196608]);
  else if (idx < 524288) o_w1[idx - 393216] = __float2half(w1[idx - 393216]);
  else if (idx < 917504) o_wif[idx - 524288] = __float2half(wif[idx - 524288]);
  else o_wib[idx - 917504] = __float2half(wib[idx - 917504]);
}

// ---------------------------------------------------------------------------
// fp16 MFMA GEMM (xg projections): C[m][n] = A[m][:]·B[n][:] + bias[n]
// ---------------------------------------------------------------------------
__global__ __launch_bounds__(256) void gemm16(
    const __half* __restrict__ A, const __half* __restrict__ Bm,
    fpp bias, float* __restrict__ C, int N, int K)
{
  __shared__ __half As[64 * 40];
  __shared__ __half Bs[64 * 40];
  const int bm = blockIdx.x * 64, bn = blockIdx.y * 64;
  const int tid = threadIdx.x;
  const int wave = tid >> 6, lane = tid & 63;
  const int lm = lane & 15, quad = lane >> 4;
  floatx4 acc[4];
#pragma unroll
  for (int nt = 0; nt < 4; nt++) acc[nt] = (floatx4){0.f, 0.f, 0.f, 0.f};

  const int row = tid >> 2, kc = tid & 3;
  for (int k0 = 0; k0 < K; k0 += 32) {
    __syncthreads();
    *(float4*)&As[row * 40 + kc * 8] =
      *(const float4*)&A[(size_t)(bm + row) * K + k0 + kc * 8];
    *(float4*)&Bs[row * 40 + kc * 8] =
      *(const float4*)&Bm[(size_t)(bn + row) * K + k0 + kc * 8];
    __syncthreads();
    half8 af = *(const half8*)&As[(wave * 16 + lm) * 40 + quad * 8];
#pragma unroll
    for (int nt = 0; nt < 4; nt++) {
      half8 bf = *(const half8*)&Bs[(nt * 16 + lm) * 40 + quad * 8];
      acc[nt] = __builtin_amdgcn_mfma_f32_16x16x32_f16(af, bf, acc[nt], 0, 0, 0);
    }
  }
#pragma unroll
  for (int nt = 0; nt < 4; nt++) {
    int n = bn + nt * 16 + lm;
    float bv = bias[n];
#pragma unroll
    for (int r = 0; r < 4; r++) {
      int m = bm + wave * 16 + quad * 4 + r;
      C[(size_t)m * N + n] = acc[nt][r] + bv;
    }
  }
}

// ---------------------------------------------------------------------------
// PERSISTENT GRU with explicit register double-buffering of B (Whh) frags.
// Block = 32 batch rows x one direction (grid 128). h-state in registers +
// fp16 LDS copy for next step's MFMA A-frags. B prefetched k-block ahead;
// last k-block prefetches next step's k0=0 (latency hidden by epilogue).
// ---------------------------------------------------------------------------
__global__ __launch_bounds__(256, 1) void gru_persistent(
    const float* __restrict__ xg_f, const float* __restrict__ xg_b,
    const __half* __restrict__ whh16_f, const __half* __restrict__ whh16_b,
    fpp bhh_f, fpp bhh_b, __half* __restrict__ seq)
{
  const int dir = blockIdx.x >> 6;
  const int tile = blockIdx.x & 63;
  const int bm = tile * 32;
  const float* __restrict__ xg = dir ? xg_b : xg_f;
  const __half* __restrict__ Whh = dir ? whh16_b : whh16_f;
  fpp bhh = dir ? bhh_b : bhh_f;
  const int dcol = dir * NH;
  const int tid = threadIdx.x;
  const int wave = tid >> 6, lane = tid & 63;
  const int lm = lane & 15, quad = lane >> 4;

  __shared__ __half h16[32 * 264];

  // step-invariant B fragment pointers
  const __half* bp[3][4];
#pragma unroll
  for (int g = 0; g < 3; g++)
#pragma unroll
    for (int c = 0; c < 4; c++)
      bp[g][c] = Whh + (size_t)(g * NH + (wave * 4 + c) * 16 + lm) * NH + quad * 8;

  // preload xg + biases for this thread's fixed (m,n) positions
  float xr_[4][2][4], xz_[4][2][4], xn_[4][2][4];
  float br_[4], bz_[4], bn_[4];
#pragma unroll
  for (int c = 0; c < 4; c++) {
    int n = (wave * 4 + c) * 16 + lm;
    br_[c] = bhh[n]; bz_[c] = bhh[NH + n]; bn_[c] = bhh[2 * NH + n];
#pragma unroll
    for (int mt = 0; mt < 2; mt++)
#pragma unroll
      for (int r = 0; r < 4; r++) {
        int m = bm + mt * 16 + quad * 4 + r;
        const float* xp = xg + (size_t)m * NG + n;
        xr_[c][mt][r] = xp[0];
        xz_[c][mt][r] = xp[NH];
        xn_[c][mt][r] = xp[2 * NH];
      }
  }

  float hp[4][2][4];
#pragma unroll
  for (int c = 0; c < 4; c++)
#pragma unroll
    for (int mt = 0; mt < 2; mt++)
#pragma unroll
      for (int r = 0; r < 4; r++) hp[c][mt][r] = 0.f;

  // prime B double-buffer with k0 = 0
  half8 bcur[3][4];
#pragma unroll
  for (int g = 0; g < 3; g++)
#pragma unroll
    for (int c = 0; c < 4; c++)
      bcur[g][c] = *(const half8*)(bp[g][c]);

  const int arow0 = lm * 264 + quad * 8;
  const int hbase = (quad * 4) * 264 + wave * 64 + lm;

  for (int step = 0; step < NT; step++) {
    const int t_out = dir ? (NT - 1 - step) : step;
    floatx4 acc[3][4][2];
#pragma unroll
    for (int g = 0; g < 3; g++)
#pragma unroll
      for (int c = 0; c < 4; c++)
#pragma unroll
        for (int mt = 0; mt < 2; mt++)
          acc[g][c][mt] = (floatx4){0.f, 0.f, 0.f, 0.f};

    if (step > 0) {
#pragma unroll
      for (int kb = 0; kb < 8; kb++) {
        const int k0 = kb * 32;
        const int kn = (kb == 7) ? 0 : k0 + 32;   // last block prefetches next step's k0=0
        half8 bnx[3][4];
#pragma unroll
        for (int g = 0; g < 3; g++)
#pragma unroll
          for (int c = 0; c < 4; c++)
            bnx[g][c] = *(const half8*)(bp[g][c] + kn);
        half8 a0 = *(const half8*)&h16[arow0 + k0];
        half8 a1 = *(const half8*)&h16[arow0 + 16 * 264 + k0];
#pragma unroll
        for (int g = 0; g < 3; g++)
#pragma unroll
          for (int c = 0; c < 4; c++) {
            acc[g][c][0] = __builtin_amdgcn_mfma_f32_16x16x32_f16(a0, bcur[g][c], acc[g][c][0], 0, 0, 0);
            acc[g][c][1] = __builtin_amdgcn_mfma_f32_16x16x32_f16(a1, bcur[g][c], acc[g][c][1], 0, 0, 0);
          }
#pragma unroll
        for (int g = 0; g < 3; g++)
#pragma unroll
          for (int c = 0; c < 4; c++)
            bcur[g][c] = bnx[g][c];
      }
      __syncthreads();  // all h16 reads done before overwrite
    }

    size_t sbase = ((size_t)(bm + quad * 4) * NT + t_out) * ND + dcol + wave * 64 + lm;
#pragma unroll
    for (int c = 0; c < 4; c++)
#pragma unroll
      for (int mt = 0; mt < 2; mt++)
#pragma unroll
        for (int r = 0; r < 4; r++) {
          float rg = fast_sig(xr_[c][mt][r] + acc[0][c][mt][r] + br_[c]);
          float zg = fast_sig(xz_[c][mt][r] + acc[1][c][mt][r] + bz_[c]);
          float nn = fast_tanh(xn_[c][mt][r] + rg * (acc[2][c][mt][r] + bn_[c]));
          float hv = (1.f - zg) * nn + zg * hp[c][mt][r];
          hp[c][mt][r] = hv;
          __half hh = __float2half(hv);
          h16[hbase + c * 16 + (mt * 16 + r) * 264] = hh;
          seq[sbase + c * 16 + (size_t)(mt * 16 + r) * (NT * ND)] = hh;
        }
    __syncthreads();  // h16 complete before next step's reads
  }
}

// ---------------------------------------------------------------------------
// Attention scores via MFMA, M=128 rows/block, single pass, no atomics.
// ---------------------------------------------------------------------------
__global__ __launch_bounds__(256) void attn_score_mfma(
    const __half* __restrict__ seq, const __half* __restrict__ w116,
    fpp b1, fpp W2, float* __restrict__ scores)
{
  const int bm = blockIdx.x * 128;
  const int tid = threadIdx.x;
  const int wave = tid >> 6, lane = tid & 63;
  const int lm = lane & 15, quad = lane >> 4;

  __shared__ __half As[128 * 40];
  __shared__ __half Bs[256 * 40];

  floatx4 acc[2][16];
#pragma unroll
  for (int mt = 0; mt < 2; mt++)
#pragma unroll
    for (int nt = 0; nt < 16; nt++) acc[mt][nt] = (floatx4){0.f, 0.f, 0.f, 0.f};

  for (int k0 = 0; k0 < ND; k0 += 32) {
    __syncthreads();
#pragma unroll
    for (int i = 0; i < 2; i++) {
      int e = tid + i * 256;
      int row = e >> 2, kc = e & 3;
      *(float4*)&As[row * 40 + kc * 8] =
        *(const float4*)&seq[(size_t)(bm + row) * ND + k0 + kc * 8];
    }
#pragma unroll
    for (int i = 0; i < 4; i++) {
      int e = tid + i * 256;
      int row = e >> 2, kc = e & 3;
      *(float4*)&Bs[row * 40 + kc * 8] =
        *(const float4*)&w116[(size_t)row * ND + k0 + kc * 8];
    }
    __syncthreads();
    half8 a0 = *(const half8*)&As[((wave * 2 + 0) * 16 + lm) * 40 + quad * 8];
    half8 a1 = *(const half8*)&As[((wave * 2 + 1) * 16 + lm) * 40 + quad * 8];
#pragma unroll
    for (int nt = 0; nt < 16; nt++) {
      half8 bf = *(const half8*)&Bs[(nt * 16 + lm) * 40 + quad * 8];
      acc[0][nt] = __builtin_amdgcn_mfma_f32_16x16x32_f16(a0, bf, acc[0][nt], 0, 0, 0);
      acc[1][nt] = __builtin_amdgcn_mfma_f32_16x16x32_f16(a1, bf, acc[1][nt], 0, 0, 0);
    }
  }

  float rs[2][4] = {};
#pragma unroll
  for (int nt = 0; nt < 16; nt++) {
    int n = nt * 16 + lm;
    float b1v = b1[n], w2v = W2[n];
#pragma unroll
    for (int mt = 0; mt < 2; mt++)
#pragma unroll
      for (int r = 0; r < 4; r++)
        rs[mt][r] += fast_tanh(acc[mt][nt][r] + b1v) * w2v;
  }
#pragma unroll
  for (int mt = 0; mt < 2; mt++)
#pragma unroll
    for (int r = 0; r < 4; r++) {
      rs[mt][r] += __shfl_xor(rs[mt][r], 1);
      rs[mt][r] += __shfl_xor(rs[mt][r], 2);
      rs[mt][r] += __shfl_xor(rs[mt][r], 4);
      rs[mt][r] += __shfl_xor(rs[mt][r], 8);
    }
  if (lm == 0) {
#pragma unroll
    for (int mt = 0; mt < 2; mt++)
#pragma unroll
      for (int r = 0; r < 4; r++)
        scores[bm + (wave * 2 + mt) * 16 + quad * 4 + r] = rs[mt][r];
  }
}

__global__ void softmax_t(float* __restrict__ s)
{
  int b = blockIdx.x, lane = threadIdx.x;
  float v = (lane < NT) ? s[(size_t)b * NT + lane] : -1e30f;
  float m = v;
#pragma unroll
  for (int off = 32; off >= 1; off >>= 1) m = fmaxf(m, __shfl_xor(m, off));
  float e = (lane < NT) ? __expf(v - m) : 0.f;
  float sum = e;
#pragma unroll
  for (int off = 32; off >= 1; off >>= 1) sum += __shfl_xor(sum, off);
  if (lane < NT) s[(size_t)b * NT + lane] = e / sum;
}

__global__ void context_c(const __half* __restrict__ seq,
                          const float* __restrict__ w, float* __restrict__ c)
{
  int idx = blockIdx.x * 256 + threadIdx.x;  // NB*64 groups of 8 cols
  int b = idx >> 6, d8 = (idx & 63) * 8;
  float s[8] = {};
  for (int t = 0; t < NT; t++) {
    float wt = w[(size_t)b * NT + t];
    half8 v = *(const half8*)&seq[((size_t)b * NT + t) * ND + d8];
#pragma unroll
    for (int i = 0; i < 8; i++) s[i] += wt * (float)v[i];
  }
  float* cp = c + (size_t)b * ND + d8;
#pragma unroll
  for (int i = 0; i < 8; i++) cp[i] = s[i];
}

// ---------------------------------------------------------------------------
// Fused joints projection + forward kinematics. One wave handles 4 (b,t).
// ---------------------------------------------------------------------------
__constant__ float c_lower[6] = {-3.1416f, -1.5708f, -3.1416f, -2.6f, -1.5708f, -1.2f};
__constant__ float c_upper[6] = { 3.1416f,  1.5708f,  3.1416f,  0.1f,  1.5708f,  1.2f};

__global__ __launch_bounds__(256) void joints_fk(
    const __half* __restrict__ seq, const float* __restrict__ c,
    fpp jW, fpp jb, float* __restrict__ out)
{
  __shared__ float w[6 * ND];
  const int tid = threadIdx.x;
#pragma unroll
  for (int i = 0; i < 12; i++) w[tid + i * 256] = jW[tid + i * 256];
  __syncthreads();

  const int wave = tid >> 6, lane = tid & 63;
  const int d0 = lane * 8;

  for (int it = 0; it < 4; it++) {
    const int bt = blockIdx.x * 16 + wave * 4 + it;
    const int b = bt / NT;

    half8 hv = *(const half8*)&seq[(size_t)bt * ND + d0];
    float xv[8];
#pragma unroll
    for (int i = 0; i < 8; i++)
      xv[i] = (float)hv[i] + c[(size_t)b * ND + d0 + i];

    float jnt[6];
#pragma unroll
    for (int j = 0; j < 6; j++) {
      float p = 0.f;
#pragma unroll
      for (int i = 0; i < 8; i++) p = fmaf(xv[i], w[j * ND + d0 + i], p);
#pragma unroll
      for (int off = 32; off >= 1; off >>= 1) p += __shfl_xor(p, off);
      jnt[j] = p + jb[j];
    }

    float th[6];
#pragma unroll
    for (int j = 0; j < 6; j++)
      th[j] = jnt[j] * (c_upper[j] - c_lower[j]) + c_lower[j];

    float c0x = 1.f, c0y = 0.f, c0z = 0.f;
    float c1x = 0.f, c1y = 1.f, c1z = 0.f;
    float c2x = 0.f, c2y = 0.f, c2z = 1.f;
    float px = 0.f, py = 0.f, pz = 0.1f;
    float s, cc, tx_, ty_, tz_, ux_, uy_, uz_;

    // rotZ(th0)
    s = sinf(th[0]); cc = cosf(th[0]);
    tx_ = cc * c0x + s * c1x; ty_ = cc * c0y + s * c1y; tz_ = cc * c0z + s * c1z;
    ux_ = -s * c0x + cc * c1x; uy_ = -s * c0y + cc * c1y; uz_ = -s * c0z + cc * c1z;
    c0x = tx_; c0y = ty_; c0z = tz_; c1x = ux_; c1y = uy_; c1z = uz_;

    float shx = px, shy = py, shz = pz;  // shoulder2
    // rotX(th1)
    s = sinf(th[1]); cc = cosf(th[1]);
    tx_ = cc * c1x + s * c2x; ty_ = cc * c1y + s * c2y; tz_ = cc * c1z + s * c2z;
    ux_ = -s * c1x + cc * c2x; uy_ = -s * c1y + cc * c2y; uz_ = -s * c1z + cc * c2z;
    c1x = tx_; c1y = ty_; c1z = tz_; c2x = ux_; c2y = uy_; c2z = uz_;

    // rotY(th2)
    s = sinf(th[2]); cc = cosf(th[2]);
    tx_ = cc * c0x - s * c2x; ty_ = cc * c0y - s * c2y; tz_ = cc * c0z - s * c2z;
    ux_ = s * c0x + cc * c2x; uy_ = s * c0y + cc * c2y; uz_ = s * c0z + cc * c2z;
    c0x = tx_; c0y = ty_; c0z = tz_; c2x = ux_; c2y = uy_; c2z = uz_;

    // joint3 offset -> forearm
    px -= 0.25f * c1x; py -= 0.25f * c1y; pz -= 0.25f * c1z;
    float fox = px, foy = py, foz = pz;
    // rotX(th3)
    s = sinf(th[3]); cc = cosf(th[3]);
    tx_ = cc * c1x + s * c2x; ty_ = cc * c1y + s * c2y; tz_ = cc * c1z + s * c2z;
    ux_ = -s * c1x + cc * c2x; uy_ = -s * c1y + cc * c2y; uz_ = -s * c1z + cc * c2z;
    c1x = tx_; c1y = ty_; c1z = tz_; c2x = ux_; c2y = uy_; c2z = uz_;

    // rotY(th4)
    s = sinf(th[4]); cc = cosf(th[4]);
    tx_ = cc * c0x - s * c2x; ty_ = cc * c0y - s * c2y; tz_ = cc * c0z - s * c2z;
    ux_ = s * c0x + cc * c2x; uy_ = s * c0y + cc * c2y; uz_ = s * c0z + cc * c2z;
    c0x = tx_; c0y = ty_; c0z = tz_; c2x = ux_; c2y = uy_; c2z = uz_;

    // joint5 offset -> wrist
    px -= 0.25f * c1x; py -= 0.25f * c1y; pz -= 0.25f * c1z;
    float wx = px, wy = py, wz = pz;
    // rotX(th5)
    s = sinf(th[5]); cc = cosf(th[5]);
    tx_ = cc * c1x + s * c2x; ty_ = cc * c1y + s * c2y; tz_ = cc * c1z + s * c2z;
    ux_ = -s * c1x + cc * c2x; uy_ = -s * c1y + cc * c2y; uz_ = -s * c1z + cc * c2z;
    c1x = tx_; c1y = ty_; c1z = tz_; c2x = ux_; c2y = uy_; c2z = uz_;

    float f1x = wx - 0.08f * c1x + 0.02f * c2x;
    float f1y = wy - 0.08f * c1y + 0.02f * c2y;
    float f1z = wz - 0.08f * c1z + 0.02f * c2z;
    float f4x = wx - 0.08f * c1x - 0.02f * c2x;
    float f4y = wy - 0.08f * c1y - 0.02f * c2y;
    float f4z = wz - 0.08f * c1z - 0.02f * c2z;

    float dsx = shx - fox, dsy = shy - foy, dsz = shz - foz;
    float dwx = wx - fox, dwy = wy - foy, dwz = wz - foz;
    float bodyL = 0.5f * (sqrtf(dsx * dsx + dsy * dsy + dsz * dsz) +
                          sqrtf(dwx * dwx + dwy * dwy + dwz * dwz));
    float inv = 1.f / bodyL;

    float rel[9];
    rel[0] = (wx - shx) * inv; rel[1] = (wy - shy) * inv; rel[2] = (wz - shz) * inv;
    rel[3] = (f1x - shx) * inv; rel[4] = (f1y - shy) * inv; rel[5] = (f1z - shz) * inv;
    rel[6] = (f4x - shx) * inv; rel[7] = (f4y - shy) * inv; rel[8] = (f4z - shz) * inv;

    if (lane < 9) out[(size_t)bt * 9 + lane] = rel[lane];
  }
}

// ---------------------------------------------------------------------------
extern "C" void kernel_launch(void* const* d_in, const int* in_sizes, int n_in,
                              void* d_out, int out_size, void* d_ws, size_t ws_size,
                              hipStream_t stream)
{
  fpp z     = (fpp)d_in[0];
  fpp W_fc  = (fpp)d_in[1];
  fpp b_fc  = (fpp)d_in[2];
  fpp bn_g  = (fpp)d_in[3];
  fpp bn_b  = (fpp)d_in[4];
  fpp Wih_f = (fpp)d_in[5];
  fpp Whh_f = (fpp)d_in[6];
  fpp bih_f = (fpp)d_in[7];
  fpp bhh_f = (fpp)d_in[8];
  fpp Wih_b = (fpp)d_in[9];
  fpp Whh_b = (fpp)d_in[10];
  fpp bih_b = (fpp)d_in[11];
  fpp bhh_b = (fpp)d_in[12];
  fpp aW1   = (fpp)d_in[13];
  fpp ab1   = (fpp)d_in[14];
  fpp aW2   = (fpp)d_in[15];
  fpp jW    = (fpp)d_in[16];
  fpp jb    = (fpp)d_in[17];

  float* ws     = (float*)d_ws;
  float* h0     = ws;                        // 2048*512 fp32
  float* xg_f   = h0 + 1048576;              // 2048*768 fp32
  float* xg_b   = xg_f + 1572864;            // 2048*768 fp32
  float* scale  = xg_b + 1572864;            // 512
  float* shift  = scale + 512;               // 512
  float* scores = shift + 512;               // 2048*60
  float* cbuf   = scores + 122880;           // 2048*512
  __half* gseq    = (__half*)(cbuf + 1048576);   // 2048*60*512 fp16 (126 MB)
  __half* whh16_f = gseq + 62914560;             // 768*256
  __half* whh16_b = whh16_f + 196608;            // 768*256
  __half* w116    = whh16_b + 196608;            // 256*512
  __half* wih16_f = w116 + 131072;               // 768*512
  __half* wih16_b = wih16_f + 393216;            // 768*512
  __half* h16g    = wih16_b + 393216;            // 2048*512

  // 0. weight conversions fp32->fp16
  convert_w<<<5120, 256, 0, stream>>>(Whh_f, Whh_b, aW1, Wih_f, Wih_b,
                                      whh16_f, whh16_b, w116, wih16_f, wih16_b);
  // 1. fc: h0 = z @ W_fc^T + b_fc (fp32, K=100)
  gemm_fc<<<dim3(32, 8), 256, 0, stream>>>(z, W_fc, b_fc, h0,
                                           NB, ND, NDL, NDL, NDL, ND);
  // 2. batchnorm (training stats) + leaky relu -> fp16 h
  bn_stats<<<16, 256, 0, stream>>>(h0, bn_g, bn_b, scale, shift);
  bn_lrelu_h16<<<4096, 256, 0, stream>>>(h0, scale, shift, h16g);
  // 3. time-invariant input projections via MFMA (computed ONCE)
  gemm16<<<dim3(32, 12), 256, 0, stream>>>(h16g, wih16_f, bih_f, xg_f, NG, ND);
  gemm16<<<dim3(32, 12), 256, 0, stream>>>(h16g, wih16_b, bih_b, xg_b, NG, ND);
  // 4. ENTIRE GRU recurrence: one persistent launch, both directions
  gru_persistent<<<128, 256, 0, stream>>>(xg_f, xg_b, whh16_f, whh16_b,
                                          bhh_f, bhh_b, gseq);
  // 5. attention
  attn_score_mfma<<<960, 256, 0, stream>>>(gseq, w116, ab1, aW2, scores);
  softmax_t<<<NB, 64, 0, stream>>>(scores);
  context_c<<<512, 256, 0, stream>>>(gseq, scores, cbuf);
  // 6. joints projection + forward kinematics, fused
  joints_fk<<<7680, 256, 0, stream>>>(gseq, cbuf, jW, jb, (float*)d_out);
}

// Round 10
// 792.912 us; speedup vs baseline: 1.6866x; 1.6866x over previous
//
#include <hip/hip_runtime.h>
#include <hip/hip_fp16.h>

#define NB 2048
#define NT 60
#define NDL 100
#define ND 512
#define NH 256
#define NG 768

typedef const float* __restrict__ fpp;
typedef _Float16 half8 __attribute__((ext_vector_type(8)));
typedef float floatx4 __attribute__((ext_vector_type(4)));

__device__ __forceinline__ float fast_sig(float x) {
  return 1.f / (1.f + __expf(-x));
}
__device__ __forceinline__ float fast_tanh(float x) {
  float t = __expf(2.f * x);
  return (t - 1.f) / (t + 1.f);
}

// ---------------------------------------------------------------------------
// fp32 tiled GEMM (fc layer only, K=100): C = A*B^T + bias
// ---------------------------------------------------------------------------
__global__ __launch_bounds__(256) void gemm_fc(
    fpp A, fpp Bm, fpp bias, float* __restrict__ C,
    int M, int N, int K, int lda, int ldb, int ldc)
{
  __shared__ float As[16][68];
  __shared__ float Bs[16][68];
  const int bm = blockIdx.x * 64, bn = blockIdx.y * 64;
  const int tid = threadIdx.x;
  const int tx = tid & 15, ty = tid >> 4;
  float acc[4][4] = {};
  for (int k0 = 0; k0 < K; k0 += 16) {
#pragma unroll
    for (int i = 0; i < 4; i++) {
      int e = tid + i * 256;
      int m = e >> 4, k = e & 15;
      As[k][m] = (k0 + k < K) ? A[(size_t)(bm + m) * lda + k0 + k] : 0.f;
      Bs[k][m] = (k0 + k < K) ? Bm[(size_t)(bn + m) * ldb + k0 + k] : 0.f;
    }
    __syncthreads();
#pragma unroll
    for (int kk = 0; kk < 16; kk++) {
      float4 av = *(const float4*)&As[kk][ty * 4];
      float4 bv = *(const float4*)&Bs[kk][tx * 4];
      float a_[4] = {av.x, av.y, av.z, av.w};
      float b_[4] = {bv.x, bv.y, bv.z, bv.w};
#pragma unroll
      for (int i = 0; i < 4; i++)
#pragma unroll
        for (int j = 0; j < 4; j++)
          acc[i][j] = fmaf(a_[i], b_[j], acc[i][j]);
    }
    __syncthreads();
  }
#pragma unroll
  for (int i = 0; i < 4; i++) {
    int m = bm + ty * 4 + i;
#pragma unroll
    for (int j = 0; j < 4; j++) {
      int n = bn + tx * 4 + j;
      C[(size_t)m * ldc + n] = acc[i][j] + bias[n];
    }
  }
}

// ---------------------------------------------------------------------------
// BatchNorm batch statistics -> per-column scale/shift
// ---------------------------------------------------------------------------
__global__ __launch_bounds__(256) void bn_stats(
    const float* __restrict__ h0, fpp g, fpp b,
    float* __restrict__ scale, float* __restrict__ shift)
{
  const int cl = threadIdx.x & 31;
  const int col = blockIdx.x * 32 + cl;
  const int row0 = threadIdx.x >> 5;
  float s1 = 0.f, s2 = 0.f;
  for (int r = row0; r < NB; r += 8) {
    float v = h0[(size_t)r * ND + col];
    s1 += v; s2 += v * v;
  }
  __shared__ float l1[8][33], l2[8][33];
  l1[row0][cl] = s1;
  l2[row0][cl] = s2;
  __syncthreads();
  if (row0 == 0) {
#pragma unroll
    for (int r = 1; r < 8; r++) { s1 += l1[r][cl]; s2 += l2[r][cl]; }
    float mu = s1 / NB;
    float var = s2 / NB - mu * mu;
    float sc = g[col] * rsqrtf(var + 1e-5f);
    scale[col] = sc;
    shift[col] = b[col] - mu * sc;
  }
}

__global__ void bn_lrelu_h16(const float* __restrict__ h0,
                             const float* __restrict__ scale,
                             const float* __restrict__ shift,
                             __half* __restrict__ h16g)
{
  int idx = blockIdx.x * 256 + threadIdx.x;
  int d = idx & (ND - 1);
  float v = h0[idx] * scale[d] + shift[d];
  h16g[idx] = __float2half(v >= 0.f ? v : 0.2f * v);
}

// ---------------------------------------------------------------------------
// One-time weight conversions fp32 -> fp16
// ---------------------------------------------------------------------------
__global__ void convert_w(fpp whf, fpp whb, fpp w1, fpp wif, fpp wib,
                          __half* __restrict__ o_whf, __half* __restrict__ o_whb,
                          __half* __restrict__ o_w1, __half* __restrict__ o_wif,
                          __half* __restrict__ o_wib)
{
  int idx = blockIdx.x * 256 + threadIdx.x;  // 0 .. 1310719
  if (idx < 196608) o_whf[idx] = __float2half(whf[idx]);
  else if (idx < 393216) o_whb[idx - 196608] = __float2half(whb[idx - 196608]);
  else if (idx < 524288) o_w1[idx - 393216] = __float2half(w1[idx - 393216]);
  else if (idx < 917504) o_wif[idx - 524288] = __float2half(wif[idx - 524288]);
  else o_wib[idx - 917504] = __float2half(wib[idx - 917504]);
}

// ---------------------------------------------------------------------------
// fp16 MFMA GEMM (xg projections): C[m][n] = A[m][:]·B[n][:] + bias[n]
// ---------------------------------------------------------------------------
__global__ __launch_bounds__(256) void gemm16(
    const __half* __restrict__ A, const __half* __restrict__ Bm,
    fpp bias, float* __restrict__ C, int N, int K)
{
  __shared__ __half As[64 * 40];
  __shared__ __half Bs[64 * 40];
  const int bm = blockIdx.x * 64, bn = blockIdx.y * 64;
  const int tid = threadIdx.x;
  const int wave = tid >> 6, lane = tid & 63;
  const int lm = lane & 15, quad = lane >> 4;
  floatx4 acc[4];
#pragma unroll
  for (int nt = 0; nt < 4; nt++) acc[nt] = (floatx4){0.f, 0.f, 0.f, 0.f};

  const int row = tid >> 2, kc = tid & 3;
  for (int k0 = 0; k0 < K; k0 += 32) {
    __syncthreads();
    *(float4*)&As[row * 40 + kc * 8] =
      *(const float4*)&A[(size_t)(bm + row) * K + k0 + kc * 8];
    *(float4*)&Bs[row * 40 + kc * 8] =
      *(const float4*)&Bm[(size_t)(bn + row) * K + k0 + kc * 8];
    __syncthreads();
    half8 af = *(const half8*)&As[(wave * 16 + lm) * 40 + quad * 8];
#pragma unroll
    for (int nt = 0; nt < 4; nt++) {
      half8 bf = *(const half8*)&Bs[(nt * 16 + lm) * 40 + quad * 8];
      acc[nt] = __builtin_amdgcn_mfma_f32_16x16x32_f16(af, bf, acc[nt], 0, 0, 0);
    }
  }
#pragma unroll
  for (int nt = 0; nt < 4; nt++) {
    int n = bn + nt * 16 + lm;
    float bv = bias[n];
#pragma unroll
    for (int r = 0; r < 4; r++) {
      int m = bm + wave * 16 + quad * 4 + r;
      C[(size_t)m * N + n] = acc[nt][r] + bv;
    }
  }
}

// ---------------------------------------------------------------------------
// PERSISTENT GRU, register-resident weights.
// Grid 256 = 128 row-tiles x 2 dirs. Block 256 thr = 4 waves @ 1 wave/SIMD
// (512-VGPR budget). Each wave owns a 64-col n-slice for ALL 3 gates:
//   B frags kb 0..6 live in 336 VGPRs (loaded once); kb7 streamed from L2.
// xg (time-invariant) staged once in LDS; h-state fp16 in LDS (stride 264)
// + fp32 hp in regs; seq written via cooperative LDS->global float4 copy.
// ---------------------------------------------------------------------------
__global__ __launch_bounds__(256, 1) void gru_persistent(
    const float* __restrict__ xg_f, const float* __restrict__ xg_b,
    const __half* __restrict__ whh16_f, const __half* __restrict__ whh16_b,
    fpp bhh_f, fpp bhh_b, __half* __restrict__ seq)
{
  const int dir  = blockIdx.x & 1;
  const int tile = blockIdx.x >> 1;
  const int bm   = tile * 16;
  const float* __restrict__ xg = dir ? xg_b : xg_f;
  const __half* __restrict__ Whh = dir ? whh16_b : whh16_f;
  fpp bhh = dir ? bhh_b : bhh_f;
  const int dcol = dir * NH;
  const int tid = threadIdx.x;
  const int wave = tid >> 6, lane = tid & 63;
  const int lm = lane & 15, quad = lane >> 4;

  __shared__ float xgs[16 * 772];      // 16 rows x 768 (stride 772) = 49.4 KB
  __shared__ __half h16[16 * 264];     // 16 rows x 256 (stride 264) = 8.4 KB

  // ---- stage xg rows (block rows contiguous at bm*NG), row-padded ----
  {
    const float4* src = (const float4*)(xg + (size_t)bm * NG);
#pragma unroll
    for (int i = 0; i < 12; i++) {
      int chunk = tid + i * 256;         // 0..3071 (16 rows x 192 float4)
      int row = chunk / 192, c4 = chunk - row * 192;
      *(float4*)&xgs[row * 772 + c4 * 4] = src[chunk];
    }
  }

  // ---- B fragments: kb 0..6 resident in registers ----
  const __half* bwp = Whh + (size_t)(wave * 64 + lm) * NH + quad * 8;
  half8 breg[3][4][7];
#pragma unroll
  for (int g = 0; g < 3; g++)
#pragma unroll
    for (int c = 0; c < 4; c++)
#pragma unroll
      for (int kb = 0; kb < 7; kb++)
        breg[g][c][kb] = *(const half8*)(bwp + (size_t)(g * NH + c * 16) * NH + kb * 32);

  float br_[4], bz_[4], bn_[4];
#pragma unroll
  for (int c = 0; c < 4; c++) {
    int n = wave * 64 + c * 16 + lm;
    br_[c] = bhh[n]; bz_[c] = bhh[NH + n]; bn_[c] = bhh[2 * NH + n];
  }

  float hp[4][4];
#pragma unroll
  for (int c = 0; c < 4; c++)
#pragma unroll
    for (int r = 0; r < 4; r++) hp[c][r] = 0.f;

  __syncthreads();  // xgs staged

  const int arow = lm * 264 + quad * 8;

  for (int step = 0; step < NT; step++) {
    const int t_out = dir ? (NT - 1 - step) : step;
    floatx4 acc[3][4];
#pragma unroll
    for (int g = 0; g < 3; g++)
#pragma unroll
      for (int c = 0; c < 4; c++) acc[g][c] = (floatx4){0.f, 0.f, 0.f, 0.f};

    if (step > 0) {
#pragma unroll
      for (int kb = 0; kb < 7; kb++) {
        half8 a = *(const half8*)&h16[arow + kb * 32];
#pragma unroll
        for (int g = 0; g < 3; g++)
#pragma unroll
          for (int c = 0; c < 4; c++)
            acc[g][c] = __builtin_amdgcn_mfma_f32_16x16x32_f16(a, breg[g][c][kb], acc[g][c], 0, 0, 0);
      }
      {
        half8 a = *(const half8*)&h16[arow + 224];
        half8 b7[3][4];
#pragma unroll
        for (int g = 0; g < 3; g++)
#pragma unroll
          for (int c = 0; c < 4; c++)
            b7[g][c] = *(const half8*)(bwp + (size_t)(g * NH + c * 16) * NH + 224);
#pragma unroll
        for (int g = 0; g < 3; g++)
#pragma unroll
          for (int c = 0; c < 4; c++)
            acc[g][c] = __builtin_amdgcn_mfma_f32_16x16x32_f16(a, b7[g][c], acc[g][c], 0, 0, 0);
      }
      __syncthreads();  // h16 reads done before overwrite
    }

    // ---- epilogue: gates + state update ----
#pragma unroll
    for (int c = 0; c < 4; c++) {
      int n = wave * 64 + c * 16 + lm;
#pragma unroll
      for (int r = 0; r < 4; r++) {
        int m = quad * 4 + r;
        const float* xp = &xgs[m * 772 + n];
        float rg = fast_sig(xp[0]      + acc[0][c][r] + br_[c]);
        float zg = fast_sig(xp[NH]     + acc[1][c][r] + bz_[c]);
        float nn = fast_tanh(xp[2 * NH] + rg * (acc[2][c][r] + bn_[c]));
        float hv = (1.f - zg) * nn + zg * hp[c][r];
        hp[c][r] = hv;
        h16[m * 264 + n] = __float2half(hv);
      }
    }
    __syncthreads();  // h16 complete

    // ---- cooperative copy h16 -> seq[t_out] (coalesced float4 stores) ----
#pragma unroll
    for (int i = 0; i < 2; i++) {
      int chunk = tid + i * 256;         // 0..511 = 16 rows x 32 chunks(16B)
      int m = chunk >> 5, part = chunk & 31;
      float4 v = *(const float4*)&h16[m * 264 + part * 8];
      *(float4*)&seq[((size_t)(bm + m) * NT + t_out) * ND + dcol + part * 8] = v;
    }
  }
}

// ---------------------------------------------------------------------------
// Attention scores via MFMA, M=128 rows/block, single pass, no atomics.
// ---------------------------------------------------------------------------
__global__ __launch_bounds__(256) void attn_score_mfma(
    const __half* __restrict__ seq, const __half* __restrict__ w116,
    fpp b1, fpp W2, float* __restrict__ scores)
{
  const int bm = blockIdx.x * 128;
  const int tid = threadIdx.x;
  const int wave = tid >> 6, lane = tid & 63;
  const int lm = lane & 15, quad = lane >> 4;

  __shared__ __half As[128 * 40];
  __shared__ __half Bs[256 * 40];

  floatx4 acc[2][16];
#pragma unroll
  for (int mt = 0; mt < 2; mt++)
#pragma unroll
    for (int nt = 0; nt < 16; nt++) acc[mt][nt] = (floatx4){0.f, 0.f, 0.f, 0.f};

  for (int k0 = 0; k0 < ND; k0 += 32) {
    __syncthreads();
#pragma unroll
    for (int i = 0; i < 2; i++) {
      int e = tid + i * 256;
      int row = e >> 2, kc = e & 3;
      *(float4*)&As[row * 40 + kc * 8] =
        *(const float4*)&seq[(size_t)(bm + row) * ND + k0 + kc * 8];
    }
#pragma unroll
    for (int i = 0; i < 4; i++) {
      int e = tid + i * 256;
      int row = e >> 2, kc = e & 3;
      *(float4*)&Bs[row * 40 + kc * 8] =
        *(const float4*)&w116[(size_t)row * ND + k0 + kc * 8];
    }
    __syncthreads();
    half8 a0 = *(const half8*)&As[((wave * 2 + 0) * 16 + lm) * 40 + quad * 8];
    half8 a1 = *(const half8*)&As[((wave * 2 + 1) * 16 + lm) * 40 + quad * 8];
#pragma unroll
    for (int nt = 0; nt < 16; nt++) {
      half8 bf = *(const half8*)&Bs[(nt * 16 + lm) * 40 + quad * 8];
      acc[0][nt] = __builtin_amdgcn_mfma_f32_16x16x32_f16(a0, bf, acc[0][nt], 0, 0, 0);
      acc[1][nt] = __builtin_amdgcn_mfma_f32_16x16x32_f16(a1, bf, acc[1][nt], 0, 0, 0);
    }
  }

  float rs[2][4] = {};
#pragma unroll
  for (int nt = 0; nt < 16; nt++) {
    int n = nt * 16 + lm;
    float b1v = b1[n], w2v = W2[n];
#pragma unroll
    for (int mt = 0; mt < 2; mt++)
#pragma unroll
      for (int r = 0; r < 4; r++)
        rs[mt][r] += fast_tanh(acc[mt][nt][r] + b1v) * w2v;
  }
#pragma unroll
  for (int mt = 0; mt < 2; mt++)
#pragma unroll
    for (int r = 0; r < 4; r++) {
      rs[mt][r] += __shfl_xor(rs[mt][r], 1);
      rs[mt][r] += __shfl_xor(rs[mt][r], 2);
      rs[mt][r] += __shfl_xor(rs[mt][r], 4);
      rs[mt][r] += __shfl_xor(rs[mt][r], 8);
    }
  if (lm == 0) {
#pragma unroll
    for (int mt = 0; mt < 2; mt++)
#pragma unroll
      for (int r = 0; r < 4; r++)
        scores[bm + (wave * 2 + mt) * 16 + quad * 4 + r] = rs[mt][r];
  }
}

__global__ void softmax_t(float* __restrict__ s)
{
  int b = blockIdx.x, lane = threadIdx.x;
  float v = (lane < NT) ? s[(size_t)b * NT + lane] : -1e30f;
  float m = v;
#pragma unroll
  for (int off = 32; off >= 1; off >>= 1) m = fmaxf(m, __shfl_xor(m, off));
  float e = (lane < NT) ? __expf(v - m) : 0.f;
  float sum = e;
#pragma unroll
  for (int off = 32; off >= 1; off >>= 1) sum += __shfl_xor(sum, off);
  if (lane < NT) s[(size_t)b * NT + lane] = e / sum;
}

__global__ void context_c(const __half* __restrict__ seq,
                          const float* __restrict__ w, float* __restrict__ c)
{
  int idx = blockIdx.x * 256 + threadIdx.x;  // NB*64 groups of 8 cols
  int b = idx >> 6, d8 = (idx & 63) * 8;
  float s[8] = {};
  for (int t = 0; t < NT; t++) {
    float wt = w[(size_t)b * NT + t];
    half8 v = *(const half8*)&seq[((size_t)b * NT + t) * ND + d8];
#pragma unroll
    for (int i = 0; i < 8; i++) s[i] += wt * (float)v[i];
  }
  float* cp = c + (size_t)b * ND + d8;
#pragma unroll
  for (int i = 0; i < 8; i++) cp[i] = s[i];
}

// ---------------------------------------------------------------------------
// Fused joints projection + forward kinematics. One wave handles 4 (b,t).
// ---------------------------------------------------------------------------
__constant__ float c_lower[6] = {-3.1416f, -1.5708f, -3.1416f, -2.6f, -1.5708f, -1.2f};
__constant__ float c_upper[6] = { 3.1416f,  1.5708f,  3.1416f,  0.1f,  1.5708f,  1.2f};

__global__ __launch_bounds__(256) void joints_fk(
    const __half* __restrict__ seq, const float* __restrict__ c,
    fpp jW, fpp jb, float* __restrict__ out)
{
  __shared__ float w[6 * ND];
  const int tid = threadIdx.x;
#pragma unroll
  for (int i = 0; i < 12; i++) w[tid + i * 256] = jW[tid + i * 256];
  __syncthreads();

  const int wave = tid >> 6, lane = tid & 63;
  const int d0 = lane * 8;

  for (int it = 0; it < 4; it++) {
    const int bt = blockIdx.x * 16 + wave * 4 + it;
    const int b = bt / NT;

    half8 hv = *(const half8*)&seq[(size_t)bt * ND + d0];
    float xv[8];
#pragma unroll
    for (int i = 0; i < 8; i++)
      xv[i] = (float)hv[i] + c[(size_t)b * ND + d0 + i];

    float jnt[6];
#pragma unroll
    for (int j = 0; j < 6; j++) {
      float p = 0.f;
#pragma unroll
      for (int i = 0; i < 8; i++) p = fmaf(xv[i], w[j * ND + d0 + i], p);
#pragma unroll
      for (int off = 32; off >= 1; off >>= 1) p += __shfl_xor(p, off);
      jnt[j] = p + jb[j];
    }

    float th[6];
#pragma unroll
    for (int j = 0; j < 6; j++)
      th[j] = jnt[j] * (c_upper[j] - c_lower[j]) + c_lower[j];

    float c0x = 1.f, c0y = 0.f, c0z = 0.f;
    float c1x = 0.f, c1y = 1.f, c1z = 0.f;
    float c2x = 0.f, c2y = 0.f, c2z = 1.f;
    float px = 0.f, py = 0.f, pz = 0.1f;
    float s, cc, tx_, ty_, tz_, ux_, uy_, uz_;

    // rotZ(th0)
    s = sinf(th[0]); cc = cosf(th[0]);
    tx_ = cc * c0x + s * c1x; ty_ = cc * c0y + s * c1y; tz_ = cc * c0z + s * c1z;
    ux_ = -s * c0x + cc * c1x; uy_ = -s * c0y + cc * c1y; uz_ = -s * c0z + cc * c1z;
    c0x = tx_; c0y = ty_; c0z = tz_; c1x = ux_; c1y = uy_; c1z = uz_;

    float shx = px, shy = py, shz = pz;  // shoulder2
    // rotX(th1)
    s = sinf(th[1]); cc = cosf(th[1]);
    tx_ = cc * c1x + s * c2x; ty_ = cc * c1y + s * c2y; tz_ = cc * c1z + s * c2z;
    ux_ = -s * c1x + cc * c2x; uy_ = -s * c1y + cc * c2y; uz_ = -s * c1z + cc * c2z;
    c1x = tx_; c1y = ty_; c1z = tz_; c2x = ux_; c2y = uy_; c2z = uz_;

    // rotY(th2)
    s = sinf(th[2]); cc = cosf(th[2]);
    tx_ = cc * c0x - s * c2x; ty_ = cc * c0y - s * c2y; tz_ = cc * c0z - s * c2z;
    ux_ = s * c0x + cc * c2x; uy_ = s * c0y + cc * c2y; uz_ = s * c0z + cc * c2z;
    c0x = tx_; c0y = ty_; c0z = tz_; c2x = ux_; c2y = uy_; c2z = uz_;

    // joint3 offset -> forearm
    px -= 0.25f * c1x; py -= 0.25f * c1y; pz -= 0.25f * c1z;
    float fox = px, foy = py, foz = pz;
    // rotX(th3)
    s = sinf(th[3]); cc = cosf(th[3]);
    tx_ = cc * c1x + s * c2x; ty_ = cc * c1y + s * c2y; tz_ = cc * c1z + s * c2z;
    ux_ = -s * c1x + cc * c2x; uy_ = -s * c1y + cc * c2y; uz_ = -s * c1z + cc * c2z;
    c1x = tx_; c1y = ty_; c1z = tz_; c2x = ux_; c2y = uy_; c2z = uz_;

    // rotY(th4)
    s = sinf(th[4]); cc = cosf(th[4]);
    tx_ = cc * c0x - s * c2x; ty_ = cc * c0y - s * c2y; tz_ = cc * c0z - s * c2z;
    ux_ = s * c0x + cc * c2x; uy_ = s * c0y + cc * c2y; uz_ = s * c0z + cc * c2z;
    c0x = tx_; c0y = ty_; c0z = tz_; c2x = ux_; c2y = uy_; c2z = uz_;

    // joint5 offset -> wrist
    px -= 0.25f * c1x; py -= 0.25f * c1y; pz -= 0.25f * c1z;
    float wx = px, wy = py, wz = pz;
    // rotX(th5)
    s = sinf(th[5]); cc = cosf(th[5]);
    tx_ = cc * c1x + s * c2x; ty_ = cc * c1y + s * c2y; tz_ = cc * c1z + s * c2z;
    ux_ = -s * c1x + cc * c2x; uy_ = -s * c1y + cc * c2y; uz_ = -s * c1z + cc * c2z;
    c1x = tx_; c1y = ty_; c1z = tz_; c2x = ux_; c2y = uy_; c2z = uz_;

    float f1x = wx - 0.08f * c1x + 0.02f * c2x;
    float f1y = wy - 0.08f * c1y + 0.02f * c2y;
    float f1z = wz - 0.08f * c1z + 0.02f * c2z;
    float f4x = wx - 0.08f * c1x - 0.02f * c2x;
    float f4y = wy - 0.08f * c1y - 0.02f * c2y;
    float f4z = wz - 0.08f * c1z - 0.02f * c2z;

    float dsx = shx - fox, dsy = shy - foy, dsz = shz - foz;
    float dwx = wx - fox, dwy = wy - foy, dwz = wz - foz;
    float bodyL = 0.5f * (sqrtf(dsx * dsx + dsy * dsy + dsz * dsz) +
                          sqrtf(dwx * dwx + dwy * dwy + dwz * dwz));
    float inv = 1.f / bodyL;

    float rel[9];
    rel[0] = (wx - shx) * inv; rel[1] = (wy - shy) * inv; rel[2] = (wz - shz) * inv;
    rel[3] = (f1x - shx) * inv; rel[4] = (f1y - shy) * inv; rel[5] = (f1z - shz) * inv;
    rel[6] = (f4x - shx) * inv; rel[7] = (f4y - shy) * inv; rel[8] = (f4z - shz) * inv;

    if (lane < 9) out[(size_t)bt * 9 + lane] = rel[lane];
  }
}

// ---------------------------------------------------------------------------
extern "C" void kernel_launch(void* const* d_in, const int* in_sizes, int n_in,
                              void* d_out, int out_size, void* d_ws, size_t ws_size,
                              hipStream_t stream)
{
  fpp z     = (fpp)d_in[0];
  fpp W_fc  = (fpp)d_in[1];
  fpp b_fc  = (fpp)d_in[2];
  fpp bn_g  = (fpp)d_in[3];
  fpp bn_b  = (fpp)d_in[4];
  fpp Wih_f = (fpp)d_in[5];
  fpp Whh_f = (fpp)d_in[6];
  fpp bih_f = (fpp)d_in[7];
  fpp bhh_f = (fpp)d_in[8];
  fpp Wih_b = (fpp)d_in[9];
  fpp Whh_b = (fpp)d_in[10];
  fpp bih_b = (fpp)d_in[11];
  fpp bhh_b = (fpp)d_in[12];
  fpp aW1   = (fpp)d_in[13];
  fpp ab1   = (fpp)d_in[14];
  fpp aW2   = (fpp)d_in[15];
  fpp jW    = (fpp)d_in[16];
  fpp jb    = (fpp)d_in[17];

  float* ws     = (float*)d_ws;
  float* h0     = ws;                        // 2048*512 fp32
  float* xg_f   = h0 + 1048576;              // 2048*768 fp32
  float* xg_b   = xg_f + 1572864;            // 2048*768 fp32
  float* scale  = xg_b + 1572864;            // 512
  float* shift  = scale + 512;               // 512
  float* scores = shift + 512;               // 2048*60
  float* cbuf   = scores + 122880;           // 2048*512
  __half* gseq    = (__half*)(cbuf + 1048576);   // 2048*60*512 fp16 (126 MB)
  __half* whh16_f = gseq + 62914560;             // 768*256
  __half* whh16_b = whh16_f + 196608;            // 768*256
  __half* w116    = whh16_b + 196608;            // 256*512
  __half* wih16_f = w116 + 131072;               // 768*512
  __half* wih16_b = wih16_f + 393216;            // 768*512
  __half* h16g    = wih16_b + 393216;            // 2048*512

  // 0. weight conversions fp32->fp16
  convert_w<<<5120, 256, 0, stream>>>(Whh_f, Whh_b, aW1, Wih_f, Wih_b,
                                      whh16_f, whh16_b, w116, wih16_f, wih16_b);
  // 1. fc: h0 = z @ W_fc^T + b_fc (fp32, K=100)
  gemm_fc<<<dim3(32, 8), 256, 0, stream>>>(z, W_fc, b_fc, h0,
                                           NB, ND, NDL, NDL, NDL, ND);
  // 2. batchnorm (training stats) + leaky relu -> fp16 h
  bn_stats<<<16, 256, 0, stream>>>(h0, bn_g, bn_b, scale, shift);
  bn_lrelu_h16<<<4096, 256, 0, stream>>>(h0, scale, shift, h16g);
  // 3. time-invariant input projections via MFMA (computed ONCE)
  gemm16<<<dim3(32, 12), 256, 0, stream>>>(h16g, wih16_f, bih_f, xg_f, NG, ND);
  gemm16<<<dim3(32, 12), 256, 0, stream>>>(h16g, wih16_b, bih_b, xg_b, NG, ND);
  // 4. ENTIRE GRU recurrence: one persistent launch, weights in registers
  gru_persistent<<<256, 256, 0, stream>>>(xg_f, xg_b, whh16_f, whh16_b,
                                          bhh_f, bhh_b, gseq);
  // 5. attention
  attn_score_mfma<<<960, 256, 0, stream>>>(gseq, w116, ab1, aW2, scores);
  softmax_t<<<NB, 64, 0, stream>>>(scores);
  context_c<<<512, 256, 0, stream>>>(gseq, scores, cbuf);
  // 6. joints projection + forward kinematics, fused
  joints_fk<<<7680, 256, 0, stream>>>(gseq, cbuf, jW, jb, (float*)d_out);
}

// Round 11
// 686.085 us; speedup vs baseline: 1.9492x; 1.1557x over previous
//
#include <hip/hip_runtime.h>
#include <hip/hip_fp16.h>

#define NB 2048
#define NT 60
#define NDL 100
#define ND 512
#define NH 256
#define NG 768

typedef const float* __restrict__ fpp;
typedef _Float16 half8 __attribute__((ext_vector_type(8)));
typedef float floatx4 __attribute__((ext_vector_type(4)));

__device__ __forceinline__ float fast_sig(float x) {
  return 1.f / (1.f + __expf(-x));
}
__device__ __forceinline__ float fast_tanh(float x) {
  float t = __expf(2.f * x);
  return (t - 1.f) / (t + 1.f);
}

// ---------------------------------------------------------------------------
// fp32 tiled GEMM (fc layer only, K=100): C = A*B^T + bias
// ---------------------------------------------------------------------------
__global__ __launch_bounds__(256) void gemm_fc(
    fpp A, fpp Bm, fpp bias, float* __restrict__ C,
    int M, int N, int K, int lda, int ldb, int ldc)
{
  __shared__ float As[16][68];
  __shared__ float Bs[16][68];
  const int bm = blockIdx.x * 64, bn = blockIdx.y * 64;
  const int tid = threadIdx.x;
  const int tx = tid & 15, ty = tid >> 4;
  float acc[4][4] = {};
  for (int k0 = 0; k0 < K; k0 += 16) {
#pragma unroll
    for (int i = 0; i < 4; i++) {
      int e = tid + i * 256;
      int m = e >> 4, k = e & 15;
      As[k][m] = (k0 + k < K) ? A[(size_t)(bm + m) * lda + k0 + k] : 0.f;
      Bs[k][m] = (k0 + k < K) ? Bm[(size_t)(bn + m) * ldb + k0 + k] : 0.f;
    }
    __syncthreads();
#pragma unroll
    for (int kk = 0; kk < 16; kk++) {
      float4 av = *(const float4*)&As[kk][ty * 4];
      float4 bv = *(const float4*)&Bs[kk][tx * 4];
      float a_[4] = {av.x, av.y, av.z, av.w};
      float b_[4] = {bv.x, bv.y, bv.z, bv.w};
#pragma unroll
      for (int i = 0; i < 4; i++)
#pragma unroll
        for (int j = 0; j < 4; j++)
          acc[i][j] = fmaf(a_[i], b_[j], acc[i][j]);
    }
    __syncthreads();
  }
#pragma unroll
  for (int i = 0; i < 4; i++) {
    int m = bm + ty * 4 + i;
#pragma unroll
    for (int j = 0; j < 4; j++) {
      int n = bn + tx * 4 + j;
      C[(size_t)m * ldc + n] = acc[i][j] + bias[n];
    }
  }
}

// ---------------------------------------------------------------------------
// BatchNorm batch statistics -> per-column scale/shift
// ---------------------------------------------------------------------------
__global__ __launch_bounds__(256) void bn_stats(
    const float* __restrict__ h0, fpp g, fpp b,
    float* __restrict__ scale, float* __restrict__ shift)
{
  const int cl = threadIdx.x & 31;
  const int col = blockIdx.x * 32 + cl;
  const int row0 = threadIdx.x >> 5;
  float s1 = 0.f, s2 = 0.f;
  for (int r = row0; r < NB; r += 8) {
    float v = h0[(size_t)r * ND + col];
    s1 += v; s2 += v * v;
  }
  __shared__ float l1[8][33], l2[8][33];
  l1[row0][cl] = s1;
  l2[row0][cl] = s2;
  __syncthreads();
  if (row0 == 0) {
#pragma unroll
    for (int r = 1; r < 8; r++) { s1 += l1[r][cl]; s2 += l2[r][cl]; }
    float mu = s1 / NB;
    float var = s2 / NB - mu * mu;
    float sc = g[col] * rsqrtf(var + 1e-5f);
    scale[col] = sc;
    shift[col] = b[col] - mu * sc;
  }
}

__global__ void bn_lrelu_h16(const float* __restrict__ h0,
                             const float* __restrict__ scale,
                             const float* __restrict__ shift,
                             __half* __restrict__ h16g)
{
  int idx = blockIdx.x * 256 + threadIdx.x;
  int d = idx & (ND - 1);
  float v = h0[idx] * scale[d] + shift[d];
  h16g[idx] = __float2half(v >= 0.f ? v : 0.2f * v);
}

// ---------------------------------------------------------------------------
// One-time weight conversions fp32 -> fp16
// ---------------------------------------------------------------------------
__global__ void convert_w(fpp whf, fpp whb, fpp w1, fpp wif, fpp wib,
                          __half* __restrict__ o_whf, __half* __restrict__ o_whb,
                          __half* __restrict__ o_w1, __half* __restrict__ o_wif,
                          __half* __restrict__ o_wib)
{
  int idx = blockIdx.x * 256 + threadIdx.x;  // 0 .. 1310719
  if (idx < 196608) o_whf[idx] = __float2half(whf[idx]);
  else if (idx < 393216) o_whb[idx - 196608] = __float2half(whb[idx - 196608]);
  else if (idx < 524288) o_w1[idx - 393216] = __float2half(w1[idx - 393216]);
  else if (idx < 917504) o_wif[idx - 524288] = __float2half(wif[idx - 524288]);
  else o_wib[idx - 917504] = __float2half(wib[idx - 917504]);
}

// ---------------------------------------------------------------------------
// fp16 MFMA GEMM (xg projections): C[m][n] = A[m][:]·B[n][:] + bias[n]
// ---------------------------------------------------------------------------
__global__ __launch_bounds__(256) void gemm16(
    const __half* __restrict__ A, const __half* __restrict__ Bm,
    fpp bias, float* __restrict__ C, int N, int K)
{
  __shared__ __half As[64 * 40];
  __shared__ __half Bs[64 * 40];
  const int bm = blockIdx.x * 64, bn = blockIdx.y * 64;
  const int tid = threadIdx.x;
  const int wave = tid >> 6, lane = tid & 63;
  const int lm = lane & 15, quad = lane >> 4;
  floatx4 acc[4];
#pragma unroll
  for (int nt = 0; nt < 4; nt++) acc[nt] = (floatx4){0.f, 0.f, 0.f, 0.f};

  const int row = tid >> 2, kc = tid & 3;
  for (int k0 = 0; k0 < K; k0 += 32) {
    __syncthreads();
    *(float4*)&As[row * 40 + kc * 8] =
      *(const float4*)&A[(size_t)(bm + row) * K + k0 + kc * 8];
    *(float4*)&Bs[row * 40 + kc * 8] =
      *(const float4*)&Bm[(size_t)(bn + row) * K + k0 + kc * 8];
    __syncthreads();
    half8 af = *(const half8*)&As[(wave * 16 + lm) * 40 + quad * 8];
#pragma unroll
    for (int nt = 0; nt < 4; nt++) {
      half8 bf = *(const half8*)&Bs[(nt * 16 + lm) * 40 + quad * 8];
      acc[nt] = __builtin_amdgcn_mfma_f32_16x16x32_f16(af, bf, acc[nt], 0, 0, 0);
    }
  }
#pragma unroll
  for (int nt = 0; nt < 4; nt++) {
    int n = bn + nt * 16 + lm;
    float bv = bias[n];
#pragma unroll
    for (int r = 0; r < 4; r++) {
      int m = bm + wave * 16 + quad * 4 + r;
      C[(size_t)m * N + n] = acc[nt][r] + bv;
    }
  }
}

// ---------------------------------------------------------------------------
// PERSISTENT GRU, 512 threads (8 waves, 2 waves/SIMD for latency hiding).
// Grid 256 = 128 row-tiles x 2 dirs, 1 block/CU. Each wave owns a 32-col
// n-slice for all 3 gates: B frags kb 0..5 resident in 144 VGPRs; kb6/kb7
// streamed from L2 with early prefetch. xg (time-invariant) + biases in
// registers (24+6 values). h-state fp16 in LDS (stride 264) + fp32 hp regs;
// seq written via cooperative LDS->global float4 copy (1 per thread).
// ---------------------------------------------------------------------------
__global__ __launch_bounds__(512, 1) void gru_persistent(
    const float* __restrict__ xg_f, const float* __restrict__ xg_b,
    const __half* __restrict__ whh16_f, const __half* __restrict__ whh16_b,
    fpp bhh_f, fpp bhh_b, __half* __restrict__ seq)
{
  const int dir  = blockIdx.x & 1;
  const int tile = blockIdx.x >> 1;
  const int bm   = tile * 16;
  const float* __restrict__ xg = dir ? xg_b : xg_f;
  const __half* __restrict__ Whh = dir ? whh16_b : whh16_f;
  fpp bhh = dir ? bhh_b : bhh_f;
  const int dcol = dir * NH;
  const int tid = threadIdx.x;
  const int wave = tid >> 6, lane = tid & 63;
  const int lm = lane & 15, quad = lane >> 4;
  const int n0 = wave * 32;

  __shared__ __half h16[16 * 264];     // 16 rows x 256 (stride 264) = 8.4 KB

  // ---- B fragment base pointers (per gate g, col-tile c) ----
  const __half* bp[3][2];
#pragma unroll
  for (int g = 0; g < 3; g++)
#pragma unroll
    for (int c = 0; c < 2; c++)
      bp[g][c] = Whh + (size_t)(g * NH + n0 + c * 16 + lm) * NH + quad * 8;

  // ---- resident B frags kb 0..5 (144 VGPRs) ----
  half8 breg[3][2][6];
#pragma unroll
  for (int g = 0; g < 3; g++)
#pragma unroll
    for (int c = 0; c < 2; c++)
#pragma unroll
      for (int kb = 0; kb < 6; kb++)
        breg[g][c][kb] = *(const half8*)(bp[g][c] + kb * 32);

  // ---- xg + biases in registers (time-invariant) ----
  float xr_[2][4], xz_[2][4], xn_[2][4];
  float br_[2], bz_[2], bn_[2];
#pragma unroll
  for (int c = 0; c < 2; c++) {
    int n = n0 + c * 16 + lm;
    br_[c] = bhh[n]; bz_[c] = bhh[NH + n]; bn_[c] = bhh[2 * NH + n];
#pragma unroll
    for (int r = 0; r < 4; r++) {
      int m = bm + quad * 4 + r;
      const float* xp = xg + (size_t)m * NG + n;
      xr_[c][r] = xp[0];
      xz_[c][r] = xp[NH];
      xn_[c][r] = xp[2 * NH];
    }
  }

  float hp[2][4];
#pragma unroll
  for (int c = 0; c < 2; c++)
#pragma unroll
    for (int r = 0; r < 4; r++) hp[c][r] = 0.f;

  const int arow = lm * 264 + quad * 8;

  for (int step = 0; step < NT; step++) {
    const int t_out = dir ? (NT - 1 - step) : step;
    floatx4 acc[3][2];
#pragma unroll
    for (int g = 0; g < 3; g++)
#pragma unroll
      for (int c = 0; c < 2; c++) acc[g][c] = (floatx4){0.f, 0.f, 0.f, 0.f};

    if (step > 0) {
      // early prefetch of streamed kb6/kb7 frags (used ~300 cyc later)
      half8 b6[3][2], b7[3][2];
#pragma unroll
      for (int g = 0; g < 3; g++)
#pragma unroll
        for (int c = 0; c < 2; c++) {
          b6[g][c] = *(const half8*)(bp[g][c] + 192);
          b7[g][c] = *(const half8*)(bp[g][c] + 224);
        }
#pragma unroll
      for (int kb = 0; kb < 6; kb++) {
        half8 a = *(const half8*)&h16[arow + kb * 32];
#pragma unroll
        for (int g = 0; g < 3; g++)
#pragma unroll
          for (int c = 0; c < 2; c++)
            acc[g][c] = __builtin_amdgcn_mfma_f32_16x16x32_f16(a, breg[g][c][kb], acc[g][c], 0, 0, 0);
      }
      {
        half8 a = *(const half8*)&h16[arow + 192];
#pragma unroll
        for (int g = 0; g < 3; g++)
#pragma unroll
          for (int c = 0; c < 2; c++)
            acc[g][c] = __builtin_amdgcn_mfma_f32_16x16x32_f16(a, b6[g][c], acc[g][c], 0, 0, 0);
      }
      {
        half8 a = *(const half8*)&h16[arow + 224];
#pragma unroll
        for (int g = 0; g < 3; g++)
#pragma unroll
          for (int c = 0; c < 2; c++)
            acc[g][c] = __builtin_amdgcn_mfma_f32_16x16x32_f16(a, b7[g][c], acc[g][c], 0, 0, 0);
      }
      __syncthreads();  // h16 reads done before overwrite
    }

    // ---- epilogue: gates + state update (all operands in registers) ----
#pragma unroll
    for (int c = 0; c < 2; c++) {
      int n = n0 + c * 16 + lm;
#pragma unroll
      for (int r = 0; r < 4; r++) {
        int m = quad * 4 + r;
        float rg = fast_sig(xr_[c][r] + acc[0][c][r] + br_[c]);
        float zg = fast_sig(xz_[c][r] + acc[1][c][r] + bz_[c]);
        float nn = fast_tanh(xn_[c][r] + rg * (acc[2][c][r] + bn_[c]));
        float hv = (1.f - zg) * nn + zg * hp[c][r];
        hp[c][r] = hv;
        h16[m * 264 + n] = __float2half(hv);
      }
    }
    __syncthreads();  // h16 complete

    // ---- cooperative copy h16 -> seq[t_out] (coalesced float4 stores) ----
    {
      int m = tid >> 5, part = tid & 31;   // 512 thr = 16 rows x 32 chunks
      float4 v = *(const float4*)&h16[m * 264 + part * 8];
      *(float4*)&seq[((size_t)(bm + m) * NT + t_out) * ND + dcol + part * 8] = v;
    }
  }
}

// ---------------------------------------------------------------------------
// Attention scores via MFMA, M=128 rows/block, single pass, no atomics.
// ---------------------------------------------------------------------------
__global__ __launch_bounds__(256) void attn_score_mfma(
    const __half* __restrict__ seq, const __half* __restrict__ w116,
    fpp b1, fpp W2, float* __restrict__ scores)
{
  const int bm = blockIdx.x * 128;
  const int tid = threadIdx.x;
  const int wave = tid >> 6, lane = tid & 63;
  const int lm = lane & 15, quad = lane >> 4;

  __shared__ __half As[128 * 40];
  __shared__ __half Bs[256 * 40];

  floatx4 acc[2][16];
#pragma unroll
  for (int mt = 0; mt < 2; mt++)
#pragma unroll
    for (int nt = 0; nt < 16; nt++) acc[mt][nt] = (floatx4){0.f, 0.f, 0.f, 0.f};

  for (int k0 = 0; k0 < ND; k0 += 32) {
    __syncthreads();
#pragma unroll
    for (int i = 0; i < 2; i++) {
      int e = tid + i * 256;
      int row = e >> 2, kc = e & 3;
      *(float4*)&As[row * 40 + kc * 8] =
        *(const float4*)&seq[(size_t)(bm + row) * ND + k0 + kc * 8];
    }
#pragma unroll
    for (int i = 0; i < 4; i++) {
      int e = tid + i * 256;
      int row = e >> 2, kc = e & 3;
      *(float4*)&Bs[row * 40 + kc * 8] =
        *(const float4*)&w116[(size_t)row * ND + k0 + kc * 8];
    }
    __syncthreads();
    half8 a0 = *(const half8*)&As[((wave * 2 + 0) * 16 + lm) * 40 + quad * 8];
    half8 a1 = *(const half8*)&As[((wave * 2 + 1) * 16 + lm) * 40 + quad * 8];
#pragma unroll
    for (int nt = 0; nt < 16; nt++) {
      half8 bf = *(const half8*)&Bs[(nt * 16 + lm) * 40 + quad * 8];
      acc[0][nt] = __builtin_amdgcn_mfma_f32_16x16x32_f16(a0, bf, acc[0][nt], 0, 0, 0);
      acc[1][nt] = __builtin_amdgcn_mfma_f32_16x16x32_f16(a1, bf, acc[1][nt], 0, 0, 0);
    }
  }

  float rs[2][4] = {};
#pragma unroll
  for (int nt = 0; nt < 16; nt++) {
    int n = nt * 16 + lm;
    float b1v = b1[n], w2v = W2[n];
#pragma unroll
    for (int mt = 0; mt < 2; mt++)
#pragma unroll
      for (int r = 0; r < 4; r++)
        rs[mt][r] += fast_tanh(acc[mt][nt][r] + b1v) * w2v;
  }
#pragma unroll
  for (int mt = 0; mt < 2; mt++)
#pragma unroll
    for (int r = 0; r < 4; r++) {
      rs[mt][r] += __shfl_xor(rs[mt][r], 1);
      rs[mt][r] += __shfl_xor(rs[mt][r], 2);
      rs[mt][r] += __shfl_xor(rs[mt][r], 4);
      rs[mt][r] += __shfl_xor(rs[mt][r], 8);
    }
  if (lm == 0) {
#pragma unroll
    for (int mt = 0; mt < 2; mt++)
#pragma unroll
      for (int r = 0; r < 4; r++)
        scores[bm + (wave * 2 + mt) * 16 + quad * 4 + r] = rs[mt][r];
  }
}

__global__ void softmax_t(float* __restrict__ s)
{
  int b = blockIdx.x, lane = threadIdx.x;
  float v = (lane < NT) ? s[(size_t)b * NT + lane] : -1e30f;
  float m = v;
#pragma unroll
  for (int off = 32; off >= 1; off >>= 1) m = fmaxf(m, __shfl_xor(m, off));
  float e = (lane < NT) ? __expf(v - m) : 0.f;
  float sum = e;
#pragma unroll
  for (int off = 32; off >= 1; off >>= 1) sum += __shfl_xor(sum, off);
  if (lane < NT) s[(size_t)b * NT + lane] = e / sum;
}

__global__ void context_c(const __half* __restrict__ seq,
                          const float* __restrict__ w, float* __restrict__ c)
{
  int idx = blockIdx.x * 256 + threadIdx.x;  // NB*64 groups of 8 cols
  int b = idx >> 6, d8 = (idx & 63) * 8;
  float s[8] = {};
  for (int t = 0; t < NT; t++) {
    float wt = w[(size_t)b * NT + t];
    half8 v = *(const half8*)&seq[((size_t)b * NT + t) * ND + d8];
#pragma unroll
    for (int i = 0; i < 8; i++) s[i] += wt * (float)v[i];
  }
  float* cp = c + (size_t)b * ND + d8;
#pragma unroll
  for (int i = 0; i < 8; i++) cp[i] = s[i];
}

// ---------------------------------------------------------------------------
// Fused joints projection + forward kinematics. One wave handles 4 (b,t).
// ---------------------------------------------------------------------------
__constant__ float c_lower[6] = {-3.1416f, -1.5708f, -3.1416f, -2.6f, -1.5708f, -1.2f};
__constant__ float c_upper[6] = { 3.1416f,  1.5708f,  3.1416f,  0.1f,  1.5708f,  1.2f};

__global__ __launch_bounds__(256) void joints_fk(
    const __half* __restrict__ seq, const float* __restrict__ c,
    fpp jW, fpp jb, float* __restrict__ out)
{
  __shared__ float w[6 * ND];
  const int tid = threadIdx.x;
#pragma unroll
  for (int i = 0; i < 12; i++) w[tid + i * 256] = jW[tid + i * 256];
  __syncthreads();

  const int wave = tid >> 6, lane = tid & 63;
  const int d0 = lane * 8;

  for (int it = 0; it < 4; it++) {
    const int bt = blockIdx.x * 16 + wave * 4 + it;
    const int b = bt / NT;

    half8 hv = *(const half8*)&seq[(size_t)bt * ND + d0];
    float xv[8];
#pragma unroll
    for (int i = 0; i < 8; i++)
      xv[i] = (float)hv[i] + c[(size_t)b * ND + d0 + i];

    float jnt[6];
#pragma unroll
    for (int j = 0; j < 6; j++) {
      float p = 0.f;
#pragma unroll
      for (int i = 0; i < 8; i++) p = fmaf(xv[i], w[j * ND + d0 + i], p);
#pragma unroll
      for (int off = 32; off >= 1; off >>= 1) p += __shfl_xor(p, off);
      jnt[j] = p + jb[j];
    }

    float th[6];
#pragma unroll
    for (int j = 0; j < 6; j++)
      th[j] = jnt[j] * (c_upper[j] - c_lower[j]) + c_lower[j];

    float c0x = 1.f, c0y = 0.f, c0z = 0.f;
    float c1x = 0.f, c1y = 1.f, c1z = 0.f;
    float c2x = 0.f, c2y = 0.f, c2z = 1.f;
    float px = 0.f, py = 0.f, pz = 0.1f;
    float s, cc, tx_, ty_, tz_, ux_, uy_, uz_;

    // rotZ(th0)
    s = sinf(th[0]); cc = cosf(th[0]);
    tx_ = cc * c0x + s * c1x; ty_ = cc * c0y + s * c1y; tz_ = cc * c0z + s * c1z;
    ux_ = -s * c0x + cc * c1x; uy_ = -s * c0y + cc * c1y; uz_ = -s * c0z + cc * c1z;
    c0x = tx_; c0y = ty_; c0z = tz_; c1x = ux_; c1y = uy_; c1z = uz_;

    float shx = px, shy = py, shz = pz;  // shoulder2
    // rotX(th1)
    s = sinf(th[1]); cc = cosf(th[1]);
    tx_ = cc * c1x + s * c2x; ty_ = cc * c1y + s * c2y; tz_ = cc * c1z + s * c2z;
    ux_ = -s * c1x + cc * c2x; uy_ = -s * c1y + cc * c2y; uz_ = -s * c1z + cc * c2z;
    c1x = tx_; c1y = ty_; c1z = tz_; c2x = ux_; c2y = uy_; c2z = uz_;

    // rotY(th2)
    s = sinf(th[2]); cc = cosf(th[2]);
    tx_ = cc * c0x - s * c2x; ty_ = cc * c0y - s * c2y; tz_ = cc * c0z - s * c2z;
    ux_ = s * c0x + cc * c2x; uy_ = s * c0y + cc * c2y; uz_ = s * c0z + cc * c2z;
    c0x = tx_; c0y = ty_; c0z = tz_; c2x = ux_; c2y = uy_; c2z = uz_;

    // joint3 offset -> forearm
    px -= 0.25f * c1x; py -= 0.25f * c1y; pz -= 0.25f * c1z;
    float fox = px, foy = py, foz = pz;
    // rotX(th3)
    s = sinf(th[3]); cc = cosf(th[3]);
    tx_ = cc * c1x + s * c2x; ty_ = cc * c1y + s * c2y; tz_ = cc * c1z + s * c2z;
    ux_ = -s * c1x + cc * c2x; uy_ = -s * c1y + cc * c2y; uz_ = -s * c1z + cc * c2z;
    c1x = tx_; c1y = ty_; c1z = tz_; c2x = ux_; c2y = uy_; c2z = uz_;

    // rotY(th4)
    s = sinf(th[4]); cc = cosf(th[4]);
    tx_ = cc * c0x - s * c2x; ty_ = cc * c0y - s * c2y; tz_ = cc * c0z - s * c2z;
    ux_ = s * c0x + cc * c2x; uy_ = s * c0y + cc * c2y; uz_ = s * c0z + cc * c2z;
    c0x = tx_; c0y = ty_; c0z = tz_; c2x = ux_; c2y = uy_; c2z = uz_;

    // joint5 offset -> wrist
    px -= 0.25f * c1x; py -= 0.25f * c1y; pz -= 0.25f * c1z;
    float wx = px, wy = py, wz = pz;
    // rotX(th5)
    s = sinf(th[5]); cc = cosf(th[5]);
    tx_ = cc * c1x + s * c2x; ty_ = cc * c1y + s * c2y; tz_ = cc * c1z + s * c2z;
    ux_ = -s * c1x + cc * c2x; uy_ = -s * c1y + cc * c2y; uz_ = -s * c1z + cc * c2z;
    c1x = tx_; c1y = ty_; c1z = tz_; c2x = ux_; c2y = uy_; c2z = uz_;

    float f1x = wx - 0.08f * c1x + 0.02f * c2x;
    float f1y = wy - 0.08f * c1y + 0.02f * c2y;
    float f1z = wz - 0.08f * c1z + 0.02f * c2z;
    float f4x = wx - 0.08f * c1x - 0.02f * c2x;
    float f4y = wy - 0.08f * c1y - 0.02f * c2y;
    float f4z = wz - 0.08f * c1z - 0.02f * c2z;

    float dsx = shx - fox, dsy = shy - foy, dsz = shz - foz;
    float dwx = wx - fox, dwy = wy - foy, dwz = wz - foz;
    float bodyL = 0.5f * (sqrtf(dsx * dsx + dsy * dsy + dsz * dsz) +
                          sqrtf(dwx * dwx + dwy * dwy + dwz * dwz));
    float inv = 1.f / bodyL;

    float rel[9];
    rel[0] = (wx - shx) * inv; rel[1] = (wy - shy) * inv; rel[2] = (wz - shz) * inv;
    rel[3] = (f1x - shx) * inv; rel[4] = (f1y - shy) * inv; rel[5] = (f1z - shz) * inv;
    rel[6] = (f4x - shx) * inv; rel[7] = (f4y - shy) * inv; rel[8] = (f4z - shz) * inv;

    if (lane < 9) out[(size_t)bt * 9 + lane] = rel[lane];
  }
}

// ---------------------------------------------------------------------------
extern "C" void kernel_launch(void* const* d_in, const int* in_sizes, int n_in,
                              void* d_out, int out_size, void* d_ws, size_t ws_size,
                              hipStream_t stream)
{
  fpp z     = (fpp)d_in[0];
  fpp W_fc  = (fpp)d_in[1];
  fpp b_fc  = (fpp)d_in[2];
  fpp bn_g  = (fpp)d_in[3];
  fpp bn_b  = (fpp)d_in[4];
  fpp Wih_f = (fpp)d_in[5];
  fpp Whh_f = (fpp)d_in[6];
  fpp bih_f = (fpp)d_in[7];
  fpp bhh_f = (fpp)d_in[8];
  fpp Wih_b = (fpp)d_in[9];
  fpp Whh_b = (fpp)d_in[10];
  fpp bih_b = (fpp)d_in[11];
  fpp bhh_b = (fpp)d_in[12];
  fpp aW1   = (fpp)d_in[13];
  fpp ab1   = (fpp)d_in[14];
  fpp aW2   = (fpp)d_in[15];
  fpp jW    = (fpp)d_in[16];
  fpp jb    = (fpp)d_in[17];

  float* ws     = (float*)d_ws;
  float* h0     = ws;                        // 2048*512 fp32
  float* xg_f   = h0 + 1048576;              // 2048*768 fp32
  float* xg_b   = xg_f + 1572864;            // 2048*768 fp32
  float* scale  = xg_b + 1572864;            // 512
  float* shift  = scale + 512;               // 512
  float* scores = shift + 512;               // 2048*60
  float* cbuf   = scores + 122880;           // 2048*512
  __half* gseq    = (__half*)(cbuf + 1048576);   // 2048*60*512 fp16 (126 MB)
  __half* whh16_f = gseq + 62914560;             // 768*256
  __half* whh16_b = whh16_f + 196608;            // 768*256
  __half* w116    = whh16_b + 196608;            // 256*512
  __half* wih16_f = w116 + 131072;               // 768*512
  __half* wih16_b = wih16_f + 393216;            // 768*512
  __half* h16g    = wih16_b + 393216;            // 2048*512

  // 0. weight conversions fp32->fp16
  convert_w<<<5120, 256, 0, stream>>>(Whh_f, Whh_b, aW1, Wih_f, Wih_b,
                                      whh16_f, whh16_b, w116, wih16_f, wih16_b);
  // 1. fc: h0 = z @ W_fc^T + b_fc (fp32, K=100)
  gemm_fc<<<dim3(32, 8), 256, 0, stream>>>(z, W_fc, b_fc, h0,
                                           NB, ND, NDL, NDL, NDL, ND);
  // 2. batchnorm (training stats) + leaky relu -> fp16 h
  bn_stats<<<16, 256, 0, stream>>>(h0, bn_g, bn_b, scale, shift);
  bn_lrelu_h16<<<4096, 256, 0, stream>>>(h0, scale, shift, h16g);
  // 3. time-invariant input projections via MFMA (computed ONCE)
  gemm16<<<dim3(32, 12), 256, 0, stream>>>(h16g, wih16_f, bih_f, xg_f, NG, ND);
  gemm16<<<dim3(32, 12), 256, 0, stream>>>(h16g, wih16_b, bih_b, xg_b, NG, ND);
  // 4. ENTIRE GRU recurrence: one persistent launch, 8 waves/block
  gru_persistent<<<256, 512, 0, stream>>>(xg_f, xg_b, whh16_f, whh16_b,
                                          bhh_f, bhh_b, gseq);
  // 5. attention
  attn_score_mfma<<<960, 256, 0, stream>>>(gseq, w116, ab1, aW2, scores);
  softmax_t<<<NB, 64, 0, stream>>>(scores);
  context_c<<<512, 256, 0, stream>>>(gseq, scores, cbuf);
  // 6. joints projection + forward kinematics, fused
  joints_fk<<<7680, 256, 0, stream>>>(gseq, cbuf, jW, jb, (float*)d_out);
}

// Round 12
// 629.643 us; speedup vs baseline: 2.1239x; 1.0896x over previous
//
#include <hip/hip_runtime.h>
#include <hip/hip_fp16.h>

#define NB 2048
#define NT 60
#define NDL 100
#define ND 512
#define NH 256
#define NG 768

typedef const float* __restrict__ fpp;
typedef _Float16 half8 __attribute__((ext_vector_type(8)));
typedef float floatx4 __attribute__((ext_vector_type(4)));

__device__ __forceinline__ float fast_sig(float x) {
  return 1.f / (1.f + __expf(-x));
}
__device__ __forceinline__ float fast_tanh(float x) {
  float t = __expf(2.f * x);
  return (t - 1.f) / (t + 1.f);
}

// ---------------------------------------------------------------------------
// fp32 tiled GEMM (fc layer only, K=100): C = A*B^T + bias
// ---------------------------------------------------------------------------
__global__ __launch_bounds__(256) void gemm_fc(
    fpp A, fpp Bm, fpp bias, float* __restrict__ C,
    int M, int N, int K, int lda, int ldb, int ldc)
{
  __shared__ float As[16][68];
  __shared__ float Bs[16][68];
  const int bm = blockIdx.x * 64, bn = blockIdx.y * 64;
  const int tid = threadIdx.x;
  const int tx = tid & 15, ty = tid >> 4;
  float acc[4][4] = {};
  for (int k0 = 0; k0 < K; k0 += 16) {
#pragma unroll
    for (int i = 0; i < 4; i++) {
      int e = tid + i * 256;
      int m = e >> 4, k = e & 15;
      As[k][m] = (k0 + k < K) ? A[(size_t)(bm + m) * lda + k0 + k] : 0.f;
      Bs[k][m] = (k0 + k < K) ? Bm[(size_t)(bn + m) * ldb + k0 + k] : 0.f;
    }
    __syncthreads();
#pragma unroll
    for (int kk = 0; kk < 16; kk++) {
      float4 av = *(const float4*)&As[kk][ty * 4];
      float4 bv = *(const float4*)&Bs[kk][tx * 4];
      float a_[4] = {av.x, av.y, av.z, av.w};
      float b_[4] = {bv.x, bv.y, bv.z, bv.w};
#pragma unroll
      for (int i = 0; i < 4; i++)
#pragma unroll
        for (int j = 0; j < 4; j++)
          acc[i][j] = fmaf(a_[i], b_[j], acc[i][j]);
    }
    __syncthreads();
  }
#pragma unroll
  for (int i = 0; i < 4; i++) {
    int m = bm + ty * 4 + i;
#pragma unroll
    for (int j = 0; j < 4; j++) {
      int n = bn + tx * 4 + j;
      C[(size_t)m * ldc + n] = acc[i][j] + bias[n];
    }
  }
}

// ---------------------------------------------------------------------------
// BN partial sums: 64 blocks x 32 rows, coalesced, atomicAdd into s1/s2[512].
// ---------------------------------------------------------------------------
__global__ __launch_bounds__(256) void bn_partial(
    const float* __restrict__ h0, float* __restrict__ s1g,
    float* __restrict__ s2g)
{
  const int r0 = blockIdx.x * 32;
  const int tid = threadIdx.x;
  float a1 = 0.f, a2 = 0.f, b1 = 0.f, b2 = 0.f;
  for (int r = 0; r < 32; r++) {
    float v = h0[(size_t)(r0 + r) * ND + tid];
    float w = h0[(size_t)(r0 + r) * ND + tid + 256];
    a1 += v; a2 += v * v;
    b1 += w; b2 += w * w;
  }
  atomicAdd(&s1g[tid], a1);
  atomicAdd(&s2g[tid], a2);
  atomicAdd(&s1g[tid + 256], b1);
  atomicAdd(&s2g[tid + 256], b2);
}

// bn (stats from s1/s2) + leaky relu, writing fp16
__global__ void bn_lrelu_h16(const float* __restrict__ h0,
                             fpp g, fpp b,
                             const float* __restrict__ s1g,
                             const float* __restrict__ s2g,
                             __half* __restrict__ h16g)
{
  int idx = blockIdx.x * 256 + threadIdx.x;
  int d = idx & (ND - 1);
  float mu = s1g[d] * (1.f / NB);
  float var = s2g[d] * (1.f / NB) - mu * mu;
  float sc = g[d] * rsqrtf(var + 1e-5f);
  float sh = b[d] - mu * sc;
  float v = h0[idx] * sc + sh;
  h16g[idx] = __float2half(v >= 0.f ? v : 0.2f * v);
}

// ---------------------------------------------------------------------------
// One-time weight conversions fp32 -> fp16
// ---------------------------------------------------------------------------
__global__ void convert_w(fpp whf, fpp whb, fpp w1, fpp wif, fpp wib,
                          __half* __restrict__ o_whf, __half* __restrict__ o_whb,
                          __half* __restrict__ o_w1, __half* __restrict__ o_wif,
                          __half* __restrict__ o_wib)
{
  int idx = blockIdx.x * 256 + threadIdx.x;  // 0 .. 1310719
  if (idx < 196608) o_whf[idx] = __float2half(whf[idx]);
  else if (idx < 393216) o_whb[idx - 196608] = __float2half(whb[idx - 196608]);
  else if (idx < 524288) o_w1[idx - 393216] = __float2half(w1[idx - 393216]);
  else if (idx < 917504) o_wif[idx - 524288] = __float2half(wif[idx - 524288]);
  else o_wib[idx - 917504] = __float2half(wib[idx - 917504]);
}

// ---------------------------------------------------------------------------
// fp16 MFMA GEMM (xg projections): C[m][n] = A[m][:]·B[n][:] + bias[n]
// ---------------------------------------------------------------------------
__global__ __launch_bounds__(256) void gemm16(
    const __half* __restrict__ A, const __half* __restrict__ Bm,
    fpp bias, float* __restrict__ C, int N, int K)
{
  __shared__ __half As[64 * 40];
  __shared__ __half Bs[64 * 40];
  const int bm = blockIdx.x * 64, bn = blockIdx.y * 64;
  const int tid = threadIdx.x;
  const int wave = tid >> 6, lane = tid & 63;
  const int lm = lane & 15, quad = lane >> 4;
  floatx4 acc[4];
#pragma unroll
  for (int nt = 0; nt < 4; nt++) acc[nt] = (floatx4){0.f, 0.f, 0.f, 0.f};

  const int row = tid >> 2, kc = tid & 3;
  for (int k0 = 0; k0 < K; k0 += 32) {
    __syncthreads();
    *(float4*)&As[row * 40 + kc * 8] =
      *(const float4*)&A[(size_t)(bm + row) * K + k0 + kc * 8];
    *(float4*)&Bs[row * 40 + kc * 8] =
      *(const float4*)&Bm[(size_t)(bn + row) * K + k0 + kc * 8];
    __syncthreads();
    half8 af = *(const half8*)&As[(wave * 16 + lm) * 40 + quad * 8];
#pragma unroll
    for (int nt = 0; nt < 4; nt++) {
      half8 bf = *(const half8*)&Bs[(nt * 16 + lm) * 40 + quad * 8];
      acc[nt] = __builtin_amdgcn_mfma_f32_16x16x32_f16(af, bf, acc[nt], 0, 0, 0);
    }
  }
#pragma unroll
  for (int nt = 0; nt < 4; nt++) {
    int n = bn + nt * 16 + lm;
    float bv = bias[n];
#pragma unroll
    for (int r = 0; r < 4; r++) {
      int m = bm + wave * 16 + quad * 4 + r;
      C[(size_t)m * N + n] = acc[nt][r] + bv;
    }
  }
}

// ---------------------------------------------------------------------------
// PERSISTENT GRU, 512 threads (8 waves, 2 waves/SIMD). Grid 256 = 128 tiles
// x 2 dirs, 1 block/CU. B frags kb0..5 register-resident; kb6/7 streamed.
// xg + biases in registers. h-state fp16 in LDS (stride 264) + fp32 hp regs.
// seq store for step s-1 issued at TOP of step s so its vmcnt drain hides
// behind the K-loop instead of stalling the epilogue barrier.
// ---------------------------------------------------------------------------
__global__ __launch_bounds__(512, 1) void gru_persistent(
    const float* __restrict__ xg_f, const float* __restrict__ xg_b,
    const __half* __restrict__ whh16_f, const __half* __restrict__ whh16_b,
    fpp bhh_f, fpp bhh_b, __half* __restrict__ seq)
{
  const int dir  = blockIdx.x & 1;
  const int tile = blockIdx.x >> 1;
  const int bm   = tile * 16;
  const float* __restrict__ xg = dir ? xg_b : xg_f;
  const __half* __restrict__ Whh = dir ? whh16_b : whh16_f;
  fpp bhh = dir ? bhh_b : bhh_f;
  const int dcol = dir * NH;
  const int tid = threadIdx.x;
  const int wave = tid >> 6, lane = tid & 63;
  const int lm = lane & 15, quad = lane >> 4;
  const int n0 = wave * 32;

  __shared__ __half h16[16 * 264];     // 16 rows x 256 (stride 264) = 8.4 KB

  // ---- B fragment base pointers (per gate g, col-tile c) ----
  const __half* bp[3][2];
#pragma unroll
  for (int g = 0; g < 3; g++)
#pragma unroll
    for (int c = 0; c < 2; c++)
      bp[g][c] = Whh + (size_t)(g * NH + n0 + c * 16 + lm) * NH + quad * 8;

  // ---- resident B frags kb 0..5 (144 VGPRs) ----
  half8 breg[3][2][6];
#pragma unroll
  for (int g = 0; g < 3; g++)
#pragma unroll
    for (int c = 0; c < 2; c++)
#pragma unroll
      for (int kb = 0; kb < 6; kb++)
        breg[g][c][kb] = *(const half8*)(bp[g][c] + kb * 32);

  // ---- xg + biases in registers (time-invariant) ----
  float xr_[2][4], xz_[2][4], xn_[2][4];
  float br_[2], bz_[2], bn_[2];
#pragma unroll
  for (int c = 0; c < 2; c++) {
    int n = n0 + c * 16 + lm;
    br_[c] = bhh[n]; bz_[c] = bhh[NH + n]; bn_[c] = bhh[2 * NH + n];
#pragma unroll
    for (int r = 0; r < 4; r++) {
      int m = bm + quad * 4 + r;
      const float* xp = xg + (size_t)m * NG + n;
      xr_[c][r] = xp[0];
      xz_[c][r] = xp[NH];
      xn_[c][r] = xp[2 * NH];
    }
  }

  float hp[2][4];
#pragma unroll
  for (int c = 0; c < 2; c++)
#pragma unroll
    for (int r = 0; r < 4; r++) hp[c][r] = 0.f;

  const int arow = lm * 264 + quad * 8;
  const int cm = tid >> 5, cpart = tid & 31;   // seq-copy coords

  for (int step = 0; step < NT; step++) {
    floatx4 acc[3][2];
#pragma unroll
    for (int g = 0; g < 3; g++)
#pragma unroll
      for (int c = 0; c < 2; c++) acc[g][c] = (floatx4){0.f, 0.f, 0.f, 0.f};

    if (step > 0) {
      // ---- issue seq store for step-1 (drain hidden behind K-loop) ----
      {
        const int t_prev = dir ? (NT - step) : (step - 1);
        float4 v = *(const float4*)&h16[cm * 264 + cpart * 8];
        *(float4*)&seq[((size_t)(bm + cm) * NT + t_prev) * ND + dcol + cpart * 8] = v;
      }
      // early prefetch of streamed kb6/kb7 frags
      half8 b6[3][2], b7[3][2];
#pragma unroll
      for (int g = 0; g < 3; g++)
#pragma unroll
        for (int c = 0; c < 2; c++) {
          b6[g][c] = *(const half8*)(bp[g][c] + 192);
          b7[g][c] = *(const half8*)(bp[g][c] + 224);
        }
#pragma unroll
      for (int kb = 0; kb < 6; kb++) {
        half8 a = *(const half8*)&h16[arow + kb * 32];
#pragma unroll
        for (int g = 0; g < 3; g++)
#pragma unroll
          for (int c = 0; c < 2; c++)
            acc[g][c] = __builtin_amdgcn_mfma_f32_16x16x32_f16(a, breg[g][c][kb], acc[g][c], 0, 0, 0);
      }
      {
        half8 a = *(const half8*)&h16[arow + 192];
#pragma unroll
        for (int g = 0; g < 3; g++)
#pragma unroll
          for (int c = 0; c < 2; c++)
            acc[g][c] = __builtin_amdgcn_mfma_f32_16x16x32_f16(a, b6[g][c], acc[g][c], 0, 0, 0);
      }
      {
        half8 a = *(const half8*)&h16[arow + 224];
#pragma unroll
        for (int g = 0; g < 3; g++)
#pragma unroll
          for (int c = 0; c < 2; c++)
            acc[g][c] = __builtin_amdgcn_mfma_f32_16x16x32_f16(a, b7[g][c], acc[g][c], 0, 0, 0);
      }
      __syncthreads();  // barrier A: h16 reads (copy + a-frags) done
    }

    // ---- epilogue: gates + state update (operands in registers) ----
#pragma unroll
    for (int c = 0; c < 2; c++) {
      int n = n0 + c * 16 + lm;
#pragma unroll
      for (int r = 0; r < 4; r++) {
        int m = quad * 4 + r;
        float rg = fast_sig(xr_[c][r] + acc[0][c][r] + br_[c]);
        float zg = fast_sig(xz_[c][r] + acc[1][c][r] + bz_[c]);
        float nn = fast_tanh(xn_[c][r] + rg * (acc[2][c][r] + bn_[c]));
        float hv = (1.f - zg) * nn + zg * hp[c][r];
        hp[c][r] = hv;
        h16[m * 264 + n] = __float2half(hv);
      }
    }
    __syncthreads();  // barrier B: h16 visible for next step
  }

  // ---- final step's seq store ----
  {
    const int t_last = dir ? 0 : (NT - 1);
    float4 v = *(const float4*)&h16[cm * 264 + cpart * 8];
    *(float4*)&seq[((size_t)(bm + cm) * NT + t_last) * ND + dcol + cpart * 8] = v;
  }
}

// ---------------------------------------------------------------------------
// Attention scores via MFMA, M=128 rows/block, single pass, no atomics.
// ---------------------------------------------------------------------------
__global__ __launch_bounds__(256) void attn_score_mfma(
    const __half* __restrict__ seq, const __half* __restrict__ w116,
    fpp b1, fpp W2, float* __restrict__ scores)
{
  const int bm = blockIdx.x * 128;
  const int tid = threadIdx.x;
  const int wave = tid >> 6, lane = tid & 63;
  const int lm = lane & 15, quad = lane >> 4;

  __shared__ __half As[128 * 40];
  __shared__ __half Bs[256 * 40];

  floatx4 acc[2][16];
#pragma unroll
  for (int mt = 0; mt < 2; mt++)
#pragma unroll
    for (int nt = 0; nt < 16; nt++) acc[mt][nt] = (floatx4){0.f, 0.f, 0.f, 0.f};

  for (int k0 = 0; k0 < ND; k0 += 32) {
    __syncthreads();
#pragma unroll
    for (int i = 0; i < 2; i++) {
      int e = tid + i * 256;
      int row = e >> 2, kc = e & 3;
      *(float4*)&As[row * 40 + kc * 8] =
        *(const float4*)&seq[(size_t)(bm + row) * ND + k0 + kc * 8];
    }
#pragma unroll
    for (int i = 0; i < 4; i++) {
      int e = tid + i * 256;
      int row = e >> 2, kc = e & 3;
      *(float4*)&Bs[row * 40 + kc * 8] =
        *(const float4*)&w116[(size_t)row * ND + k0 + kc * 8];
    }
    __syncthreads();
    half8 a0 = *(const half8*)&As[((wave * 2 + 0) * 16 + lm) * 40 + quad * 8];
    half8 a1 = *(const half8*)&As[((wave * 2 + 1) * 16 + lm) * 40 + quad * 8];
#pragma unroll
    for (int nt = 0; nt < 16; nt++) {
      half8 bf = *(const half8*)&Bs[(nt * 16 + lm) * 40 + quad * 8];
      acc[0][nt] = __builtin_amdgcn_mfma_f32_16x16x32_f16(a0, bf, acc[0][nt], 0, 0, 0);
      acc[1][nt] = __builtin_amdgcn_mfma_f32_16x16x32_f16(a1, bf, acc[1][nt], 0, 0, 0);
    }
  }

  float rs[2][4] = {};
#pragma unroll
  for (int nt = 0; nt < 16; nt++) {
    int n = nt * 16 + lm;
    float b1v = b1[n], w2v = W2[n];
#pragma unroll
    for (int mt = 0; mt < 2; mt++)
#pragma unroll
      for (int r = 0; r < 4; r++)
        rs[mt][r] += fast_tanh(acc[mt][nt][r] + b1v) * w2v;
  }
#pragma unroll
  for (int mt = 0; mt < 2; mt++)
#pragma unroll
    for (int r = 0; r < 4; r++) {
      rs[mt][r] += __shfl_xor(rs[mt][r], 1);
      rs[mt][r] += __shfl_xor(rs[mt][r], 2);
      rs[mt][r] += __shfl_xor(rs[mt][r], 4);
      rs[mt][r] += __shfl_xor(rs[mt][r], 8);
    }
  if (lm == 0) {
#pragma unroll
    for (int mt = 0; mt < 2; mt++)
#pragma unroll
      for (int r = 0; r < 4; r++)
        scores[bm + (wave * 2 + mt) * 16 + quad * 4 + r] = rs[mt][r];
  }
}

__global__ void softmax_t(float* __restrict__ s)
{
  int b = blockIdx.x, lane = threadIdx.x;
  float v = (lane < NT) ? s[(size_t)b * NT + lane] : -1e30f;
  float m = v;
#pragma unroll
  for (int off = 32; off >= 1; off >>= 1) m = fmaxf(m, __shfl_xor(m, off));
  float e = (lane < NT) ? __expf(v - m) : 0.f;
  float sum = e;
#pragma unroll
  for (int off = 32; off >= 1; off >>= 1) sum += __shfl_xor(sum, off);
  if (lane < NT) s[(size_t)b * NT + lane] = e / sum;
}

// ---------------------------------------------------------------------------
// FUSED context + joints projection + FK. One block per batch row b.
// seq[b] staged ONCE into LDS (60 KB); c computed in-block; 60 FKs from LDS.
// ---------------------------------------------------------------------------
__constant__ float c_lower[6] = {-3.1416f, -1.5708f, -3.1416f, -2.6f, -1.5708f, -1.2f};
__constant__ float c_upper[6] = { 3.1416f,  1.5708f,  3.1416f,  0.1f,  1.5708f,  1.2f};

__global__ __launch_bounds__(256) void ctx_joints_fk(
    const __half* __restrict__ seq, const float* __restrict__ wsm,
    fpp jW, fpp jb, float* __restrict__ out)
{
  const int b = blockIdx.x;
  const int tid = threadIdx.x;

  __shared__ __half sq[NT * ND];     // 60 KB
  __shared__ float  wj[6 * ND];      // 12 KB
  __shared__ float  cs[ND];          // 2 KB
  __shared__ float  wt[NT];

  // stage seq[b] (3840 float4) + jW + softmax weights
  {
    const float4* src = (const float4*)(seq + (size_t)b * NT * ND);
#pragma unroll
    for (int i = 0; i < 15; i++) {
      int ch = tid + i * 256;
      *(float4*)&sq[ch * 8] = src[ch];
    }
#pragma unroll
    for (int i = 0; i < 12; i++) wj[tid + i * 256] = jW[tid + i * 256];
    if (tid < NT) wt[tid] = wsm[(size_t)b * NT + tid];
  }
  __syncthreads();

  // context: 2 cols per thread
  {
    float s0 = 0.f, s1 = 0.f;
    for (int t = 0; t < NT; t++) {
      float w = wt[t];
      s0 += w * (float)sq[t * ND + tid * 2];
      s1 += w * (float)sq[t * ND + tid * 2 + 1];
    }
    cs[tid * 2] = s0;
    cs[tid * 2 + 1] = s1;
  }
  __syncthreads();

  const int wave = tid >> 6, lane = tid & 63;
  const int d0 = lane * 8;

  for (int it = 0; it < 15; it++) {
    const int t = it * 4 + wave;

    half8 hv = *(const half8*)&sq[t * ND + d0];
    float xv[8];
#pragma unroll
    for (int i = 0; i < 8; i++)
      xv[i] = (float)hv[i] + cs[d0 + i];

    float jnt[6];
#pragma unroll
    for (int j = 0; j < 6; j++) {
      float p = 0.f;
#pragma unroll
      for (int i = 0; i < 8; i++) p = fmaf(xv[i], wj[j * ND + d0 + i], p);
#pragma unroll
      for (int off = 32; off >= 1; off >>= 1) p += __shfl_xor(p, off);
      jnt[j] = p + jb[j];
    }

    float th[6];
#pragma unroll
    for (int j = 0; j < 6; j++)
      th[j] = jnt[j] * (c_upper[j] - c_lower[j]) + c_lower[j];

    float c0x = 1.f, c0y = 0.f, c0z = 0.f;
    float c1x = 0.f, c1y = 1.f, c1z = 0.f;
    float c2x = 0.f, c2y = 0.f, c2z = 1.f;
    float px = 0.f, py = 0.f, pz = 0.1f;
    float s, cc, tx_, ty_, tz_, ux_, uy_, uz_;

    // rotZ(th0)
    s = sinf(th[0]); cc = cosf(th[0]);
    tx_ = cc * c0x + s * c1x; ty_ = cc * c0y + s * c1y; tz_ = cc * c0z + s * c1z;
    ux_ = -s * c0x + cc * c1x; uy_ = -s * c0y + cc * c1y; uz_ = -s * c0z + cc * c1z;
    c0x = tx_; c0y = ty_; c0z = tz_; c1x = ux_; c1y = uy_; c1z = uz_;

    float shx = px, shy = py, shz = pz;  // shoulder2
    // rotX(th1)
    s = sinf(th[1]); cc = cosf(th[1]);
    tx_ = cc * c1x + s * c2x; ty_ = cc * c1y + s * c2y; tz_ = cc * c1z + s * c2z;
    ux_ = -s * c1x + cc * c2x; uy_ = -s * c1y + cc * c2y; uz_ = -s * c1z + cc * c2z;
    c1x = tx_; c1y = ty_; c1z = tz_; c2x = ux_; c2y = uy_; c2z = uz_;

    // rotY(th2)
    s = sinf(th[2]); cc = cosf(th[2]);
    tx_ = cc * c0x - s * c2x; ty_ = cc * c0y - s * c2y; tz_ = cc * c0z - s * c2z;
    ux_ = s * c0x + cc * c2x; uy_ = s * c0y + cc * c2y; uz_ = s * c0z + cc * c2z;
    c0x = tx_; c0y = ty_; c0z = tz_; c2x = ux_; c2y = uy_; c2z = uz_;

    // joint3 offset -> forearm
    px -= 0.25f * c1x; py -= 0.25f * c1y; pz -= 0.25f * c1z;
    float fox = px, foy = py, foz = pz;
    // rotX(th3)
    s = sinf(th[3]); cc = cosf(th[3]);
    tx_ = cc * c1x + s * c2x; ty_ = cc * c1y + s * c2y; tz_ = cc * c1z + s * c2z;
    ux_ = -s * c1x + cc * c2x; uy_ = -s * c1y + cc * c2y; uz_ = -s * c1z + cc * c2z;
    c1x = tx_; c1y = ty_; c1z = tz_; c2x = ux_; c2y = uy_; c2z = uz_;

    // rotY(th4)
    s = sinf(th[4]); cc = cosf(th[4]);
    tx_ = cc * c0x - s * c2x; ty_ = cc * c0y - s * c2y; tz_ = cc * c0z - s * c2z;
    ux_ = s * c0x + cc * c2x; uy_ = s * c0y + cc * c2y; uz_ = s * c0z + cc * c2z;
    c0x = tx_; c0y = ty_; c0z = tz_; c2x = ux_; c2y = uy_; c2z = uz_;

    // joint5 offset -> wrist
    px -= 0.25f * c1x; py -= 0.25f * c1y; pz -= 0.25f * c1z;
    float wx = px, wy = py, wz = pz;
    // rotX(th5)
    s = sinf(th[5]); cc = cosf(th[5]);
    tx_ = cc * c1x + s * c2x; ty_ = cc * c1y + s * c2y; tz_ = cc * c1z + s * c2z;
    ux_ = -s * c1x + cc * c2x; uy_ = -s * c1y + cc * c2y; uz_ = -s * c1z + cc * c2z;
    c1x = tx_; c1y = ty_; c1z = tz_; c2x = ux_; c2y = uy_; c2z = uz_;

    float f1x = wx - 0.08f * c1x + 0.02f * c2x;
    float f1y = wy - 0.08f * c1y + 0.02f * c2y;
    float f1z = wz - 0.08f * c1z + 0.02f * c2z;
    float f4x = wx - 0.08f * c1x - 0.02f * c2x;
    float f4y = wy - 0.08f * c1y - 0.02f * c2y;
    float f4z = wz - 0.08f * c1z - 0.02f * c2z;

    float dsx = shx - fox, dsy = shy - foy, dsz = shz - foz;
    float dwx = wx - fox, dwy = wy - foy, dwz = wz - foz;
    float bodyL = 0.5f * (sqrtf(dsx * dsx + dsy * dsy + dsz * dsz) +
                          sqrtf(dwx * dwx + dwy * dwy + dwz * dwz));
    float inv = 1.f / bodyL;

    float rel[9];
    rel[0] = (wx - shx) * inv; rel[1] = (wy - shy) * inv; rel[2] = (wz - shz) * inv;
    rel[3] = (f1x - shx) * inv; rel[4] = (f1y - shy) * inv; rel[5] = (f1z - shz) * inv;
    rel[6] = (f4x - shx) * inv; rel[7] = (f4y - shy) * inv; rel[8] = (f4z - shz) * inv;

    if (lane < 9) out[((size_t)b * NT + t) * 9 + lane] = rel[lane];
  }
}

// ---------------------------------------------------------------------------
extern "C" void kernel_launch(void* const* d_in, const int* in_sizes, int n_in,
                              void* d_out, int out_size, void* d_ws, size_t ws_size,
                              hipStream_t stream)
{
  fpp z     = (fpp)d_in[0];
  fpp W_fc  = (fpp)d_in[1];
  fpp b_fc  = (fpp)d_in[2];
  fpp bn_g  = (fpp)d_in[3];
  fpp bn_b  = (fpp)d_in[4];
  fpp Wih_f = (fpp)d_in[5];
  fpp Whh_f = (fpp)d_in[6];
  fpp bih_f = (fpp)d_in[7];
  fpp bhh_f = (fpp)d_in[8];
  fpp Wih_b = (fpp)d_in[9];
  fpp Whh_b = (fpp)d_in[10];
  fpp bih_b = (fpp)d_in[11];
  fpp bhh_b = (fpp)d_in[12];
  fpp aW1   = (fpp)d_in[13];
  fpp ab1   = (fpp)d_in[14];
  fpp aW2   = (fpp)d_in[15];
  fpp jW    = (fpp)d_in[16];
  fpp jb    = (fpp)d_in[17];

  float* ws     = (float*)d_ws;
  float* h0     = ws;                        // 2048*512 fp32
  float* xg_f   = h0 + 1048576;              // 2048*768 fp32
  float* xg_b   = xg_f + 1572864;            // 2048*768 fp32
  float* bns1   = xg_b + 1572864;            // 512
  float* bns2   = bns1 + 512;                // 512
  float* scores = bns2 + 512;                // 2048*60
  float* cbuf   = scores + 122880;           // 2048*512 (unused, layout keep)
  __half* gseq    = (__half*)(cbuf + 1048576);   // 2048*60*512 fp16 (126 MB)
  __half* whh16_f = gseq + 62914560;             // 768*256
  __half* whh16_b = whh16_f + 196608;            // 768*256
  __half* w116    = whh16_b + 196608;            // 256*512
  __half* wih16_f = w116 + 131072;               // 768*512
  __half* wih16_b = wih16_f + 393216;            // 768*512
  __half* h16g    = wih16_b + 393216;            // 2048*512

  // 0. weight conversions fp32->fp16 + BN accumulator zero
  convert_w<<<5120, 256, 0, stream>>>(Whh_f, Whh_b, aW1, Wih_f, Wih_b,
                                      whh16_f, whh16_b, w116, wih16_f, wih16_b);
  hipMemsetAsync(bns1, 0, 1024 * sizeof(float), stream);
  // 1. fc: h0 = z @ W_fc^T + b_fc (fp32, K=100)
  gemm_fc<<<dim3(32, 8), 256, 0, stream>>>(z, W_fc, b_fc, h0,
                                           NB, ND, NDL, NDL, NDL, ND);
  // 2. batchnorm (training stats, parallel partials) + leaky relu -> fp16 h
  bn_partial<<<64, 256, 0, stream>>>(h0, bns1, bns2);
  bn_lrelu_h16<<<4096, 256, 0, stream>>>(h0, bn_g, bn_b, bns1, bns2, h16g);
  // 3. time-invariant input projections via MFMA (computed ONCE)
  gemm16<<<dim3(32, 12), 256, 0, stream>>>(h16g, wih16_f, bih_f, xg_f, NG, ND);
  gemm16<<<dim3(32, 12), 256, 0, stream>>>(h16g, wih16_b, bih_b, xg_b, NG, ND);
  // 4. ENTIRE GRU recurrence: one persistent launch, 8 waves/block
  gru_persistent<<<256, 512, 0, stream>>>(xg_f, xg_b, whh16_f, whh16_b,
                                          bhh_f, bhh_b, gseq);
  // 5. attention scores + softmax
  attn_score_mfma<<<960, 256, 0, stream>>>(gseq, w116, ab1, aW2, scores);
  softmax_t<<<NB, 64, 0, stream>>>(scores);
  // 6. fused context + joints projection + FK (one gseq pass)
  ctx_joints_fk<<<NB, 256, 0, stream>>>(gseq, scores, jW, jb, (float*)d_out);
}

// Round 13
// 584.445 us; speedup vs baseline: 2.2882x; 1.0773x over previous
//
#include <hip/hip_runtime.h>
#include <hip/hip_fp16.h>

#define NB 2048
#define NT 60
#define NDL 100
#define ND 512
#define NH 256
#define NG 768

typedef const float* __restrict__ fpp;
typedef _Float16 half8 __attribute__((ext_vector_type(8)));
typedef float floatx4 __attribute__((ext_vector_type(4)));

__device__ __forceinline__ float fast_sig(float x) {
  return 1.f / (1.f + __expf(-x));
}
__device__ __forceinline__ float fast_tanh(float x) {
  float t = __expf(2.f * x);
  return (t - 1.f) / (t + 1.f);
}

// ---------------------------------------------------------------------------
// fp32 tiled GEMM (fc layer only, K=100): C = A*B^T + bias
// ---------------------------------------------------------------------------
__global__ __launch_bounds__(256) void gemm_fc(
    fpp A, fpp Bm, fpp bias, float* __restrict__ C,
    int M, int N, int K, int lda, int ldb, int ldc)
{
  __shared__ float As[16][68];
  __shared__ float Bs[16][68];
  const int bm = blockIdx.x * 64, bn = blockIdx.y * 64;
  const int tid = threadIdx.x;
  const int tx = tid & 15, ty = tid >> 4;
  float acc[4][4] = {};
  for (int k0 = 0; k0 < K; k0 += 16) {
#pragma unroll
    for (int i = 0; i < 4; i++) {
      int e = tid + i * 256;
      int m = e >> 4, k = e & 15;
      As[k][m] = (k0 + k < K) ? A[(size_t)(bm + m) * lda + k0 + k] : 0.f;
      Bs[k][m] = (k0 + k < K) ? Bm[(size_t)(bn + m) * ldb + k0 + k] : 0.f;
    }
    __syncthreads();
#pragma unroll
    for (int kk = 0; kk < 16; kk++) {
      float4 av = *(const float4*)&As[kk][ty * 4];
      float4 bv = *(const float4*)&Bs[kk][tx * 4];
      float a_[4] = {av.x, av.y, av.z, av.w};
      float b_[4] = {bv.x, bv.y, bv.z, bv.w};
#pragma unroll
      for (int i = 0; i < 4; i++)
#pragma unroll
        for (int j = 0; j < 4; j++)
          acc[i][j] = fmaf(a_[i], b_[j], acc[i][j]);
    }
    __syncthreads();
  }
#pragma unroll
  for (int i = 0; i < 4; i++) {
    int m = bm + ty * 4 + i;
#pragma unroll
    for (int j = 0; j < 4; j++) {
      int n = bn + tx * 4 + j;
      C[(size_t)m * ldc + n] = acc[i][j] + bias[n];
    }
  }
}

// ---------------------------------------------------------------------------
// BN partial sums: 64 blocks x 32 rows, coalesced, atomicAdd into s1/s2[512].
// ---------------------------------------------------------------------------
__global__ __launch_bounds__(256) void bn_partial(
    const float* __restrict__ h0, float* __restrict__ s1g,
    float* __restrict__ s2g)
{
  const int r0 = blockIdx.x * 32;
  const int tid = threadIdx.x;
  float a1 = 0.f, a2 = 0.f, b1 = 0.f, b2 = 0.f;
  for (int r = 0; r < 32; r++) {
    float v = h0[(size_t)(r0 + r) * ND + tid];
    float w = h0[(size_t)(r0 + r) * ND + tid + 256];
    a1 += v; a2 += v * v;
    b1 += w; b2 += w * w;
  }
  atomicAdd(&s1g[tid], a1);
  atomicAdd(&s2g[tid], a2);
  atomicAdd(&s1g[tid + 256], b1);
  atomicAdd(&s2g[tid + 256], b2);
}

// bn (stats from s1/s2) + leaky relu, writing fp16
__global__ void bn_lrelu_h16(const float* __restrict__ h0,
                             fpp g, fpp b,
                             const float* __restrict__ s1g,
                             const float* __restrict__ s2g,
                             __half* __restrict__ h16g)
{
  int idx = blockIdx.x * 256 + threadIdx.x;
  int d = idx & (ND - 1);
  float mu = s1g[d] * (1.f / NB);
  float var = s2g[d] * (1.f / NB) - mu * mu;
  float sc = g[d] * rsqrtf(var + 1e-5f);
  float sh = b[d] - mu * sc;
  float v = h0[idx] * sc + sh;
  h16g[idx] = __float2half(v >= 0.f ? v : 0.2f * v);
}

// ---------------------------------------------------------------------------
// One-time weight conversions fp32 -> fp16
// ---------------------------------------------------------------------------
__global__ void convert_w(fpp whf, fpp whb, fpp w1, fpp wif, fpp wib,
                          __half* __restrict__ o_whf, __half* __restrict__ o_whb,
                          __half* __restrict__ o_w1, __half* __restrict__ o_wif,
                          __half* __restrict__ o_wib)
{
  int idx = blockIdx.x * 256 + threadIdx.x;  // 0 .. 1310719
  if (idx < 196608) o_whf[idx] = __float2half(whf[idx]);
  else if (idx < 393216) o_whb[idx - 196608] = __float2half(whb[idx - 196608]);
  else if (idx < 524288) o_w1[idx - 393216] = __float2half(w1[idx - 393216]);
  else if (idx < 917504) o_wif[idx - 524288] = __float2half(wif[idx - 524288]);
  else o_wib[idx - 917504] = __float2half(wib[idx - 917504]);
}

// ---------------------------------------------------------------------------
// fp16 MFMA GEMM (xg projections): C[m][n] = A[m][:]·B[n][:] + bias[n]
// ---------------------------------------------------------------------------
__global__ __launch_bounds__(256) void gemm16(
    const __half* __restrict__ A, const __half* __restrict__ Bm,
    fpp bias, float* __restrict__ C, int N, int K)
{
  __shared__ __half As[64 * 40];
  __shared__ __half Bs[64 * 40];
  const int bm = blockIdx.x * 64, bn = blockIdx.y * 64;
  const int tid = threadIdx.x;
  const int wave = tid >> 6, lane = tid & 63;
  const int lm = lane & 15, quad = lane >> 4;
  floatx4 acc[4];
#pragma unroll
  for (int nt = 0; nt < 4; nt++) acc[nt] = (floatx4){0.f, 0.f, 0.f, 0.f};

  const int row = tid >> 2, kc = tid & 3;
  for (int k0 = 0; k0 < K; k0 += 32) {
    __syncthreads();
    *(float4*)&As[row * 40 + kc * 8] =
      *(const float4*)&A[(size_t)(bm + row) * K + k0 + kc * 8];
    *(float4*)&Bs[row * 40 + kc * 8] =
      *(const float4*)&Bm[(size_t)(bn + row) * K + k0 + kc * 8];
    __syncthreads();
    half8 af = *(const half8*)&As[(wave * 16 + lm) * 40 + quad * 8];
#pragma unroll
    for (int nt = 0; nt < 4; nt++) {
      half8 bf = *(const half8*)&Bs[(nt * 16 + lm) * 40 + quad * 8];
      acc[nt] = __builtin_amdgcn_mfma_f32_16x16x32_f16(af, bf, acc[nt], 0, 0, 0);
    }
  }
#pragma unroll
  for (int nt = 0; nt < 4; nt++) {
    int n = bn + nt * 16 + lm;
    float bv = bias[n];
#pragma unroll
    for (int r = 0; r < 4; r++) {
      int m = bm + wave * 16 + quad * 4 + r;
      C[(size_t)m * N + n] = acc[nt][r] + bv;
    }
  }
}

// ---------------------------------------------------------------------------
// PERSISTENT GRU, 512 threads (8 waves, 2 waves/SIMD), launch_bounds(512,2)
// -> 256-VGPR cap. B frags kb0..5 pinned in registers via asm-opacity (the
// compiler was rematerializing them as L2 loads every step -> 393 KB/step/CU
// L2 stream, the r12 bottleneck). kb6/7 streamed with early prefetch.
// xg + biases in registers. h-state fp16 in LDS + fp32 hp regs. seq store
// for step s-1 issued at top of step s (drain hidden behind K-loop).
// ---------------------------------------------------------------------------
__global__ __launch_bounds__(512, 2) void gru_persistent(
    const float* __restrict__ xg_f, const float* __restrict__ xg_b,
    const __half* __restrict__ whh16_f, const __half* __restrict__ whh16_b,
    fpp bhh_f, fpp bhh_b, __half* __restrict__ seq)
{
  const int dir  = blockIdx.x & 1;
  const int tile = blockIdx.x >> 1;
  const int bm   = tile * 16;
  const float* __restrict__ xg = dir ? xg_b : xg_f;
  const __half* __restrict__ Whh = dir ? whh16_b : whh16_f;
  fpp bhh = dir ? bhh_b : bhh_f;
  const int dcol = dir * NH;
  const int tid = threadIdx.x;
  const int wave = tid >> 6, lane = tid & 63;
  const int lm = lane & 15, quad = lane >> 4;
  const int n0 = wave * 32;

  __shared__ __half h16[16 * 264];     // 16 rows x 256 (stride 264) = 8.4 KB

  // ---- B fragment base pointers (per gate g, col-tile c) ----
  const __half* bp[3][2];
#pragma unroll
  for (int g = 0; g < 3; g++)
#pragma unroll
    for (int c = 0; c < 2; c++)
      bp[g][c] = Whh + (size_t)(g * NH + n0 + c * 16 + lm) * NH + quad * 8;

  // ---- resident B frags kb 0..5 (144 VGPRs), PINNED via asm opacity ----
  floatx4 breg[3][2][6];
#pragma unroll
  for (int g = 0; g < 3; g++)
#pragma unroll
    for (int c = 0; c < 2; c++)
#pragma unroll
      for (int kb = 0; kb < 6; kb++)
        breg[g][c][kb] = *(const floatx4*)(bp[g][c] + kb * 32);
#pragma unroll
  for (int g = 0; g < 3; g++)
#pragma unroll
    for (int c = 0; c < 2; c++)
#pragma unroll
      for (int kb = 0; kb < 6; kb++)
        asm volatile("" : "+v"(breg[g][c][kb]));  // block rematerialization

  // ---- xg + biases in registers (time-invariant) ----
  float xr_[2][4], xz_[2][4], xn_[2][4];
  float br_[2], bz_[2], bn_[2];
#pragma unroll
  for (int c = 0; c < 2; c++) {
    int n = n0 + c * 16 + lm;
    br_[c] = bhh[n]; bz_[c] = bhh[NH + n]; bn_[c] = bhh[2 * NH + n];
#pragma unroll
    for (int r = 0; r < 4; r++) {
      int m = bm + quad * 4 + r;
      const float* xp = xg + (size_t)m * NG + n;
      xr_[c][r] = xp[0];
      xz_[c][r] = xp[NH];
      xn_[c][r] = xp[2 * NH];
    }
  }

  float hp[2][4];
#pragma unroll
  for (int c = 0; c < 2; c++)
#pragma unroll
    for (int r = 0; r < 4; r++) hp[c][r] = 0.f;

  const int arow = lm * 264 + quad * 8;
  const int cm = tid >> 5, cpart = tid & 31;   // seq-copy coords

  for (int step = 0; step < NT; step++) {
    floatx4 acc[3][2];
#pragma unroll
    for (int g = 0; g < 3; g++)
#pragma unroll
      for (int c = 0; c < 2; c++) acc[g][c] = (floatx4){0.f, 0.f, 0.f, 0.f};

    if (step > 0) {
      // ---- issue seq store for step-1 (drain hidden behind K-loop) ----
      {
        const int t_prev = dir ? (NT - step) : (step - 1);
        float4 v = *(const float4*)&h16[cm * 264 + cpart * 8];
        *(float4*)&seq[((size_t)(bm + cm) * NT + t_prev) * ND + dcol + cpart * 8] = v;
      }
      // early prefetch of streamed kb6/kb7 frags
      half8 b6[3][2], b7[3][2];
#pragma unroll
      for (int g = 0; g < 3; g++)
#pragma unroll
        for (int c = 0; c < 2; c++) {
          b6[g][c] = *(const half8*)(bp[g][c] + 192);
          b7[g][c] = *(const half8*)(bp[g][c] + 224);
        }
#pragma unroll
      for (int kb = 0; kb < 6; kb++) {
        half8 a = *(const half8*)&h16[arow + kb * 32];
#pragma unroll
        for (int g = 0; g < 3; g++)
#pragma unroll
          for (int c = 0; c < 2; c++)
            acc[g][c] = __builtin_amdgcn_mfma_f32_16x16x32_f16(
                a, __builtin_bit_cast(half8, breg[g][c][kb]), acc[g][c], 0, 0, 0);
      }
      {
        half8 a = *(const half8*)&h16[arow + 192];
#pragma unroll
        for (int g = 0; g < 3; g++)
#pragma unroll
          for (int c = 0; c < 2; c++)
            acc[g][c] = __builtin_amdgcn_mfma_f32_16x16x32_f16(a, b6[g][c], acc[g][c], 0, 0, 0);
      }
      {
        half8 a = *(const half8*)&h16[arow + 224];
#pragma unroll
        for (int g = 0; g < 3; g++)
#pragma unroll
          for (int c = 0; c < 2; c++)
            acc[g][c] = __builtin_amdgcn_mfma_f32_16x16x32_f16(a, b7[g][c], acc[g][c], 0, 0, 0);
      }
      __syncthreads();  // barrier A: h16 reads (copy + a-frags) done
    }

    // ---- epilogue: gates + state update (operands in registers) ----
#pragma unroll
    for (int c = 0; c < 2; c++) {
      int n = n0 + c * 16 + lm;
#pragma unroll
      for (int r = 0; r < 4; r++) {
        int m = quad * 4 + r;
        float rg = fast_sig(xr_[c][r] + acc[0][c][r] + br_[c]);
        float zg = fast_sig(xz_[c][r] + acc[1][c][r] + bz_[c]);
        float nn = fast_tanh(xn_[c][r] + rg * (acc[2][c][r] + bn_[c]));
        float hv = (1.f - zg) * nn + zg * hp[c][r];
        hp[c][r] = hv;
        h16[m * 264 + n] = __float2half(hv);
      }
    }
    __syncthreads();  // barrier B: h16 visible for next step
  }

  // ---- final step's seq store ----
  {
    const int t_last = dir ? 0 : (NT - 1);
    float4 v = *(const float4*)&h16[cm * 264 + cpart * 8];
    *(float4*)&seq[((size_t)(bm + cm) * NT + t_last) * ND + dcol + cpart * 8] = v;
  }
}

// ---------------------------------------------------------------------------
// Attention scores via MFMA, M=128 rows/block, single pass, no atomics.
// ---------------------------------------------------------------------------
__global__ __launch_bounds__(256) void attn_score_mfma(
    const __half* __restrict__ seq, const __half* __restrict__ w116,
    fpp b1, fpp W2, float* __restrict__ scores)
{
  const int bm = blockIdx.x * 128;
  const int tid = threadIdx.x;
  const int wave = tid >> 6, lane = tid & 63;
  const int lm = lane & 15, quad = lane >> 4;

  __shared__ __half As[128 * 40];
  __shared__ __half Bs[256 * 40];

  floatx4 acc[2][16];
#pragma unroll
  for (int mt = 0; mt < 2; mt++)
#pragma unroll
    for (int nt = 0; nt < 16; nt++) acc[mt][nt] = (floatx4){0.f, 0.f, 0.f, 0.f};

  for (int k0 = 0; k0 < ND; k0 += 32) {
    __syncthreads();
#pragma unroll
    for (int i = 0; i < 2; i++) {
      int e = tid + i * 256;
      int row = e >> 2, kc = e & 3;
      *(float4*)&As[row * 40 + kc * 8] =
        *(const float4*)&seq[(size_t)(bm + row) * ND + k0 + kc * 8];
    }
#pragma unroll
    for (int i = 0; i < 4; i++) {
      int e = tid + i * 256;
      int row = e >> 2, kc = e & 3;
      *(float4*)&Bs[row * 40 + kc * 8] =
        *(const float4*)&w116[(size_t)row * ND + k0 + kc * 8];
    }
    __syncthreads();
    half8 a0 = *(const half8*)&As[((wave * 2 + 0) * 16 + lm) * 40 + quad * 8];
    half8 a1 = *(const half8*)&As[((wave * 2 + 1) * 16 + lm) * 40 + quad * 8];
#pragma unroll
    for (int nt = 0; nt < 16; nt++) {
      half8 bf = *(const half8*)&Bs[(nt * 16 + lm) * 40 + quad * 8];
      acc[0][nt] = __builtin_amdgcn_mfma_f32_16x16x32_f16(a0, bf, acc[0][nt], 0, 0, 0);
      acc[1][nt] = __builtin_amdgcn_mfma_f32_16x16x32_f16(a1, bf, acc[1][nt], 0, 0, 0);
    }
  }

  float rs[2][4] = {};
#pragma unroll
  for (int nt = 0; nt < 16; nt++) {
    int n = nt * 16 + lm;
    float b1v = b1[n], w2v = W2[n];
#pragma unroll
    for (int mt = 0; mt < 2; mt++)
#pragma unroll
      for (int r = 0; r < 4; r++)
        rs[mt][r] += fast_tanh(acc[mt][nt][r] + b1v) * w2v;
  }
#pragma unroll
  for (int mt = 0; mt < 2; mt++)
#pragma unroll
    for (int r = 0; r < 4; r++) {
      rs[mt][r] += __shfl_xor(rs[mt][r], 1);
      rs[mt][r] += __shfl_xor(rs[mt][r], 2);
      rs[mt][r] += __shfl_xor(rs[mt][r], 4);
      rs[mt][r] += __shfl_xor(rs[mt][r], 8);
    }
  if (lm == 0) {
#pragma unroll
    for (int mt = 0; mt < 2; mt++)
#pragma unroll
      for (int r = 0; r < 4; r++)
        scores[bm + (wave * 2 + mt) * 16 + quad * 4 + r] = rs[mt][r];
  }
}

__global__ void softmax_t(float* __restrict__ s)
{
  int b = blockIdx.x, lane = threadIdx.x;
  float v = (lane < NT) ? s[(size_t)b * NT + lane] : -1e30f;
  float m = v;
#pragma unroll
  for (int off = 32; off >= 1; off >>= 1) m = fmaxf(m, __shfl_xor(m, off));
  float e = (lane < NT) ? __expf(v - m) : 0.f;
  float sum = e;
#pragma unroll
  for (int off = 32; off >= 1; off >>= 1) sum += __shfl_xor(sum, off);
  if (lane < NT) s[(size_t)b * NT + lane] = e / sum;
}

// ---------------------------------------------------------------------------
// FUSED context + joints projection + FK. One block per batch row b.
// ---------------------------------------------------------------------------
__constant__ float c_lower[6] = {-3.1416f, -1.5708f, -3.1416f, -2.6f, -1.5708f, -1.2f};
__constant__ float c_upper[6] = { 3.1416f,  1.5708f,  3.1416f,  0.1f,  1.5708f,  1.2f};

__global__ __launch_bounds__(256) void ctx_joints_fk(
    const __half* __restrict__ seq, const float* __restrict__ wsm,
    fpp jW, fpp jb, float* __restrict__ out)
{
  const int b = blockIdx.x;
  const int tid = threadIdx.x;

  __shared__ __half sq[NT * ND];     // 60 KB
  __shared__ float  wj[6 * ND];      // 12 KB
  __shared__ float  cs[ND];          // 2 KB
  __shared__ float  wt[NT];

  {
    const float4* src = (const float4*)(seq + (size_t)b * NT * ND);
#pragma unroll
    for (int i = 0; i < 15; i++) {
      int ch = tid + i * 256;
      *(float4*)&sq[ch * 8] = src[ch];
    }
#pragma unroll
    for (int i = 0; i < 12; i++) wj[tid + i * 256] = jW[tid + i * 256];
    if (tid < NT) wt[tid] = wsm[(size_t)b * NT + tid];
  }
  __syncthreads();

  {
    float s0 = 0.f, s1 = 0.f;
    for (int t = 0; t < NT; t++) {
      float w = wt[t];
      s0 += w * (float)sq[t * ND + tid * 2];
      s1 += w * (float)sq[t * ND + tid * 2 + 1];
    }
    cs[tid * 2] = s0;
    cs[tid * 2 + 1] = s1;
  }
  __syncthreads();

  const int wave = tid >> 6, lane = tid & 63;
  const int d0 = lane * 8;

  for (int it = 0; it < 15; it++) {
    const int t = it * 4 + wave;

    half8 hv = *(const half8*)&sq[t * ND + d0];
    float xv[8];
#pragma unroll
    for (int i = 0; i < 8; i++)
      xv[i] = (float)hv[i] + cs[d0 + i];

    float jnt[6];
#pragma unroll
    for (int j = 0; j < 6; j++) {
      float p = 0.f;
#pragma unroll
      for (int i = 0; i < 8; i++) p = fmaf(xv[i], wj[j * ND + d0 + i], p);
#pragma unroll
      for (int off = 32; off >= 1; off >>= 1) p += __shfl_xor(p, off);
      jnt[j] = p + jb[j];
    }

    float th[6];
#pragma unroll
    for (int j = 0; j < 6; j++)
      th[j] = jnt[j] * (c_upper[j] - c_lower[j]) + c_lower[j];

    float c0x = 1.f, c0y = 0.f, c0z = 0.f;
    float c1x = 0.f, c1y = 1.f, c1z = 0.f;
    float c2x = 0.f, c2y = 0.f, c2z = 1.f;
    float px = 0.f, py = 0.f, pz = 0.1f;
    float s, cc, tx_, ty_, tz_, ux_, uy_, uz_;

    // rotZ(th0)
    s = sinf(th[0]); cc = cosf(th[0]);
    tx_ = cc * c0x + s * c1x; ty_ = cc * c0y + s * c1y; tz_ = cc * c0z + s * c1z;
    ux_ = -s * c0x + cc * c1x; uy_ = -s * c0y + cc * c1y; uz_ = -s * c0z + cc * c1z;
    c0x = tx_; c0y = ty_; c0z = tz_; c1x = ux_; c1y = uy_; c1z = uz_;

    float shx = px, shy = py, shz = pz;  // shoulder2
    // rotX(th1)
    s = sinf(th[1]); cc = cosf(th[1]);
    tx_ = cc * c1x + s * c2x; ty_ = cc * c1y + s * c2y; tz_ = cc * c1z + s * c2z;
    ux_ = -s * c1x + cc * c2x; uy_ = -s * c1y + cc * c2y; uz_ = -s * c1z + cc * c2z;
    c1x = tx_; c1y = ty_; c1z = tz_; c2x = ux_; c2y = uy_; c2z = uz_;

    // rotY(th2)
    s = sinf(th[2]); cc = cosf(th[2]);
    tx_ = cc * c0x - s * c2x; ty_ = cc * c0y - s * c2y; tz_ = cc * c0z - s * c2z;
    ux_ = s * c0x + cc * c2x; uy_ = s * c0y + cc * c2y; uz_ = s * c0z + cc * c2z;
    c0x = tx_; c0y = ty_; c0z = tz_; c2x = ux_; c2y = uy_; c2z = uz_;

    // joint3 offset -> forearm
    px -= 0.25f * c1x; py -= 0.25f * c1y; pz -= 0.25f * c1z;
    float fox = px, foy = py, foz = pz;
    // rotX(th3)
    s = sinf(th[3]); cc = cosf(th[3]);
    tx_ = cc * c1x + s * c2x; ty_ = cc * c1y + s * c2y; tz_ = cc * c1z + s * c2z;
    ux_ = -s * c1x + cc * c2x; uy_ = -s * c1y + cc * c2y; uz_ = -s * c1z + cc * c2z;
    c1x = tx_; c1y = ty_; c1z = tz_; c2x = ux_; c2y = uy_; c2z = uz_;

    // rotY(th4)
    s = sinf(th[4]); cc = cosf(th[4]);
    tx_ = cc * c0x - s * c2x; ty_ = cc * c0y - s * c2y; tz_ = cc * c0z - s * c2z;
    ux_ = s * c0x + cc * c2x; uy_ = s * c0y + cc * c2y; uz_ = s * c0z + cc * c2z;
    c0x = tx_; c0y = ty_; c0z = tz_; c2x = ux_; c2y = uy_; c2z = uz_;

    // joint5 offset -> wrist
    px -= 0.25f * c1x; py -= 0.25f * c1y; pz -= 0.25f * c1z;
    float wx = px, wy = py, wz = pz;
    // rotX(th5)
    s = sinf(th[5]); cc = cosf(th[5]);
    tx_ = cc * c1x + s * c2x; ty_ = cc * c1y + s * c2y; tz_ = cc * c1z + s * c2z;
    ux_ = -s * c1x + cc * c2x; uy_ = -s * c1y + cc * c2y; uz_ = -s * c1z + cc * c2z;
    c1x = tx_; c1y = ty_; c1z = tz_; c2x = ux_; c2y = uy_; c2z = uz_;

    float f1x = wx - 0.08f * c1x + 0.02f * c2x;
    float f1y = wy - 0.08f * c1y + 0.02f * c2y;
    float f1z = wz - 0.08f * c1z + 0.02f * c2z;
    float f4x = wx - 0.08f * c1x - 0.02f * c2x;
    float f4y = wy - 0.08f * c1y - 0.02f * c2y;
    float f4z = wz - 0.08f * c1z - 0.02f * c2z;

    float dsx = shx - fox, dsy = shy - foy, dsz = shz - foz;
    float dwx = wx - fox, dwy = wy - foy, dwz = wz - foz;
    float bodyL = 0.5f * (sqrtf(dsx * dsx + dsy * dsy + dsz * dsz) +
                          sqrtf(dwx * dwx + dwy * dwy + dwz * dwz));
    float inv = 1.f / bodyL;

    float rel[9];
    rel[0] = (wx - shx) * inv; rel[1] = (wy - shy) * inv; rel[2] = (wz - shz) * inv;
    rel[3] = (f1x - shx) * inv; rel[4] = (f1y - shy) * inv; rel[5] = (f1z - shz) * inv;
    rel[6] = (f4x - shx) * inv; rel[7] = (f4y - shy) * inv; rel[8] = (f4z - shz) * inv;

    if (lane < 9) out[((size_t)b * NT + t) * 9 + lane] = rel[lane];
  }
}

// ---------------------------------------------------------------------------
extern "C" void kernel_launch(void* const* d_in, const int* in_sizes, int n_in,
                              void* d_out, int out_size, void* d_ws, size_t ws_size,
                              hipStream_t stream)
{
  fpp z     = (fpp)d_in[0];
  fpp W_fc  = (fpp)d_in[1];
  fpp b_fc  = (fpp)d_in[2];
  fpp bn_g  = (fpp)d_in[3];
  fpp bn_b  = (fpp)d_in[4];
  fpp Wih_f = (fpp)d_in[5];
  fpp Whh_f = (fpp)d_in[6];
  fpp bih_f = (fpp)d_in[7];
  fpp bhh_f = (fpp)d_in[8];
  fpp Wih_b = (fpp)d_in[9];
  fpp Whh_b = (fpp)d_in[10];
  fpp bih_b = (fpp)d_in[11];
  fpp bhh_b = (fpp)d_in[12];
  fpp aW1   = (fpp)d_in[13];
  fpp ab1   = (fpp)d_in[14];
  fpp aW2   = (fpp)d_in[15];
  fpp jW    = (fpp)d_in[16];
  fpp jb    = (fpp)d_in[17];

  float* ws     = (float*)d_ws;
  float* h0     = ws;                        // 2048*512 fp32
  float* xg_f   = h0 + 1048576;              // 2048*768 fp32
  float* xg_b   = xg_f + 1572864;            // 2048*768 fp32
  float* bns1   = xg_b + 1572864;            // 512
  float* bns2   = bns1 + 512;                // 512
  float* scores = bns2 + 512;                // 2048*60
  float* cbuf   = scores + 122880;           // 2048*512 (unused, layout keep)
  __half* gseq    = (__half*)(cbuf + 1048576);   // 2048*60*512 fp16 (126 MB)
  __half* whh16_f = gseq + 62914560;             // 768*256
  __half* whh16_b = whh16_f + 196608;            // 768*256
  __half* w116    = whh16_b + 196608;            // 256*512
  __half* wih16_f = w116 + 131072;               // 768*512
  __half* wih16_b = wih16_f + 393216;            // 768*512
  __half* h16g    = wih16_b + 393216;            // 2048*512

  // 0. weight conversions fp32->fp16 + BN accumulator zero
  convert_w<<<5120, 256, 0, stream>>>(Whh_f, Whh_b, aW1, Wih_f, Wih_b,
                                      whh16_f, whh16_b, w116, wih16_f, wih16_b);
  hipMemsetAsync(bns1, 0, 1024 * sizeof(float), stream);
  // 1. fc: h0 = z @ W_fc^T + b_fc (fp32, K=100)
  gemm_fc<<<dim3(32, 8), 256, 0, stream>>>(z, W_fc, b_fc, h0,
                                           NB, ND, NDL, NDL, NDL, ND);
  // 2. batchnorm (training stats, parallel partials) + leaky relu -> fp16 h
  bn_partial<<<64, 256, 0, stream>>>(h0, bns1, bns2);
  bn_lrelu_h16<<<4096, 256, 0, stream>>>(h0, bn_g, bn_b, bns1, bns2, h16g);
  // 3. time-invariant input projections via MFMA (computed ONCE)
  gemm16<<<dim3(32, 12), 256, 0, stream>>>(h16g, wih16_f, bih_f, xg_f, NG, ND);
  gemm16<<<dim3(32, 12), 256, 0, stream>>>(h16g, wih16_b, bih_b, xg_b, NG, ND);
  // 4. ENTIRE GRU recurrence: one persistent launch, 8 waves/block
  gru_persistent<<<256, 512, 0, stream>>>(xg_f, xg_b, whh16_f, whh16_b,
                                          bhh_f, bhh_b, gseq);
  // 5. attention scores + softmax
  attn_score_mfma<<<960, 256, 0, stream>>>(gseq, w116, ab1, aW2, scores);
  softmax_t<<<NB, 64, 0, stream>>>(scores);
  // 6. fused context + joints projection + FK (one gseq pass)
  ctx_joints_fk<<<NB, 256, 0, stream>>>(gseq, scores, jW, jb, (float*)d_out);
}

// Round 14
// 522.249 us; speedup vs baseline: 2.5607x; 1.1191x over previous
//
#include <hip/hip_runtime.h>
#include <hip/hip_fp16.h>

#define NB 2048
#define NT 60
#define NDL 100
#define ND 512
#define NH 256
#define NG 768

typedef const float* __restrict__ fpp;
typedef _Float16 half8 __attribute__((ext_vector_type(8)));
typedef float floatx4 __attribute__((ext_vector_type(4)));

__device__ __forceinline__ float fast_rcp(float x) {
  return __builtin_amdgcn_rcpf(x);
}
__device__ __forceinline__ float fast_sig(float x) {
  return fast_rcp(1.f + __expf(-x));
}
__device__ __forceinline__ float fast_tanh(float x) {
  float t = __expf(2.f * x);
  return (t - 1.f) * fast_rcp(t + 1.f);
}

// ---------------------------------------------------------------------------
// fp32 tiled GEMM (fc layer only, K=100): C = A*B^T + bias
// ---------------------------------------------------------------------------
__global__ __launch_bounds__(256) void gemm_fc(
    fpp A, fpp Bm, fpp bias, float* __restrict__ C,
    int M, int N, int K, int lda, int ldb, int ldc)
{
  __shared__ float As[16][68];
  __shared__ float Bs[16][68];
  const int bm = blockIdx.x * 64, bn = blockIdx.y * 64;
  const int tid = threadIdx.x;
  const int tx = tid & 15, ty = tid >> 4;
  float acc[4][4] = {};
  for (int k0 = 0; k0 < K; k0 += 16) {
#pragma unroll
    for (int i = 0; i < 4; i++) {
      int e = tid + i * 256;
      int m = e >> 4, k = e & 15;
      As[k][m] = (k0 + k < K) ? A[(size_t)(bm + m) * lda + k0 + k] : 0.f;
      Bs[k][m] = (k0 + k < K) ? Bm[(size_t)(bn + m) * ldb + k0 + k] : 0.f;
    }
    __syncthreads();
#pragma unroll
    for (int kk = 0; kk < 16; kk++) {
      float4 av = *(const float4*)&As[kk][ty * 4];
      float4 bv = *(const float4*)&Bs[kk][tx * 4];
      float a_[4] = {av.x, av.y, av.z, av.w};
      float b_[4] = {bv.x, bv.y, bv.z, bv.w};
#pragma unroll
      for (int i = 0; i < 4; i++)
#pragma unroll
        for (int j = 0; j < 4; j++)
          acc[i][j] = fmaf(a_[i], b_[j], acc[i][j]);
    }
    __syncthreads();
  }
#pragma unroll
  for (int i = 0; i < 4; i++) {
    int m = bm + ty * 4 + i;
#pragma unroll
    for (int j = 0; j < 4; j++) {
      int n = bn + tx * 4 + j;
      C[(size_t)m * ldc + n] = acc[i][j] + bias[n];
    }
  }
}

// ---------------------------------------------------------------------------
// BN partial sums: 64 blocks x 32 rows, coalesced, atomicAdd into s1/s2[512].
// ---------------------------------------------------------------------------
__global__ __launch_bounds__(256) void bn_partial(
    const float* __restrict__ h0, float* __restrict__ s1g,
    float* __restrict__ s2g)
{
  const int r0 = blockIdx.x * 32;
  const int tid = threadIdx.x;
  float a1 = 0.f, a2 = 0.f, b1 = 0.f, b2 = 0.f;
  for (int r = 0; r < 32; r++) {
    float v = h0[(size_t)(r0 + r) * ND + tid];
    float w = h0[(size_t)(r0 + r) * ND + tid + 256];
    a1 += v; a2 += v * v;
    b1 += w; b2 += w * w;
  }
  atomicAdd(&s1g[tid], a1);
  atomicAdd(&s2g[tid], a2);
  atomicAdd(&s1g[tid + 256], b1);
  atomicAdd(&s2g[tid + 256], b2);
}

// bn (stats from s1/s2) + leaky relu, writing fp16
__global__ void bn_lrelu_h16(const float* __restrict__ h0,
                             fpp g, fpp b,
                             const float* __restrict__ s1g,
                             const float* __restrict__ s2g,
                             __half* __restrict__ h16g)
{
  int idx = blockIdx.x * 256 + threadIdx.x;
  int d = idx & (ND - 1);
  float mu = s1g[d] * (1.f / NB);
  float var = s2g[d] * (1.f / NB) - mu * mu;
  float sc = g[d] * rsqrtf(var + 1e-5f);
  float sh = b[d] - mu * sc;
  float v = h0[idx] * sc + sh;
  h16g[idx] = __float2half(v >= 0.f ? v : 0.2f * v);
}

// ---------------------------------------------------------------------------
// One-time weight conversions fp32 -> fp16
// ---------------------------------------------------------------------------
__global__ void convert_w(fpp whf, fpp whb, fpp w1, fpp wif, fpp wib,
                          __half* __restrict__ o_whf, __half* __restrict__ o_whb,
                          __half* __restrict__ o_w1, __half* __restrict__ o_wif,
                          __half* __restrict__ o_wib)
{
  int idx = blockIdx.x * 256 + threadIdx.x;  // 0 .. 1310719
  if (idx < 196608) o_whf[idx] = __float2half(whf[idx]);
  else if (idx < 393216) o_whb[idx - 196608] = __float2half(whb[idx - 196608]);
  else if (idx < 524288) o_w1[idx - 393216] = __float2half(w1[idx - 393216]);
  else if (idx < 917504) o_wif[idx - 524288] = __float2half(wif[idx - 524288]);
  else o_wib[idx - 917504] = __float2half(wib[idx - 917504]);
}

// ---------------------------------------------------------------------------
// fp16 MFMA GEMM (xg projections): C[m][n] = A[m][:]·B[n][:] + bias[n]
// ---------------------------------------------------------------------------
__global__ __launch_bounds__(256) void gemm16(
    const __half* __restrict__ A, const __half* __restrict__ Bm,
    fpp bias, float* __restrict__ C, int N, int K)
{
  __shared__ __half As[64 * 40];
  __shared__ __half Bs[64 * 40];
  const int bm = blockIdx.x * 64, bn = blockIdx.y * 64;
  const int tid = threadIdx.x;
  const int wave = tid >> 6, lane = tid & 63;
  const int lm = lane & 15, quad = lane >> 4;
  floatx4 acc[4];
#pragma unroll
  for (int nt = 0; nt < 4; nt++) acc[nt] = (floatx4){0.f, 0.f, 0.f, 0.f};

  const int row = tid >> 2, kc = tid & 3;
  for (int k0 = 0; k0 < K; k0 += 32) {
    __syncthreads();
    *(float4*)&As[row * 40 + kc * 8] =
      *(const float4*)&A[(size_t)(bm + row) * K + k0 + kc * 8];
    *(float4*)&Bs[row * 40 + kc * 8] =
      *(const float4*)&Bm[(size_t)(bn + row) * K + k0 + kc * 8];
    __syncthreads();
    half8 af = *(const half8*)&As[(wave * 16 + lm) * 40 + quad * 8];
#pragma unroll
    for (int nt = 0; nt < 4; nt++) {
      half8 bf = *(const half8*)&Bs[(nt * 16 + lm) * 40 + quad * 8];
      acc[nt] = __builtin_amdgcn_mfma_f32_16x16x32_f16(af, bf, acc[nt], 0, 0, 0);
    }
  }
#pragma unroll
  for (int nt = 0; nt < 4; nt++) {
    int n = bn + nt * 16 + lm;
    float bv = bias[n];
#pragma unroll
    for (int r = 0; r < 4; r++) {
      int m = bm + wave * 16 + quad * 4 + r;
      C[(size_t)m * N + n] = acc[nt][r] + bv;
    }
  }
}

// ---------------------------------------------------------------------------
// PERSISTENT GRU, 512 threads (8 waves, 2 waves/SIMD), launch_bounds(512,2).
// B frags kb0..5 pinned via asm-opacity; kb6/7 streamed with early prefetch.
// kb0 MFMA takes inline-zero C operand (no per-step acc zero-init).
// Gate nonlinearities use native v_rcp (was full-precision div = ~15 instrs).
// ---------------------------------------------------------------------------
__global__ __launch_bounds__(512, 2) void gru_persistent(
    const float* __restrict__ xg_f, const float* __restrict__ xg_b,
    const __half* __restrict__ whh16_f, const __half* __restrict__ whh16_b,
    fpp bhh_f, fpp bhh_b, __half* __restrict__ seq)
{
  const int dir  = blockIdx.x & 1;
  const int tile = blockIdx.x >> 1;
  const int bm   = tile * 16;
  const float* __restrict__ xg = dir ? xg_b : xg_f;
  const __half* __restrict__ Whh = dir ? whh16_b : whh16_f;
  fpp bhh = dir ? bhh_b : bhh_f;
  const int dcol = dir * NH;
  const int tid = threadIdx.x;
  const int wave = tid >> 6, lane = tid & 63;
  const int lm = lane & 15, quad = lane >> 4;
  const int n0 = wave * 32;

  __shared__ __half h16[16 * 264];     // 16 rows x 256 (stride 264) = 8.4 KB

  // ---- B fragment base pointers (per gate g, col-tile c) ----
  const __half* bp[3][2];
#pragma unroll
  for (int g = 0; g < 3; g++)
#pragma unroll
    for (int c = 0; c < 2; c++)
      bp[g][c] = Whh + (size_t)(g * NH + n0 + c * 16 + lm) * NH + quad * 8;

  // ---- resident B frags kb 0..5 (144 VGPRs), PINNED via asm opacity ----
  floatx4 breg[3][2][6];
#pragma unroll
  for (int g = 0; g < 3; g++)
#pragma unroll
    for (int c = 0; c < 2; c++)
#pragma unroll
      for (int kb = 0; kb < 6; kb++)
        breg[g][c][kb] = *(const floatx4*)(bp[g][c] + kb * 32);
#pragma unroll
  for (int g = 0; g < 3; g++)
#pragma unroll
    for (int c = 0; c < 2; c++)
#pragma unroll
      for (int kb = 0; kb < 6; kb++)
        asm volatile("" : "+v"(breg[g][c][kb]));  // block rematerialization

  // ---- xg + biases in registers (time-invariant) ----
  float xr_[2][4], xz_[2][4], xn_[2][4];
  float br_[2], bz_[2], bn_[2];
#pragma unroll
  for (int c = 0; c < 2; c++) {
    int n = n0 + c * 16 + lm;
    br_[c] = bhh[n]; bz_[c] = bhh[NH + n]; bn_[c] = bhh[2 * NH + n];
#pragma unroll
    for (int r = 0; r < 4; r++) {
      int m = bm + quad * 4 + r;
      const float* xp = xg + (size_t)m * NG + n;
      xr_[c][r] = xp[0];
      xz_[c][r] = xp[NH];
      xn_[c][r] = xp[2 * NH];
    }
  }

  float hp[2][4];
#pragma unroll
  for (int c = 0; c < 2; c++)
#pragma unroll
    for (int r = 0; r < 4; r++) hp[c][r] = 0.f;

  const int arow = lm * 264 + quad * 8;
  const int cm = tid >> 5, cpart = tid & 31;   // seq-copy coords

  for (int step = 0; step < NT; step++) {
    floatx4 acc[3][2];

    if (step > 0) {
      // ---- issue seq store for step-1 (drain hidden behind K-loop) ----
      {
        const int t_prev = dir ? (NT - step) : (step - 1);
        float4 v = *(const float4*)&h16[cm * 264 + cpart * 8];
        *(float4*)&seq[((size_t)(bm + cm) * NT + t_prev) * ND + dcol + cpart * 8] = v;
      }
      // early prefetch of streamed kb6/kb7 frags
      half8 b6[3][2], b7[3][2];
#pragma unroll
      for (int g = 0; g < 3; g++)
#pragma unroll
        for (int c = 0; c < 2; c++) {
          b6[g][c] = *(const half8*)(bp[g][c] + 192);
          b7[g][c] = *(const half8*)(bp[g][c] + 224);
        }
      // kb0 with inline-zero C (no acc init), then kb1..5 resident
      {
        half8 a = *(const half8*)&h16[arow];
#pragma unroll
        for (int g = 0; g < 3; g++)
#pragma unroll
          for (int c = 0; c < 2; c++)
            acc[g][c] = __builtin_amdgcn_mfma_f32_16x16x32_f16(
                a, __builtin_bit_cast(half8, breg[g][c][0]),
                (floatx4){0.f, 0.f, 0.f, 0.f}, 0, 0, 0);
      }
#pragma unroll
      for (int kb = 1; kb < 6; kb++) {
        half8 a = *(const half8*)&h16[arow + kb * 32];
#pragma unroll
        for (int g = 0; g < 3; g++)
#pragma unroll
          for (int c = 0; c < 2; c++)
            acc[g][c] = __builtin_amdgcn_mfma_f32_16x16x32_f16(
                a, __builtin_bit_cast(half8, breg[g][c][kb]), acc[g][c], 0, 0, 0);
      }
      {
        half8 a = *(const half8*)&h16[arow + 192];
#pragma unroll
        for (int g = 0; g < 3; g++)
#pragma unroll
          for (int c = 0; c < 2; c++)
            acc[g][c] = __builtin_amdgcn_mfma_f32_16x16x32_f16(a, b6[g][c], acc[g][c], 0, 0, 0);
      }
      {
        half8 a = *(const half8*)&h16[arow + 224];
#pragma unroll
        for (int g = 0; g < 3; g++)
#pragma unroll
          for (int c = 0; c < 2; c++)
            acc[g][c] = __builtin_amdgcn_mfma_f32_16x16x32_f16(a, b7[g][c], acc[g][c], 0, 0, 0);
      }
      __syncthreads();  // barrier A: h16 reads (copy + a-frags) done
    } else {
#pragma unroll
      for (int g = 0; g < 3; g++)
#pragma unroll
        for (int c = 0; c < 2; c++) acc[g][c] = (floatx4){0.f, 0.f, 0.f, 0.f};
    }

    // ---- epilogue: gates + state update (operands in registers) ----
#pragma unroll
    for (int c = 0; c < 2; c++) {
      int n = n0 + c * 16 + lm;
#pragma unroll
      for (int r = 0; r < 4; r++) {
        int m = quad * 4 + r;
        float rg = fast_sig(xr_[c][r] + acc[0][c][r] + br_[c]);
        float zg = fast_sig(xz_[c][r] + acc[1][c][r] + bz_[c]);
        float nn = fast_tanh(xn_[c][r] + rg * (acc[2][c][r] + bn_[c]));
        float hv = (1.f - zg) * nn + zg * hp[c][r];
        hp[c][r] = hv;
        h16[m * 264 + n] = __float2half(hv);
      }
    }
    __syncthreads();  // barrier B: h16 visible for next step
  }

  // ---- final step's seq store ----
  {
    const int t_last = dir ? 0 : (NT - 1);
    float4 v = *(const float4*)&h16[cm * 264 + cpart * 8];
    *(float4*)&seq[((size_t)(bm + cm) * NT + t_last) * ND + dcol + cpart * 8] = v;
  }
}

// ---------------------------------------------------------------------------
// Attention scores via MFMA, M=128 rows/block, single pass, no atomics.
// ---------------------------------------------------------------------------
__global__ __launch_bounds__(256) void attn_score_mfma(
    const __half* __restrict__ seq, const __half* __restrict__ w116,
    fpp b1, fpp W2, float* __restrict__ scores)
{
  const int bm = blockIdx.x * 128;
  const int tid = threadIdx.x;
  const int wave = tid >> 6, lane = tid & 63;
  const int lm = lane & 15, quad = lane >> 4;

  __shared__ __half As[128 * 40];
  __shared__ __half Bs[256 * 40];

  floatx4 acc[2][16];
#pragma unroll
  for (int mt = 0; mt < 2; mt++)
#pragma unroll
    for (int nt = 0; nt < 16; nt++) acc[mt][nt] = (floatx4){0.f, 0.f, 0.f, 0.f};

  for (int k0 = 0; k0 < ND; k0 += 32) {
    __syncthreads();
#pragma unroll
    for (int i = 0; i < 2; i++) {
      int e = tid + i * 256;
      int row = e >> 2, kc = e & 3;
      *(float4*)&As[row * 40 + kc * 8] =
        *(const float4*)&seq[(size_t)(bm + row) * ND + k0 + kc * 8];
    }
#pragma unroll
    for (int i = 0; i < 4; i++) {
      int e = tid + i * 256;
      int row = e >> 2, kc = e & 3;
      *(float4*)&Bs[row * 40 + kc * 8] =
        *(const float4*)&w116[(size_t)row * ND + k0 + kc * 8];
    }
    __syncthreads();
    half8 a0 = *(const half8*)&As[((wave * 2 + 0) * 16 + lm) * 40 + quad * 8];
    half8 a1 = *(const half8*)&As[((wave * 2 + 1) * 16 + lm) * 40 + quad * 8];
#pragma unroll
    for (int nt = 0; nt < 16; nt++) {
      half8 bf = *(const half8*)&Bs[(nt * 16 + lm) * 40 + quad * 8];
      acc[0][nt] = __builtin_amdgcn_mfma_f32_16x16x32_f16(a0, bf, acc[0][nt], 0, 0, 0);
      acc[1][nt] = __builtin_amdgcn_mfma_f32_16x16x32_f16(a1, bf, acc[1][nt], 0, 0, 0);
    }
  }

  float rs[2][4] = {};
#pragma unroll
  for (int nt = 0; nt < 16; nt++) {
    int n = nt * 16 + lm;
    float b1v = b1[n], w2v = W2[n];
#pragma unroll
    for (int mt = 0; mt < 2; mt++)
#pragma unroll
      for (int r = 0; r < 4; r++)
        rs[mt][r] += fast_tanh(acc[mt][nt][r] + b1v) * w2v;
  }
#pragma unroll
  for (int mt = 0; mt < 2; mt++)
#pragma unroll
    for (int r = 0; r < 4; r++) {
      rs[mt][r] += __shfl_xor(rs[mt][r], 1);
      rs[mt][r] += __shfl_xor(rs[mt][r], 2);
      rs[mt][r] += __shfl_xor(rs[mt][r], 4);
      rs[mt][r] += __shfl_xor(rs[mt][r], 8);
    }
  if (lm == 0) {
#pragma unroll
    for (int mt = 0; mt < 2; mt++)
#pragma unroll
      for (int r = 0; r < 4; r++)
        scores[bm + (wave * 2 + mt) * 16 + quad * 4 + r] = rs[mt][r];
  }
}

__global__ void softmax_t(float* __restrict__ s)
{
  int b = blockIdx.x, lane = threadIdx.x;
  float v = (lane < NT) ? s[(size_t)b * NT + lane] : -1e30f;
  float m = v;
#pragma unroll
  for (int off = 32; off >= 1; off >>= 1) m = fmaxf(m, __shfl_xor(m, off));
  float e = (lane < NT) ? __expf(v - m) : 0.f;
  float sum = e;
#pragma unroll
  for (int off = 32; off >= 1; off >>= 1) sum += __shfl_xor(sum, off);
  if (lane < NT) s[(size_t)b * NT + lane] = e * fast_rcp(sum);
}

// ---------------------------------------------------------------------------
// FUSED context + joints projection + FK. One block per batch row b.
// ---------------------------------------------------------------------------
__constant__ float c_lower[6] = {-3.1416f, -1.5708f, -3.1416f, -2.6f, -1.5708f, -1.2f};
__constant__ float c_upper[6] = { 3.1416f,  1.5708f,  3.1416f,  0.1f,  1.5708f,  1.2f};

__global__ __launch_bounds__(256) void ctx_joints_fk(
    const __half* __restrict__ seq, const float* __restrict__ wsm,
    fpp jW, fpp jb, float* __restrict__ out)
{
  const int b = blockIdx.x;
  const int tid = threadIdx.x;

  __shared__ __half sq[NT * ND];     // 60 KB
  __shared__ float  wj[6 * ND];      // 12 KB
  __shared__ float  cs[ND];          // 2 KB
  __shared__ float  wt[NT];

  {
    const float4* src = (const float4*)(seq + (size_t)b * NT * ND);
#pragma unroll
    for (int i = 0; i < 15; i++) {
      int ch = tid + i * 256;
      *(float4*)&sq[ch * 8] = src[ch];
    }
#pragma unroll
    for (int i = 0; i < 12; i++) wj[tid + i * 256] = jW[tid + i * 256];
    if (tid < NT) wt[tid] = wsm[(size_t)b * NT + tid];
  }
  __syncthreads();

  {
    float s0 = 0.f, s1 = 0.f;
    for (int t = 0; t < NT; t++) {
      float w = wt[t];
      s0 += w * (float)sq[t * ND + tid * 2];
      s1 += w * (float)sq[t * ND + tid * 2 + 1];
    }
    cs[tid * 2] = s0;
    cs[tid * 2 + 1] = s1;
  }
  __syncthreads();

  const int wave = tid >> 6, lane = tid & 63;
  const int d0 = lane * 8;

  for (int it = 0; it < 15; it++) {
    const int t = it * 4 + wave;

    half8 hv = *(const half8*)&sq[t * ND + d0];
    float xv[8];
#pragma unroll
    for (int i = 0; i < 8; i++)
      xv[i] = (float)hv[i] + cs[d0 + i];

    float jnt[6];
#pragma unroll
    for (int j = 0; j < 6; j++) {
      float p = 0.f;
#pragma unroll
      for (int i = 0; i < 8; i++) p = fmaf(xv[i], wj[j * ND + d0 + i], p);
#pragma unroll
      for (int off = 32; off >= 1; off >>= 1) p += __shfl_xor(p, off);
      jnt[j] = p + jb[j];
    }

    float th[6];
#pragma unroll
    for (int j = 0; j < 6; j++)
      th[j] = jnt[j] * (c_upper[j] - c_lower[j]) + c_lower[j];

    float c0x = 1.f, c0y = 0.f, c0z = 0.f;
    float c1x = 0.f, c1y = 1.f, c1z = 0.f;
    float c2x = 0.f, c2y = 0.f, c2z = 1.f;
    float px = 0.f, py = 0.f, pz = 0.1f;
    float s, cc, tx_, ty_, tz_, ux_, uy_, uz_;

    // rotZ(th0)
    s = sinf(th[0]); cc = cosf(th[0]);
    tx_ = cc * c0x + s * c1x; ty_ = cc * c0y + s * c1y; tz_ = cc * c0z + s * c1z;
    ux_ = -s * c0x + cc * c1x; uy_ = -s * c0y + cc * c1y; uz_ = -s * c0z + cc * c1z;
    c0x = tx_; c0y = ty_; c0z = tz_; c1x = ux_; c1y = uy_; c1z = uz_;

    float shx = px, shy = py, shz = pz;  // shoulder2
    // rotX(th1)
    s = sinf(th[1]); cc = cosf(th[1]);
    tx_ = cc * c1x + s * c2x; ty_ = cc * c1y + s * c2y; tz_ = cc * c1z + s * c2z;
    ux_ = -s * c1x + cc * c2x; uy_ = -s * c1y + cc * c2y; uz_ = -s * c1z + cc * c2z;
    c1x = tx_; c1y = ty_; c1z = tz_; c2x = ux_; c2y = uy_; c2z = uz_;

    // rotY(th2)
    s = sinf(th[2]); cc = cosf(th[2]);
    tx_ = cc * c0x - s * c2x; ty_ = cc * c0y - s * c2y; tz_ = cc * c0z - s * c2z;
    ux_ = s * c0x + cc * c2x; uy_ = s * c0y + cc * c2y; uz_ = s * c0z + cc * c2z;
    c0x = tx_; c0y = ty_; c0z = tz_; c2x = ux_; c2y = uy_; c2z = uz_;

    // joint3 offset -> forearm
    px -= 0.25f * c1x; py -= 0.25f * c1y; pz -= 0.25f * c1z;
    float fox = px, foy = py, foz = pz;
    // rotX(th3)
    s = sinf(th[3]); cc = cosf(th[3]);
    tx_ = cc * c1x + s * c2x; ty_ = cc * c1y + s * c2y; tz_ = cc * c1z + s * c2z;
    ux_ = -s * c1x + cc * c2x; uy_ = -s * c1y + cc * c2y; uz_ = -s * c1z + cc * c2z;
    c1x = tx_; c1y = ty_; c1z = tz_; c2x = ux_; c2y = uy_; c2z = uz_;

    // rotY(th4)
    s = sinf(th[4]); cc = cosf(th[4]);
    tx_ = cc * c0x - s * c2x; ty_ = cc * c0y - s * c2y; tz_ = cc * c0z - s * c2z;
    ux_ = s * c0x + cc * c2x; uy_ = s * c0y + cc * c2y; uz_ = s * c0z + cc * c2z;
    c0x = tx_; c0y = ty_; c0z = tz_; c2x = ux_; c2y = uy_; c2z = uz_;

    // joint5 offset -> wrist
    px -= 0.25f * c1x; py -= 0.25f * c1y; pz -= 0.25f * c1z;
    float wx = px, wy = py, wz = pz;
    // rotX(th5)
    s = sinf(th[5]); cc = cosf(th[5]);
    tx_ = cc * c1x + s * c2x; ty_ = cc * c1y + s * c2y; tz_ = cc * c1z + s * c2z;
    ux_ = -s * c1x + cc * c2x; uy_ = -s * c1y + cc * c2y; uz_ = -s * c1z + cc * c2z;
    c1x = tx_; c1y = ty_; c1z = tz_; c2x = ux_; c2y = uy_; c2z = uz_;

    float f1x = wx - 0.08f * c1x + 0.02f * c2x;
    float f1y = wy - 0.08f * c1y + 0.02f * c2y;
    float f1z = wz - 0.08f * c1z + 0.02f * c2z;
    float f4x = wx - 0.08f * c1x - 0.02f * c2x;
    float f4y = wy - 0.08f * c1y - 0.02f * c2y;
    float f4z = wz - 0.08f * c1z - 0.02f * c2z;

    float dsx = shx - fox, dsy = shy - foy, dsz = shz - foz;
    float dwx = wx - fox, dwy = wy - foy, dwz = wz - foz;
    float bodyL = 0.5f * (sqrtf(dsx * dsx + dsy * dsy + dsz * dsz) +
                          sqrtf(dwx * dwx + dwy * dwy + dwz * dwz));
    float inv = fast_rcp(bodyL);

    float rel[9];
    rel[0] = (wx - shx) * inv; rel[1] = (wy - shy) * inv; rel[2] = (wz - shz) * inv;
    rel[3] = (f1x - shx) * inv; rel[4] = (f1y - shy) * inv; rel[5] = (f1z - shz) * inv;
    rel[6] = (f4x - shx) * inv; rel[7] = (f4y - shy) * inv; rel[8] = (f4z - shz) * inv;

    if (lane < 9) out[((size_t)b * NT + t) * 9 + lane] = rel[lane];
  }
}

// ---------------------------------------------------------------------------
extern "C" void kernel_launch(void* const* d_in, const int* in_sizes, int n_in,
                              void* d_out, int out_size, void* d_ws, size_t ws_size,
                              hipStream_t stream)
{
  fpp z     = (fpp)d_in[0];
  fpp W_fc  = (fpp)d_in[1];
  fpp b_fc  = (fpp)d_in[2];
  fpp bn_g  = (fpp)d_in[3];
  fpp bn_b  = (fpp)d_in[4];
  fpp Wih_f = (fpp)d_in[5];
  fpp Whh_f = (fpp)d_in[6];
  fpp bih_f = (fpp)d_in[7];
  fpp bhh_f = (fpp)d_in[8];
  fpp Wih_b = (fpp)d_in[9];
  fpp Whh_b = (fpp)d_in[10];
  fpp bih_b = (fpp)d_in[11];
  fpp bhh_b = (fpp)d_in[12];
  fpp aW1   = (fpp)d_in[13];
  fpp ab1   = (fpp)d_in[14];
  fpp aW2   = (fpp)d_in[15];
  fpp jW    = (fpp)d_in[16];
  fpp jb    = (fpp)d_in[17];

  float* ws     = (float*)d_ws;
  float* h0     = ws;                        // 2048*512 fp32
  float* xg_f   = h0 + 1048576;              // 2048*768 fp32
  float* xg_b   = xg_f + 1572864;            // 2048*768 fp32
  float* bns1   = xg_b + 1572864;            // 512
  float* bns2   = bns1 + 512;                // 512
  float* scores = bns2 + 512;                // 2048*60
  float* cbuf   = scores + 122880;           // 2048*512 (unused, layout keep)
  __half* gseq    = (__half*)(cbuf + 1048576);   // 2048*60*512 fp16 (126 MB)
  __half* whh16_f = gseq + 62914560;             // 768*256
  __half* whh16_b = whh16_f + 196608;            // 768*256
  __half* w116    = whh16_b + 196608;            // 256*512
  __half* wih16_f = w116 + 131072;               // 768*512
  __half* wih16_b = wih16_f + 393216;            // 768*512
  __half* h16g    = wih16_b + 393216;            // 2048*512

  // 0. weight conversions fp32->fp16 + BN accumulator zero
  convert_w<<<5120, 256, 0, stream>>>(Whh_f, Whh_b, aW1, Wih_f, Wih_b,
                                      whh16_f, whh16_b, w116, wih16_f, wih16_b);
  hipMemsetAsync(bns1, 0, 1024 * sizeof(float), stream);
  // 1. fc: h0 = z @ W_fc^T + b_fc (fp32, K=100)
  gemm_fc<<<dim3(32, 8), 256, 0, stream>>>(z, W_fc, b_fc, h0,
                                           NB, ND, NDL, NDL, NDL, ND);
  // 2. batchnorm (training stats, parallel partials) + leaky relu -> fp16 h
  bn_partial<<<64, 256, 0, stream>>>(h0, bns1, bns2);
  bn_lrelu_h16<<<4096, 256, 0, stream>>>(h0, bn_g, bn_b, bns1, bns2, h16g);
  // 3. time-invariant input projections via MFMA (computed ONCE)
  gemm16<<<dim3(32, 12), 256, 0, stream>>>(h16g, wih16_f, bih_f, xg_f, NG, ND);
  gemm16<<<dim3(32, 12), 256, 0, stream>>>(h16g, wih16_b, bih_b, xg_b, NG, ND);
  // 4. ENTIRE GRU recurrence: one persistent launch, 8 waves/block
  gru_persistent<<<256, 512, 0, stream>>>(xg_f, xg_b, whh16_f, whh16_b,
                                          bhh_f, bhh_b, gseq);
  // 5. attention scores + softmax
  attn_score_mfma<<<960, 256, 0, stream>>>(gseq, w116, ab1, aW2, scores);
  softmax_t<<<NB, 64, 0, stream>>>(scores);
  // 6. fused context + joints projection + FK (one gseq pass)
  ctx_joints_fk<<<NB, 256, 0, stream>>>(gseq, scores, jW, jb, (float*)d_out);
}

// Round 15
// 421.113 us; speedup vs baseline: 3.1756x; 1.2402x over previous
//
#include <hip/hip_runtime.h>
#include <hip/hip_fp16.h>

#define NB 2048
#define NT 60
#define NDL 100
#define ND 512
#define NH 256
#define NG 768

typedef const float* __restrict__ fpp;
typedef _Float16 half8 __attribute__((ext_vector_type(8)));
typedef float floatx4 __attribute__((ext_vector_type(4)));

__device__ __forceinline__ float fast_rcp(float x) {
  return __builtin_amdgcn_rcpf(x);
}
__device__ __forceinline__ float fast_sig(float x) {
  return fast_rcp(1.f + __expf(-x));
}
__device__ __forceinline__ float fast_tanh(float x) {
  float t = __expf(2.f * x);
  return (t - 1.f) * fast_rcp(t + 1.f);
}

// ---------------------------------------------------------------------------
// fp32 tiled GEMM (fc layer only, K=100): C = A*B^T + bias
// ---------------------------------------------------------------------------
__global__ __launch_bounds__(256) void gemm_fc(
    fpp A, fpp Bm, fpp bias, float* __restrict__ C,
    int M, int N, int K, int lda, int ldb, int ldc)
{
  __shared__ float As[16][68];
  __shared__ float Bs[16][68];
  const int bm = blockIdx.x * 64, bn = blockIdx.y * 64;
  const int tid = threadIdx.x;
  const int tx = tid & 15, ty = tid >> 4;
  float acc[4][4] = {};
  for (int k0 = 0; k0 < K; k0 += 16) {
#pragma unroll
    for (int i = 0; i < 4; i++) {
      int e = tid + i * 256;
      int m = e >> 4, k = e & 15;
      As[k][m] = (k0 + k < K) ? A[(size_t)(bm + m) * lda + k0 + k] : 0.f;
      Bs[k][m] = (k0 + k < K) ? Bm[(size_t)(bn + m) * ldb + k0 + k] : 0.f;
    }
    __syncthreads();
#pragma unroll
    for (int kk = 0; kk < 16; kk++) {
      float4 av = *(const float4*)&As[kk][ty * 4];
      float4 bv = *(const float4*)&Bs[kk][tx * 4];
      float a_[4] = {av.x, av.y, av.z, av.w};
      float b_[4] = {bv.x, bv.y, bv.z, bv.w};
#pragma unroll
      for (int i = 0; i < 4; i++)
#pragma unroll
        for (int j = 0; j < 4; j++)
          acc[i][j] = fmaf(a_[i], b_[j], acc[i][j]);
    }
    __syncthreads();
  }
#pragma unroll
  for (int i = 0; i < 4; i++) {
    int m = bm + ty * 4 + i;
#pragma unroll
    for (int j = 0; j < 4; j++) {
      int n = bn + tx * 4 + j;
      C[(size_t)m * ldc + n] = acc[i][j] + bias[n];
    }
  }
}

// ---------------------------------------------------------------------------
// BN partial sums: 64 blocks x 32 rows, coalesced, atomicAdd into s1/s2[512].
// ---------------------------------------------------------------------------
__global__ __launch_bounds__(256) void bn_partial(
    const float* __restrict__ h0, float* __restrict__ s1g,
    float* __restrict__ s2g)
{
  const int r0 = blockIdx.x * 32;
  const int tid = threadIdx.x;
  float a1 = 0.f, a2 = 0.f, b1 = 0.f, b2 = 0.f;
  for (int r = 0; r < 32; r++) {
    float v = h0[(size_t)(r0 + r) * ND + tid];
    float w = h0[(size_t)(r0 + r) * ND + tid + 256];
    a1 += v; a2 += v * v;
    b1 += w; b2 += w * w;
  }
  atomicAdd(&s1g[tid], a1);
  atomicAdd(&s2g[tid], a2);
  atomicAdd(&s1g[tid + 256], b1);
  atomicAdd(&s2g[tid + 256], b2);
}

// bn (stats from s1/s2) + leaky relu, writing fp16
__global__ void bn_lrelu_h16(const float* __restrict__ h0,
                             fpp g, fpp b,
                             const float* __restrict__ s1g,
                             const float* __restrict__ s2g,
                             __half* __restrict__ h16g)
{
  int idx = blockIdx.x * 256 + threadIdx.x;
  int d = idx & (ND - 1);
  float mu = s1g[d] * (1.f / NB);
  float var = s2g[d] * (1.f / NB) - mu * mu;
  float sc = g[d] * rsqrtf(var + 1e-5f);
  float sh = b[d] - mu * sc;
  float v = h0[idx] * sc + sh;
  h16g[idx] = __float2half(v >= 0.f ? v : 0.2f * v);
}

// ---------------------------------------------------------------------------
// One-time weight conversions fp32 -> fp16 (+ zero-padded jW 16x512)
// ---------------------------------------------------------------------------
__global__ void convert_w(fpp whf, fpp whb, fpp w1, fpp wif, fpp wib, fpp jw,
                          __half* __restrict__ o_whf, __half* __restrict__ o_whb,
                          __half* __restrict__ o_w1, __half* __restrict__ o_wif,
                          __half* __restrict__ o_wib, __half* __restrict__ o_jw)
{
  int idx = blockIdx.x * 256 + threadIdx.x;  // 0 .. 1318911
  if (idx < 196608) o_whf[idx] = __float2half(whf[idx]);
  else if (idx < 393216) o_whb[idx - 196608] = __float2half(whb[idx - 196608]);
  else if (idx < 524288) o_w1[idx - 393216] = __float2half(w1[idx - 393216]);
  else if (idx < 917504) o_wif[idx - 524288] = __float2half(wif[idx - 524288]);
  else if (idx < 1310720) o_wib[idx - 917504] = __float2half(wib[idx - 917504]);
  else if (idx < 1318912) {
    int e = idx - 1310720;           // 16 x 512, rows >= 6 zero
    o_jw[e] = (e < 6 * ND) ? __float2half(jw[e]) : __float2half(0.f);
  }
}

// ---------------------------------------------------------------------------
// fp16 MFMA GEMM (xg projections): C[m][n] = A[m][:]·B[n][:] + bias[n]
// ---------------------------------------------------------------------------
__global__ __launch_bounds__(256) void gemm16(
    const __half* __restrict__ A, const __half* __restrict__ Bm,
    fpp bias, float* __restrict__ C, int N, int K)
{
  __shared__ __half As[64 * 40];
  __shared__ __half Bs[64 * 40];
  const int bm = blockIdx.x * 64, bn = blockIdx.y * 64;
  const int tid = threadIdx.x;
  const int wave = tid >> 6, lane = tid & 63;
  const int lm = lane & 15, quad = lane >> 4;
  floatx4 acc[4];
#pragma unroll
  for (int nt = 0; nt < 4; nt++) acc[nt] = (floatx4){0.f, 0.f, 0.f, 0.f};

  const int row = tid >> 2, kc = tid & 3;
  for (int k0 = 0; k0 < K; k0 += 32) {
    __syncthreads();
    *(float4*)&As[row * 40 + kc * 8] =
      *(const float4*)&A[(size_t)(bm + row) * K + k0 + kc * 8];
    *(float4*)&Bs[row * 40 + kc * 8] =
      *(const float4*)&Bm[(size_t)(bn + row) * K + k0 + kc * 8];
    __syncthreads();
    half8 af = *(const half8*)&As[(wave * 16 + lm) * 40 + quad * 8];
#pragma unroll
    for (int nt = 0; nt < 4; nt++) {
      half8 bf = *(const half8*)&Bs[(nt * 16 + lm) * 40 + quad * 8];
      acc[nt] = __builtin_amdgcn_mfma_f32_16x16x32_f16(af, bf, acc[nt], 0, 0, 0);
    }
  }
#pragma unroll
  for (int nt = 0; nt < 4; nt++) {
    int n = bn + nt * 16 + lm;
    float bv = bias[n];
#pragma unroll
    for (int r = 0; r < 4; r++) {
      int m = bm + wave * 16 + quad * 4 + r;
      C[(size_t)m * N + n] = acc[nt][r] + bv;
    }
  }
}

// ---------------------------------------------------------------------------
// PERSISTENT GRU, 512 threads (8 waves, 2 waves/SIMD), launch_bounds(512,2).
// B frags kb0..5 pinned via asm-opacity; kb6/7 streamed with early prefetch.
// h-state DOUBLE-BUFFERED in LDS -> single barrier per step (write buf s&1,
// read buf (s-1)&1; the end-of-step barrier provides both orderings).
// seq store for step s-1 issued at top of step s (drains a full step later).
// ---------------------------------------------------------------------------
__global__ __launch_bounds__(512, 2) void gru_persistent(
    const float* __restrict__ xg_f, const float* __restrict__ xg_b,
    const __half* __restrict__ whh16_f, const __half* __restrict__ whh16_b,
    fpp bhh_f, fpp bhh_b, __half* __restrict__ seq)
{
  const int dir  = blockIdx.x & 1;
  const int tile = blockIdx.x >> 1;
  const int bm   = tile * 16;
  const float* __restrict__ xg = dir ? xg_b : xg_f;
  const __half* __restrict__ Whh = dir ? whh16_b : whh16_f;
  fpp bhh = dir ? bhh_b : bhh_f;
  const int dcol = dir * NH;
  const int tid = threadIdx.x;
  const int wave = tid >> 6, lane = tid & 63;
  const int lm = lane & 15, quad = lane >> 4;
  const int n0 = wave * 32;

  __shared__ __half h16s[2][16 * 264];   // double-buffered h state (16.9 KB)

  // ---- B fragment base pointers (per gate g, col-tile c) ----
  const __half* bp[3][2];
#pragma unroll
  for (int g = 0; g < 3; g++)
#pragma unroll
    for (int c = 0; c < 2; c++)
      bp[g][c] = Whh + (size_t)(g * NH + n0 + c * 16 + lm) * NH + quad * 8;

  // ---- resident B frags kb 0..5 (144 VGPRs), PINNED via asm opacity ----
  floatx4 breg[3][2][6];
#pragma unroll
  for (int g = 0; g < 3; g++)
#pragma unroll
    for (int c = 0; c < 2; c++)
#pragma unroll
      for (int kb = 0; kb < 6; kb++)
        breg[g][c][kb] = *(const floatx4*)(bp[g][c] + kb * 32);
#pragma unroll
  for (int g = 0; g < 3; g++)
#pragma unroll
    for (int c = 0; c < 2; c++)
#pragma unroll
      for (int kb = 0; kb < 6; kb++)
        asm volatile("" : "+v"(breg[g][c][kb]));  // block rematerialization

  // ---- xg + biases in registers (time-invariant) ----
  float xr_[2][4], xz_[2][4], xn_[2][4];
  float br_[2], bz_[2], bn_[2];
#pragma unroll
  for (int c = 0; c < 2; c++) {
    int n = n0 + c * 16 + lm;
    br_[c] = bhh[n]; bz_[c] = bhh[NH + n]; bn_[c] = bhh[2 * NH + n];
#pragma unroll
    for (int r = 0; r < 4; r++) {
      int m = bm + quad * 4 + r;
      const float* xp = xg + (size_t)m * NG + n;
      xr_[c][r] = xp[0];
      xz_[c][r] = xp[NH];
      xn_[c][r] = xp[2 * NH];
    }
  }

  float hp[2][4];
#pragma unroll
  for (int c = 0; c < 2; c++)
#pragma unroll
    for (int r = 0; r < 4; r++) hp[c][r] = 0.f;

  const int arow = lm * 264 + quad * 8;
  const int cm = tid >> 5, cpart = tid & 31;   // seq-copy coords

  for (int step = 0; step < NT; step++) {
    const int cur = step & 1, prv = cur ^ 1;
    __half* __restrict__ hCur = h16s[cur];
    const __half* __restrict__ hPrv = h16s[prv];
    floatx4 acc[3][2];

    if (step > 0) {
      // ---- issue seq store for step-1 (drains a full step later) ----
      {
        const int t_prev = dir ? (NT - step) : (step - 1);
        float4 v = *(const float4*)&hPrv[cm * 264 + cpart * 8];
        *(float4*)&seq[((size_t)(bm + cm) * NT + t_prev) * ND + dcol + cpart * 8] = v;
      }
      // early prefetch of streamed kb6/kb7 frags
      half8 b6[3][2], b7[3][2];
#pragma unroll
      for (int g = 0; g < 3; g++)
#pragma unroll
        for (int c = 0; c < 2; c++) {
          b6[g][c] = *(const half8*)(bp[g][c] + 192);
          b7[g][c] = *(const half8*)(bp[g][c] + 224);
        }
      // kb0 with inline-zero C (no acc init), then kb1..5 resident
      {
        half8 a = *(const half8*)&hPrv[arow];
#pragma unroll
        for (int g = 0; g < 3; g++)
#pragma unroll
          for (int c = 0; c < 2; c++)
            acc[g][c] = __builtin_amdgcn_mfma_f32_16x16x32_f16(
                a, __builtin_bit_cast(half8, breg[g][c][0]),
                (floatx4){0.f, 0.f, 0.f, 0.f}, 0, 0, 0);
      }
#pragma unroll
      for (int kb = 1; kb < 6; kb++) {
        half8 a = *(const half8*)&hPrv[arow + kb * 32];
#pragma unroll
        for (int g = 0; g < 3; g++)
#pragma unroll
          for (int c = 0; c < 2; c++)
            acc[g][c] = __builtin_amdgcn_mfma_f32_16x16x32_f16(
                a, __builtin_bit_cast(half8, breg[g][c][kb]), acc[g][c], 0, 0, 0);
      }
      {
        half8 a = *(const half8*)&hPrv[arow + 192];
#pragma unroll
        for (int g = 0; g < 3; g++)
#pragma unroll
          for (int c = 0; c < 2; c++)
            acc[g][c] = __builtin_amdgcn_mfma_f32_16x16x32_f16(a, b6[g][c], acc[g][c], 0, 0, 0);
      }
      {
        half8 a = *(const half8*)&hPrv[arow + 224];
#pragma unroll
        for (int g = 0; g < 3; g++)
#pragma unroll
          for (int c = 0; c < 2; c++)
            acc[g][c] = __builtin_amdgcn_mfma_f32_16x16x32_f16(a, b7[g][c], acc[g][c], 0, 0, 0);
      }
    } else {
#pragma unroll
      for (int g = 0; g < 3; g++)
#pragma unroll
        for (int c = 0; c < 2; c++) acc[g][c] = (floatx4){0.f, 0.f, 0.f, 0.f};
    }

    // ---- epilogue: gates + state update (operands in registers) ----
#pragma unroll
    for (int c = 0; c < 2; c++) {
      int n = n0 + c * 16 + lm;
#pragma unroll
      for (int r = 0; r < 4; r++) {
        int m = quad * 4 + r;
        float rg = fast_sig(xr_[c][r] + acc[0][c][r] + br_[c]);
        float zg = fast_sig(xz_[c][r] + acc[1][c][r] + bz_[c]);
        float nn = fast_tanh(xn_[c][r] + rg * (acc[2][c][r] + bn_[c]));
        float hv = (1.f - zg) * nn + zg * hp[c][r];
        hp[c][r] = hv;
        hCur[m * 264 + n] = __float2half(hv);
      }
    }
    __syncthreads();  // single barrier: hCur visible for next step's reads
  }

  // ---- final step's seq store ----
  {
    const int t_last = dir ? 0 : (NT - 1);
    const __half* hLast = h16s[(NT - 1) & 1];
    float4 v = *(const float4*)&hLast[cm * 264 + cpart * 8];
    *(float4*)&seq[((size_t)(bm + cm) * NT + t_last) * ND + dcol + cpart * 8] = v;
  }
}

// ---------------------------------------------------------------------------
// Attention scores via MFMA, M=128 rows/block, single pass, no atomics.
// FUSED: also computes gJ = seq @ jW16^T (16-col zero-padded joint proj) --
// the c-context term is recovered later as cJ[b] = sum_t w[bt]*gJ[bt]
// (projection commutes with softmax-weighted sum).
// ---------------------------------------------------------------------------
__global__ __launch_bounds__(256) void attn_score_mfma(
    const __half* __restrict__ seq, const __half* __restrict__ w116,
    const __half* __restrict__ jw16, fpp b1, fpp W2,
    float* __restrict__ scores, float* __restrict__ gJ)
{
  const int bm = blockIdx.x * 128;
  const int tid = threadIdx.x;
  const int wave = tid >> 6, lane = tid & 63;
  const int lm = lane & 15, quad = lane >> 4;

  __shared__ __half As[128 * 40];
  __shared__ __half Bs[256 * 40];
  __shared__ __half Js[16 * 40];

  floatx4 acc[2][16];
  floatx4 accJ[2];
#pragma unroll
  for (int mt = 0; mt < 2; mt++) {
#pragma unroll
    for (int nt = 0; nt < 16; nt++) acc[mt][nt] = (floatx4){0.f, 0.f, 0.f, 0.f};
    accJ[mt] = (floatx4){0.f, 0.f, 0.f, 0.f};
  }

  for (int k0 = 0; k0 < ND; k0 += 32) {
    __syncthreads();
#pragma unroll
    for (int i = 0; i < 2; i++) {
      int e = tid + i * 256;
      int row = e >> 2, kc = e & 3;
      *(float4*)&As[row * 40 + kc * 8] =
        *(const float4*)&seq[(size_t)(bm + row) * ND + k0 + kc * 8];
    }
#pragma unroll
    for (int i = 0; i < 4; i++) {
      int e = tid + i * 256;
      int row = e >> 2, kc = e & 3;
      *(float4*)&Bs[row * 40 + kc * 8] =
        *(const float4*)&w116[(size_t)row * ND + k0 + kc * 8];
    }
    if (tid < 64) {
      int row = tid >> 2, kc = tid & 3;
      *(float4*)&Js[row * 40 + kc * 8] =
        *(const float4*)&jw16[(size_t)row * ND + k0 + kc * 8];
    }
    __syncthreads();
    half8 a0 = *(const half8*)&As[((wave * 2 + 0) * 16 + lm) * 40 + quad * 8];
    half8 a1 = *(const half8*)&As[((wave * 2 + 1) * 16 + lm) * 40 + quad * 8];
#pragma unroll
    for (int nt = 0; nt < 16; nt++) {
      half8 bf = *(const half8*)&Bs[(nt * 16 + lm) * 40 + quad * 8];
      acc[0][nt] = __builtin_amdgcn_mfma_f32_16x16x32_f16(a0, bf, acc[0][nt], 0, 0, 0);
      acc[1][nt] = __builtin_amdgcn_mfma_f32_16x16x32_f16(a1, bf, acc[1][nt], 0, 0, 0);
    }
    {
      half8 bj = *(const half8*)&Js[lm * 40 + quad * 8];
      accJ[0] = __builtin_amdgcn_mfma_f32_16x16x32_f16(a0, bj, accJ[0], 0, 0, 0);
      accJ[1] = __builtin_amdgcn_mfma_f32_16x16x32_f16(a1, bj, accJ[1], 0, 0, 0);
    }
  }

  float rs[2][4] = {};
#pragma unroll
  for (int nt = 0; nt < 16; nt++) {
    int n = nt * 16 + lm;
    float b1v = b1[n], w2v = W2[n];
#pragma unroll
    for (int mt = 0; mt < 2; mt++)
#pragma unroll
      for (int r = 0; r < 4; r++)
        rs[mt][r] += fast_tanh(acc[mt][nt][r] + b1v) * w2v;
  }
#pragma unroll
  for (int mt = 0; mt < 2; mt++)
#pragma unroll
    for (int r = 0; r < 4; r++) {
      rs[mt][r] += __shfl_xor(rs[mt][r], 1);
      rs[mt][r] += __shfl_xor(rs[mt][r], 2);
      rs[mt][r] += __shfl_xor(rs[mt][r], 4);
      rs[mt][r] += __shfl_xor(rs[mt][r], 8);
    }
  if (lm == 0) {
#pragma unroll
    for (int mt = 0; mt < 2; mt++)
#pragma unroll
      for (int r = 0; r < 4; r++)
        scores[bm + (wave * 2 + mt) * 16 + quad * 4 + r] = rs[mt][r];
  }
  // gJ write: row = bt, col = lm (joint idx, 0..15)
#pragma unroll
  for (int mt = 0; mt < 2; mt++)
#pragma unroll
    for (int r = 0; r < 4; r++) {
      int row = bm + (wave * 2 + mt) * 16 + quad * 4 + r;
      gJ[(size_t)row * 16 + lm] = accJ[mt][r];
    }
}

__global__ void softmax_t(float* __restrict__ s)
{
  int b = blockIdx.x, lane = threadIdx.x;
  float v = (lane < NT) ? s[(size_t)b * NT + lane] : -1e30f;
  float m = v;
#pragma unroll
  for (int off = 32; off >= 1; off >>= 1) m = fmaxf(m, __shfl_xor(m, off));
  float e = (lane < NT) ? __expf(v - m) : 0.f;
  float sum = e;
#pragma unroll
  for (int off = 32; off >= 1; off >>= 1) sum += __shfl_xor(sum, off);
  if (lane < NT) s[(size_t)b * NT + lane] = e * fast_rcp(sum);
}

// cJ[b][j] = sum_t w[b][t] * gJ[b*NT+t][j]   (thread = (b,j), j in [0,16))
__global__ __launch_bounds__(256) void ctx_j(
    const float* __restrict__ gJ, const float* __restrict__ wsm,
    float* __restrict__ cJ)
{
  int gid = blockIdx.x * 256 + threadIdx.x;   // 2048*16
  int b = gid >> 4, j = gid & 15;
  float s = 0.f;
  const float* wp = wsm + (size_t)b * NT;
  const float* gp = gJ + (size_t)b * NT * 16 + j;
  for (int t = 0; t < NT; t++)
    s += wp[t] * gp[t * 16];
  cJ[gid] = s;
}

// ---------------------------------------------------------------------------
// Scalar FK: one thread per (b,t). jnt = gJ[bt] + cJ[b] + jb.
// ---------------------------------------------------------------------------
__constant__ float c_lower[6] = {-3.1416f, -1.5708f, -3.1416f, -2.6f, -1.5708f, -1.2f};
__constant__ float c_upper[6] = { 3.1416f,  1.5708f,  3.1416f,  0.1f,  1.5708f,  1.2f};

__global__ __launch_bounds__(256) void fk_scalar(
    const float* __restrict__ gJ, const float* __restrict__ cJ,
    fpp jb, float* __restrict__ out)
{
  int bt = blockIdx.x * 256 + threadIdx.x;   // 122880
  int b = bt / NT;

  float th[6];
#pragma unroll
  for (int j = 0; j < 6; j++) {
    float jnt = gJ[(size_t)bt * 16 + j] + cJ[b * 16 + j] + jb[j];
    th[j] = jnt * (c_upper[j] - c_lower[j]) + c_lower[j];
  }

  float c0x = 1.f, c0y = 0.f, c0z = 0.f;
  float c1x = 0.f, c1y = 1.f, c1z = 0.f;
  float c2x = 0.f, c2y = 0.f, c2z = 1.f;
  float px = 0.f, py = 0.f, pz = 0.1f;
  float s, cc, tx_, ty_, tz_, ux_, uy_, uz_;

  // rotZ(th0)
  s = sinf(th[0]); cc = cosf(th[0]);
  tx_ = cc * c0x + s * c1x; ty_ = cc * c0y + s * c1y; tz_ = cc * c0z + s * c1z;
  ux_ = -s * c0x + cc * c1x; uy_ = -s * c0y + cc * c1y; uz_ = -s * c0z + cc * c1z;
  c0x = tx_; c0y = ty_; c0z = tz_; c1x = ux_; c1y = uy_; c1z = uz_;

  float shx = px, shy = py, shz = pz;  // shoulder2
  // rotX(th1)
  s = sinf(th[1]); cc = cosf(th[1]);
  tx_ = cc * c1x + s * c2x; ty_ = cc * c1y + s * c2y; tz_ = cc * c1z + s * c2z;
  ux_ = -s * c1x + cc * c2x; uy_ = -s * c1y + cc * c2y; uz_ = -s * c1z + cc * c2z;
  c1x = tx_; c1y = ty_; c1z = tz_; c2x = ux_; c2y = uy_; c2z = uz_;

  // rotY(th2)
  s = sinf(th[2]); cc = cosf(th[2]);
  tx_ = cc * c0x - s * c2x; ty_ = cc * c0y - s * c2y; tz_ = cc * c0z - s * c2z;
  ux_ = s * c0x + cc * c2x; uy_ = s * c0y + cc * c2y; uz_ = s * c0z + cc * c2z;
  c0x = tx_; c0y = ty_; c0z = tz_; c2x = ux_; c2y = uy_; c2z = uz_;

  // joint3 offset -> forearm
  px -= 0.25f * c1x; py -= 0.25f * c1y; pz -= 0.25f * c1z;
  float fox = px, foy = py, foz = pz;
  // rotX(th3)
  s = sinf(th[3]); cc = cosf(th[3]);
  tx_ = cc * c1x + s * c2x; ty_ = cc * c1y + s * c2y; tz_ = cc * c1z + s * c2z;
  ux_ = -s * c1x + cc * c2x; uy_ = -s * c1y + cc * c2y; uz_ = -s * c1z + cc * c2z;
  c1x = tx_; c1y = ty_; c1z = tz_; c2x = ux_; c2y = uy_; c2z = uz_;

  // rotY(th4)
  s = sinf(th[4]); cc = cosf(th[4]);
  tx_ = cc * c0x - s * c2x; ty_ = cc * c0y - s * c2y; tz_ = cc * c0z - s * c2z;
  ux_ = s * c0x + cc * c2x; uy_ = s * c0y + cc * c2y; uz_ = s * c0z + cc * c2z;
  c0x = tx_; c0y = ty_; c0z = tz_; c2x = ux_; c2y = uy_; c2z = uz_;

  // joint5 offset -> wrist
  px -= 0.25f * c1x; py -= 0.25f * c1y; pz -= 0.25f * c1z;
  float wx = px, wy = py, wz = pz;
  // rotX(th5)
  s = sinf(th[5]); cc = cosf(th[5]);
  tx_ = cc * c1x + s * c2x; ty_ = cc * c1y + s * c2y; tz_ = cc * c1z + s * c2z;
  ux_ = -s * c1x + cc * c2x; uy_ = -s * c1y + cc * c2y; uz_ = -s * c1z + cc * c2z;
  c1x = tx_; c1y = ty_; c1z = tz_; c2x = ux_; c2y = uy_; c2z = uz_;

  float f1x = wx - 0.08f * c1x + 0.02f * c2x;
  float f1y = wy - 0.08f * c1y + 0.02f * c2y;
  float f1z = wz - 0.08f * c1z + 0.02f * c2z;
  float f4x = wx - 0.08f * c1x - 0.02f * c2x;
  float f4y = wy - 0.08f * c1y - 0.02f * c2y;
  float f4z = wz - 0.08f * c1z - 0.02f * c2z;

  float dsx = shx - fox, dsy = shy - foy, dsz = shz - foz;
  float dwx = wx - fox, dwy = wy - foy, dwz = wz - foz;
  float bodyL = 0.5f * (sqrtf(dsx * dsx + dsy * dsy + dsz * dsz) +
                        sqrtf(dwx * dwx + dwy * dwy + dwz * dwz));
  float inv = fast_rcp(bodyL);

  float* o = out + (size_t)bt * 9;
  o[0] = (wx - shx) * inv; o[1] = (wy - shy) * inv; o[2] = (wz - shz) * inv;
  o[3] = (f1x - shx) * inv; o[4] = (f1y - shy) * inv; o[5] = (f1z - shz) * inv;
  o[6] = (f4x - shx) * inv; o[7] = (f4y - shy) * inv; o[8] = (f4z - shz) * inv;
}

// ---------------------------------------------------------------------------
extern "C" void kernel_launch(void* const* d_in, const int* in_sizes, int n_in,
                              void* d_out, int out_size, void* d_ws, size_t ws_size,
                              hipStream_t stream)
{
  fpp z     = (fpp)d_in[0];
  fpp W_fc  = (fpp)d_in[1];
  fpp b_fc  = (fpp)d_in[2];
  fpp bn_g  = (fpp)d_in[3];
  fpp bn_b  = (fpp)d_in[4];
  fpp Wih_f = (fpp)d_in[5];
  fpp Whh_f = (fpp)d_in[6];
  fpp bih_f = (fpp)d_in[7];
  fpp bhh_f = (fpp)d_in[8];
  fpp Wih_b = (fpp)d_in[9];
  fpp Whh_b = (fpp)d_in[10];
  fpp bih_b = (fpp)d_in[11];
  fpp bhh_b = (fpp)d_in[12];
  fpp aW1   = (fpp)d_in[13];
  fpp ab1   = (fpp)d_in[14];
  fpp aW2   = (fpp)d_in[15];
  fpp jW    = (fpp)d_in[16];
  fpp jb    = (fpp)d_in[17];

  float* ws     = (float*)d_ws;
  float* h0     = ws;                        // 2048*512 fp32
  float* xg_f   = h0 + 1048576;              // 2048*768 fp32
  float* xg_b   = xg_f + 1572864;            // 2048*768 fp32
  float* bns1   = xg_b + 1572864;            // 512
  float* bns2   = bns1 + 512;                // 512
  float* scores = bns2 + 512;                // 2048*60
  float* cbuf   = scores + 122880;           // 2048*512 (unused, layout keep)
  __half* gseq    = (__half*)(cbuf + 1048576);   // 2048*60*512 fp16 (126 MB)
  __half* whh16_f = gseq + 62914560;             // 768*256
  __half* whh16_b = whh16_f + 196608;            // 768*256
  __half* w116    = whh16_b + 196608;            // 256*512
  __half* wih16_f = w116 + 131072;               // 768*512
  __half* wih16_b = wih16_f + 393216;            // 768*512
  __half* h16g    = wih16_b + 393216;            // 2048*512
  __half* jw16    = h16g + 1048576;              // 16*512
  float*  gJ      = (float*)(jw16 + 8192);       // 122880*16 fp32 (7.9 MB)
  float*  cJ      = gJ + 1966080;                // 2048*16 fp32

  // 0. weight conversions fp32->fp16 (incl. zero-padded jW) + BN acc zero
  convert_w<<<5152, 256, 0, stream>>>(Whh_f, Whh_b, aW1, Wih_f, Wih_b, jW,
                                      whh16_f, whh16_b, w116, wih16_f, wih16_b,
                                      jw16);
  hipMemsetAsync(bns1, 0, 1024 * sizeof(float), stream);
  // 1. fc: h0 = z @ W_fc^T + b_fc (fp32, K=100)
  gemm_fc<<<dim3(32, 8), 256, 0, stream>>>(z, W_fc, b_fc, h0,
                                           NB, ND, NDL, NDL, NDL, ND);
  // 2. batchnorm (training stats, parallel partials) + leaky relu -> fp16 h
  bn_partial<<<64, 256, 0, stream>>>(h0, bns1, bns2);
  bn_lrelu_h16<<<4096, 256, 0, stream>>>(h0, bn_g, bn_b, bns1, bns2, h16g);
  // 3. time-invariant input projections via MFMA (computed ONCE)
  gemm16<<<dim3(32, 12), 256, 0, stream>>>(h16g, wih16_f, bih_f, xg_f, NG, ND);
  gemm16<<<dim3(32, 12), 256, 0, stream>>>(h16g, wih16_b, bih_b, xg_b, NG, ND);
  // 4. ENTIRE GRU recurrence: one persistent launch, 8 waves/block
  gru_persistent<<<256, 512, 0, stream>>>(xg_f, xg_b, whh16_f, whh16_b,
                                          bhh_f, bhh_b, gseq);
  // 5. attention scores + joint projection gJ (fused), softmax
  attn_score_mfma<<<960, 256, 0, stream>>>(gseq, w116, jw16, ab1, aW2,
                                           scores, gJ);
  softmax_t<<<NB, 64, 0, stream>>>(scores);
  // 6. context-in-joint-space reduction + scalar FK
  ctx_j<<<128, 256, 0, stream>>>(gJ, scores, cJ);
  fk_scalar<<<480, 256, 0, stream>>>(gJ, cJ, jb, (float*)d_out);
}

// Round 16
// 396.625 us; speedup vs baseline: 3.3717x; 1.0617x over previous
//
#include <hip/hip_runtime.h>
#include <hip/hip_fp16.h>

#define NB 2048
#define NT 60
#define NDL 100
#define ND 512
#define NH 256
#define NG 768

typedef const float* __restrict__ fpp;
typedef _Float16 half8 __attribute__((ext_vector_type(8)));
typedef float floatx4 __attribute__((ext_vector_type(4)));

__device__ __forceinline__ float fast_rcp(float x) {
  return __builtin_amdgcn_rcpf(x);
}
__device__ __forceinline__ float fast_sig(float x) {
  return fast_rcp(1.f + __expf(-x));
}
__device__ __forceinline__ float fast_tanh(float x) {
  float t = __expf(2.f * x);
  return (t - 1.f) * fast_rcp(t + 1.f);
}

// ---------------------------------------------------------------------------
// fp32 tiled GEMM (fc layer only, K=100): C = A*B^T + bias
// ---------------------------------------------------------------------------
__global__ __launch_bounds__(256) void gemm_fc(
    fpp A, fpp Bm, fpp bias, float* __restrict__ C,
    int M, int N, int K, int lda, int ldb, int ldc)
{
  __shared__ float As[16][68];
  __shared__ float Bs[16][68];
  const int bm = blockIdx.x * 64, bn = blockIdx.y * 64;
  const int tid = threadIdx.x;
  const int tx = tid & 15, ty = tid >> 4;
  float acc[4][4] = {};
  for (int k0 = 0; k0 < K; k0 += 16) {
#pragma unroll
    for (int i = 0; i < 4; i++) {
      int e = tid + i * 256;
      int m = e >> 4, k = e & 15;
      As[k][m] = (k0 + k < K) ? A[(size_t)(bm + m) * lda + k0 + k] : 0.f;
      Bs[k][m] = (k0 + k < K) ? Bm[(size_t)(bn + m) * ldb + k0 + k] : 0.f;
    }
    __syncthreads();
#pragma unroll
    for (int kk = 0; kk < 16; kk++) {
      float4 av = *(const float4*)&As[kk][ty * 4];
      float4 bv = *(const float4*)&Bs[kk][tx * 4];
      float a_[4] = {av.x, av.y, av.z, av.w};
      float b_[4] = {bv.x, bv.y, bv.z, bv.w};
#pragma unroll
      for (int i = 0; i < 4; i++)
#pragma unroll
        for (int j = 0; j < 4; j++)
          acc[i][j] = fmaf(a_[i], b_[j], acc[i][j]);
    }
    __syncthreads();
  }
#pragma unroll
  for (int i = 0; i < 4; i++) {
    int m = bm + ty * 4 + i;
#pragma unroll
    for (int j = 0; j < 4; j++) {
      int n = bn + tx * 4 + j;
      C[(size_t)m * ldc + n] = acc[i][j] + bias[n];
    }
  }
}

// ---------------------------------------------------------------------------
// BN partial sums: 64 blocks x 32 rows, coalesced, atomicAdd into s1/s2[512].
// ---------------------------------------------------------------------------
__global__ __launch_bounds__(256) void bn_partial(
    const float* __restrict__ h0, float* __restrict__ s1g,
    float* __restrict__ s2g)
{
  const int r0 = blockIdx.x * 32;
  const int tid = threadIdx.x;
  float a1 = 0.f, a2 = 0.f, b1 = 0.f, b2 = 0.f;
  for (int r = 0; r < 32; r++) {
    float v = h0[(size_t)(r0 + r) * ND + tid];
    float w = h0[(size_t)(r0 + r) * ND + tid + 256];
    a1 += v; a2 += v * v;
    b1 += w; b2 += w * w;
  }
  atomicAdd(&s1g[tid], a1);
  atomicAdd(&s2g[tid], a2);
  atomicAdd(&s1g[tid + 256], b1);
  atomicAdd(&s2g[tid + 256], b2);
}

// bn (stats from s1/s2) + leaky relu, writing fp16
__global__ void bn_lrelu_h16(const float* __restrict__ h0,
                             fpp g, fpp b,
                             const float* __restrict__ s1g,
                             const float* __restrict__ s2g,
                             __half* __restrict__ h16g)
{
  int idx = blockIdx.x * 256 + threadIdx.x;
  int d = idx & (ND - 1);
  float mu = s1g[d] * (1.f / NB);
  float var = s2g[d] * (1.f / NB) - mu * mu;
  float sc = g[d] * rsqrtf(var + 1e-5f);
  float sh = b[d] - mu * sc;
  float v = h0[idx] * sc + sh;
  h16g[idx] = __float2half(v >= 0.f ? v : 0.2f * v);
}

// ---------------------------------------------------------------------------
// One-time weight conversions fp32 -> fp16 (+ zero-padded jW 16x512)
// ---------------------------------------------------------------------------
__global__ void convert_w(fpp whf, fpp whb, fpp w1, fpp wif, fpp wib, fpp jw,
                          __half* __restrict__ o_whf, __half* __restrict__ o_whb,
                          __half* __restrict__ o_w1, __half* __restrict__ o_wif,
                          __half* __restrict__ o_wib, __half* __restrict__ o_jw)
{
  int idx = blockIdx.x * 256 + threadIdx.x;  // 0 .. 1318911
  if (idx < 196608) o_whf[idx] = __float2half(whf[idx]);
  else if (idx < 393216) o_whb[idx - 196608] = __float2half(whb[idx - 196608]);
  else if (idx < 524288) o_w1[idx - 393216] = __float2half(w1[idx - 393216]);
  else if (idx < 917504) o_wif[idx - 524288] = __float2half(wif[idx - 524288]);
  else if (idx < 1310720) o_wib[idx - 917504] = __float2half(wib[idx - 917504]);
  else if (idx < 1318912) {
    int e = idx - 1310720;           // 16 x 512, rows >= 6 zero
    o_jw[e] = (e < 6 * ND) ? __float2half(jw[e]) : __float2half(0.f);
  }
}

// ---------------------------------------------------------------------------
// fp16 MFMA GEMM, BOTH xg projections in one launch (grid.z selects dir).
// ---------------------------------------------------------------------------
__global__ __launch_bounds__(256) void gemm16_dual(
    const __half* __restrict__ A,
    const __half* __restrict__ B0, const __half* __restrict__ B1,
    fpp bias0, fpp bias1, float* __restrict__ C0, float* __restrict__ C1,
    int N, int K)
{
  const __half* __restrict__ Bm = blockIdx.z ? B1 : B0;
  fpp bias = blockIdx.z ? bias1 : bias0;
  float* __restrict__ C = blockIdx.z ? C1 : C0;

  __shared__ __half As[64 * 40];
  __shared__ __half Bs[64 * 40];
  const int bm = blockIdx.x * 64, bn = blockIdx.y * 64;
  const int tid = threadIdx.x;
  const int wave = tid >> 6, lane = tid & 63;
  const int lm = lane & 15, quad = lane >> 4;
  floatx4 acc[4];
#pragma unroll
  for (int nt = 0; nt < 4; nt++) acc[nt] = (floatx4){0.f, 0.f, 0.f, 0.f};

  const int row = tid >> 2, kc = tid & 3;
  for (int k0 = 0; k0 < K; k0 += 32) {
    __syncthreads();
    *(float4*)&As[row * 40 + kc * 8] =
      *(const float4*)&A[(size_t)(bm + row) * K + k0 + kc * 8];
    *(float4*)&Bs[row * 40 + kc * 8] =
      *(const float4*)&Bm[(size_t)(bn + row) * K + k0 + kc * 8];
    __syncthreads();
    half8 af = *(const half8*)&As[(wave * 16 + lm) * 40 + quad * 8];
#pragma unroll
    for (int nt = 0; nt < 4; nt++) {
      half8 bf = *(const half8*)&Bs[(nt * 16 + lm) * 40 + quad * 8];
      acc[nt] = __builtin_amdgcn_mfma_f32_16x16x32_f16(af, bf, acc[nt], 0, 0, 0);
    }
  }
#pragma unroll
  for (int nt = 0; nt < 4; nt++) {
    int n = bn + nt * 16 + lm;
    float bv = bias[n];
#pragma unroll
    for (int r = 0; r < 4; r++) {
      int m = bm + wave * 16 + quad * 4 + r;
      C[(size_t)m * N + n] = acc[nt][r] + bv;
    }
  }
}

// ---------------------------------------------------------------------------
// PERSISTENT GRU (unchanged from r15): 512 thr, weights pinned in registers,
// double-buffered LDS h-state, seq store hoisted a step.
// ---------------------------------------------------------------------------
__global__ __launch_bounds__(512, 2) void gru_persistent(
    const float* __restrict__ xg_f, const float* __restrict__ xg_b,
    const __half* __restrict__ whh16_f, const __half* __restrict__ whh16_b,
    fpp bhh_f, fpp bhh_b, __half* __restrict__ seq)
{
  const int dir  = blockIdx.x & 1;
  const int tile = blockIdx.x >> 1;
  const int bm   = tile * 16;
  const float* __restrict__ xg = dir ? xg_b : xg_f;
  const __half* __restrict__ Whh = dir ? whh16_b : whh16_f;
  fpp bhh = dir ? bhh_b : bhh_f;
  const int dcol = dir * NH;
  const int tid = threadIdx.x;
  const int wave = tid >> 6, lane = tid & 63;
  const int lm = lane & 15, quad = lane >> 4;
  const int n0 = wave * 32;

  __shared__ __half h16s[2][16 * 264];

  const __half* bp[3][2];
#pragma unroll
  for (int g = 0; g < 3; g++)
#pragma unroll
    for (int c = 0; c < 2; c++)
      bp[g][c] = Whh + (size_t)(g * NH + n0 + c * 16 + lm) * NH + quad * 8;

  floatx4 breg[3][2][6];
#pragma unroll
  for (int g = 0; g < 3; g++)
#pragma unroll
    for (int c = 0; c < 2; c++)
#pragma unroll
      for (int kb = 0; kb < 6; kb++)
        breg[g][c][kb] = *(const floatx4*)(bp[g][c] + kb * 32);
#pragma unroll
  for (int g = 0; g < 3; g++)
#pragma unroll
    for (int c = 0; c < 2; c++)
#pragma unroll
      for (int kb = 0; kb < 6; kb++)
        asm volatile("" : "+v"(breg[g][c][kb]));

  float xr_[2][4], xz_[2][4], xn_[2][4];
  float br_[2], bz_[2], bn_[2];
#pragma unroll
  for (int c = 0; c < 2; c++) {
    int n = n0 + c * 16 + lm;
    br_[c] = bhh[n]; bz_[c] = bhh[NH + n]; bn_[c] = bhh[2 * NH + n];
#pragma unroll
    for (int r = 0; r < 4; r++) {
      int m = bm + quad * 4 + r;
      const float* xp = xg + (size_t)m * NG + n;
      xr_[c][r] = xp[0];
      xz_[c][r] = xp[NH];
      xn_[c][r] = xp[2 * NH];
    }
  }

  float hp[2][4];
#pragma unroll
  for (int c = 0; c < 2; c++)
#pragma unroll
    for (int r = 0; r < 4; r++) hp[c][r] = 0.f;

  const int arow = lm * 264 + quad * 8;
  const int cm = tid >> 5, cpart = tid & 31;

  for (int step = 0; step < NT; step++) {
    const int cur = step & 1, prv = cur ^ 1;
    __half* __restrict__ hCur = h16s[cur];
    const __half* __restrict__ hPrv = h16s[prv];
    floatx4 acc[3][2];

    if (step > 0) {
      {
        const int t_prev = dir ? (NT - step) : (step - 1);
        float4 v = *(const float4*)&hPrv[cm * 264 + cpart * 8];
        *(float4*)&seq[((size_t)(bm + cm) * NT + t_prev) * ND + dcol + cpart * 8] = v;
      }
      half8 b6[3][2], b7[3][2];
#pragma unroll
      for (int g = 0; g < 3; g++)
#pragma unroll
        for (int c = 0; c < 2; c++) {
          b6[g][c] = *(const half8*)(bp[g][c] + 192);
          b7[g][c] = *(const half8*)(bp[g][c] + 224);
        }
      {
        half8 a = *(const half8*)&hPrv[arow];
#pragma unroll
        for (int g = 0; g < 3; g++)
#pragma unroll
          for (int c = 0; c < 2; c++)
            acc[g][c] = __builtin_amdgcn_mfma_f32_16x16x32_f16(
                a, __builtin_bit_cast(half8, breg[g][c][0]),
                (floatx4){0.f, 0.f, 0.f, 0.f}, 0, 0, 0);
      }
#pragma unroll
      for (int kb = 1; kb < 6; kb++) {
        half8 a = *(const half8*)&hPrv[arow + kb * 32];
#pragma unroll
        for (int g = 0; g < 3; g++)
#pragma unroll
          for (int c = 0; c < 2; c++)
            acc[g][c] = __builtin_amdgcn_mfma_f32_16x16x32_f16(
                a, __builtin_bit_cast(half8, breg[g][c][kb]), acc[g][c], 0, 0, 0);
      }
      {
        half8 a = *(const half8*)&hPrv[arow + 192];
#pragma unroll
        for (int g = 0; g < 3; g++)
#pragma unroll
          for (int c = 0; c < 2; c++)
            acc[g][c] = __builtin_amdgcn_mfma_f32_16x16x32_f16(a, b6[g][c], acc[g][c], 0, 0, 0);
      }
      {
        half8 a = *(const half8*)&hPrv[arow + 224];
#pragma unroll
        for (int g = 0; g < 3; g++)
#pragma unroll
          for (int c = 0; c < 2; c++)
            acc[g][c] = __builtin_amdgcn_mfma_f32_16x16x32_f16(a, b7[g][c], acc[g][c], 0, 0, 0);
      }
    } else {
#pragma unroll
      for (int g = 0; g < 3; g++)
#pragma unroll
        for (int c = 0; c < 2; c++) acc[g][c] = (floatx4){0.f, 0.f, 0.f, 0.f};
    }

#pragma unroll
    for (int c = 0; c < 2; c++) {
      int n = n0 + c * 16 + lm;
#pragma unroll
      for (int r = 0; r < 4; r++) {
        int m = quad * 4 + r;
        float rg = fast_sig(xr_[c][r] + acc[0][c][r] + br_[c]);
        float zg = fast_sig(xz_[c][r] + acc[1][c][r] + bz_[c]);
        float nn = fast_tanh(xn_[c][r] + rg * (acc[2][c][r] + bn_[c]));
        float hv = (1.f - zg) * nn + zg * hp[c][r];
        hp[c][r] = hv;
        hCur[m * 264 + n] = __float2half(hv);
      }
    }
    __syncthreads();
  }

  {
    const int t_last = dir ? 0 : (NT - 1);
    const __half* hLast = h16s[(NT - 1) & 1];
    float4 v = *(const float4*)&hLast[cm * 264 + cpart * 8];
    *(float4*)&seq[((size_t)(bm + cm) * NT + t_last) * ND + dcol + cpart * 8] = v;
  }
}

// ---------------------------------------------------------------------------
// Attention scores + gJ via MFMA, M=128/block, 2x2 wave partition:
// wave = (m-half, n-half). Per wave/k0: 4 a-frags + 8 b-frags -> 32 MFMAs
// (LDS-pipe balanced vs r15's 19 reads / 34 MFMAs x4-wave duplication).
// Cross-wave N reduction via LDS partials. nh==1 waves carry the gJ tile.
// ---------------------------------------------------------------------------
__global__ __launch_bounds__(256) void attn_score_mfma(
    const __half* __restrict__ seq, const __half* __restrict__ w116,
    const __half* __restrict__ jw16, fpp b1, fpp W2,
    float* __restrict__ scores, float* __restrict__ gJ)
{
  const int bm = blockIdx.x * 128;
  const int tid = threadIdx.x;
  const int wave = tid >> 6, lane = tid & 63;
  const int lm = lane & 15, quad = lane >> 4;
  const int mh = wave & 1;       // rows mh*64 .. mh*64+63
  const int nh = wave >> 1;      // nt nh*8 .. nh*8+7

  __shared__ __half As[128 * 40];
  __shared__ __half Bs[256 * 40];
  __shared__ __half Js[16 * 40];
  __shared__ float partial[2][128];

  floatx4 acc[4][8];
  floatx4 accJ[4];
#pragma unroll
  for (int t = 0; t < 4; t++) {
#pragma unroll
    for (int u = 0; u < 8; u++) acc[t][u] = (floatx4){0.f, 0.f, 0.f, 0.f};
    accJ[t] = (floatx4){0.f, 0.f, 0.f, 0.f};
  }

  for (int k0 = 0; k0 < ND; k0 += 32) {
    __syncthreads();
#pragma unroll
    for (int i = 0; i < 2; i++) {
      int e = tid + i * 256;
      int row = e >> 2, kc = e & 3;
      *(float4*)&As[row * 40 + kc * 8] =
        *(const float4*)&seq[(size_t)(bm + row) * ND + k0 + kc * 8];
    }
#pragma unroll
    for (int i = 0; i < 4; i++) {
      int e = tid + i * 256;
      int row = e >> 2, kc = e & 3;
      *(float4*)&Bs[row * 40 + kc * 8] =
        *(const float4*)&w116[(size_t)row * ND + k0 + kc * 8];
    }
    if (tid < 64) {
      int row = tid >> 2, kc = tid & 3;
      *(float4*)&Js[row * 40 + kc * 8] =
        *(const float4*)&jw16[(size_t)row * ND + k0 + kc * 8];
    }
    __syncthreads();
    half8 a[4];
#pragma unroll
    for (int t = 0; t < 4; t++)
      a[t] = *(const half8*)&As[((mh * 4 + t) * 16 + lm) * 40 + quad * 8];
#pragma unroll
    for (int u = 0; u < 8; u++) {
      half8 bf = *(const half8*)&Bs[((nh * 8 + u) * 16 + lm) * 40 + quad * 8];
#pragma unroll
      for (int t = 0; t < 4; t++)
        acc[t][u] = __builtin_amdgcn_mfma_f32_16x16x32_f16(a[t], bf, acc[t][u], 0, 0, 0);
    }
    if (nh == 1) {
      half8 bj = *(const half8*)&Js[lm * 40 + quad * 8];
#pragma unroll
      for (int t = 0; t < 4; t++)
        accJ[t] = __builtin_amdgcn_mfma_f32_16x16x32_f16(a[t], bj, accJ[t], 0, 0, 0);
    }
  }

  float rs[4][4] = {};
#pragma unroll
  for (int u = 0; u < 8; u++) {
    int n = (nh * 8 + u) * 16 + lm;
    float b1v = b1[n], w2v = W2[n];
#pragma unroll
    for (int t = 0; t < 4; t++)
#pragma unroll
      for (int r = 0; r < 4; r++)
        rs[t][r] += fast_tanh(acc[t][u][r] + b1v) * w2v;
  }
#pragma unroll
  for (int t = 0; t < 4; t++)
#pragma unroll
    for (int r = 0; r < 4; r++) {
      rs[t][r] += __shfl_xor(rs[t][r], 1);
      rs[t][r] += __shfl_xor(rs[t][r], 2);
      rs[t][r] += __shfl_xor(rs[t][r], 4);
      rs[t][r] += __shfl_xor(rs[t][r], 8);
    }
  if (lm == 0) {
#pragma unroll
    for (int t = 0; t < 4; t++)
#pragma unroll
      for (int r = 0; r < 4; r++)
        partial[nh][mh * 64 + t * 16 + quad * 4 + r] = rs[t][r];
  }
  if (nh == 1) {
#pragma unroll
    for (int t = 0; t < 4; t++)
#pragma unroll
      for (int r = 0; r < 4; r++) {
        int row = bm + mh * 64 + t * 16 + quad * 4 + r;
        gJ[(size_t)row * 16 + lm] = accJ[t][r];
      }
  }
  __syncthreads();
  if (tid < 128) scores[bm + tid] = partial[0][tid] + partial[1][tid];
}

// ---------------------------------------------------------------------------
// FUSED softmax + cJ + scalar FK. One wave per batch row b.
// ---------------------------------------------------------------------------
__constant__ float c_lower[6] = {-3.1416f, -1.5708f, -3.1416f, -2.6f, -1.5708f, -1.2f};
__constant__ float c_upper[6] = { 3.1416f,  1.5708f,  3.1416f,  0.1f,  1.5708f,  1.2f};

__global__ __launch_bounds__(64) void attn_post(
    const float* __restrict__ scores_in, const float* __restrict__ gJ,
    fpp jb, float* __restrict__ out)
{
  const int b = blockIdx.x;
  const int t = threadIdx.x;    // 64 lanes, lanes 0..59 active for FK

  // --- softmax over time (wave-wide) ---
  float v = (t < NT) ? scores_in[(size_t)b * NT + t] : -1e30f;
  float m = v;
#pragma unroll
  for (int off = 32; off >= 1; off >>= 1) m = fmaxf(m, __shfl_xor(m, off));
  float e = (t < NT) ? __expf(v - m) : 0.f;
  float sum = e;
#pragma unroll
  for (int off = 32; off >= 1; off >>= 1) sum += __shfl_xor(sum, off);
  float w = e * fast_rcp(sum);

  // --- stage gJ[b] (60x16) + weights into LDS ---
  __shared__ float gj[NT * 16];
  __shared__ float wl[64];
  __shared__ float cj[16];
  wl[t] = w;
  const float* gsrc = gJ + (size_t)b * NT * 16;
#pragma unroll
  for (int i = 0; i < 15; i++) gj[t + i * 64] = gsrc[t + i * 64];
  __syncthreads();

  // --- cJ[j] = sum_t w[t]*gJ[t][j] ---
  if (t < 16) {
    float s = 0.f;
    for (int tt = 0; tt < NT; tt++) s += wl[tt] * gj[tt * 16 + t];
    cj[t] = s;
  }
  __syncthreads();

  if (t >= NT) return;

  float th[6];
#pragma unroll
  for (int j = 0; j < 6; j++) {
    float jnt = gj[t * 16 + j] + cj[j] + jb[j];
    th[j] = jnt * (c_upper[j] - c_lower[j]) + c_lower[j];
  }

  float c0x = 1.f, c0y = 0.f, c0z = 0.f;
  float c1x = 0.f, c1y = 1.f, c1z = 0.f;
  float c2x = 0.f, c2y = 0.f, c2z = 1.f;
  float px = 0.f, py = 0.f, pz = 0.1f;
  float s, cc, tx_, ty_, tz_, ux_, uy_, uz_;

  // rotZ(th0)
  s = sinf(th[0]); cc = cosf(th[0]);
  tx_ = cc * c0x + s * c1x; ty_ = cc * c0y + s * c1y; tz_ = cc * c0z + s * c1z;
  ux_ = -s * c0x + cc * c1x; uy_ = -s * c0y + cc * c1y; uz_ = -s * c0z + cc * c1z;
  c0x = tx_; c0y = ty_; c0z = tz_; c1x = ux_; c1y = uy_; c1z = uz_;

  float shx = px, shy = py, shz = pz;  // shoulder2
  // rotX(th1)
  s = sinf(th[1]); cc = cosf(th[1]);
  tx_ = cc * c1x + s * c2x; ty_ = cc * c1y + s * c2y; tz_ = cc * c1z + s * c2z;
  ux_ = -s * c1x + cc * c2x; uy_ = -s * c1y + cc * c2y; uz_ = -s * c1z + cc * c2z;
  c1x = tx_; c1y = ty_; c1z = tz_; c2x = ux_; c2y = uy_; c2z = uz_;

  // rotY(th2)
  s = sinf(th[2]); cc = cosf(th[2]);
  tx_ = cc * c0x - s * c2x; ty_ = cc * c0y - s * c2y; tz_ = cc * c0z - s * c2z;
  ux_ = s * c0x + cc * c2x; uy_ = s * c0y + cc * c2y; uz_ = s * c0z + cc * c2z;
  c0x = tx_; c0y = ty_; c0z = tz_; c2x = ux_; c2y = uy_; c2z = uz_;

  // joint3 offset -> forearm
  px -= 0.25f * c1x; py -= 0.25f * c1y; pz -= 0.25f * c1z;
  float fox = px, foy = py, foz = pz;
  // rotX(th3)
  s = sinf(th[3]); cc = cosf(th[3]);
  tx_ = cc * c1x + s * c2x; ty_ = cc * c1y + s * c2y; tz_ = cc * c1z + s * c2z;
  ux_ = -s * c1x + cc * c2x; uy_ = -s * c1y + cc * c2y; uz_ = -s * c1z + cc * c2z;
  c1x = tx_; c1y = ty_; c1z = tz_; c2x = ux_; c2y = uy_; c2z = uz_;

  // rotY(th4)
  s = sinf(th[4]); cc = cosf(th[4]);
  tx_ = cc * c0x - s * c2x; ty_ = cc * c0y - s * c2y; tz_ = cc * c0z - s * c2z;
  ux_ = s * c0x + cc * c2x; uy_ = s * c0y + cc * c2y; uz_ = s * c0z + cc * c2z;
  c0x = tx_; c0y = ty_; c0z = tz_; c2x = ux_; c2y = uy_; c2z = uz_;

  // joint5 offset -> wrist
  px -= 0.25f * c1x; py -= 0.25f * c1y; pz -= 0.25f * c1z;
  float wx = px, wy = py, wz = pz;
  // rotX(th5)
  s = sinf(th[5]); cc = cosf(th[5]);
  tx_ = cc * c1x + s * c2x; ty_ = cc * c1y + s * c2y; tz_ = cc * c1z + s * c2z;
  ux_ = -s * c1x + cc * c2x; uy_ = -s * c1y + cc * c2y; uz_ = -s * c1z + cc * c2z;
  c1x = tx_; c1y = ty_; c1z = tz_; c2x = ux_; c2y = uy_; c2z = uz_;

  float f1x = wx - 0.08f * c1x + 0.02f * c2x;
  float f1y = wy - 0.08f * c1y + 0.02f * c2y;
  float f1z = wz - 0.08f * c1z + 0.02f * c2z;
  float f4x = wx - 0.08f * c1x - 0.02f * c2x;
  float f4y = wy - 0.08f * c1y - 0.02f * c2y;
  float f4z = wz - 0.08f * c1z - 0.02f * c2z;

  float dsx = shx - fox, dsy = shy - foy, dsz = shz - foz;
  float dwx = wx - fox, dwy = wy - foy, dwz = wz - foz;
  float bodyL = 0.5f * (sqrtf(dsx * dsx + dsy * dsy + dsz * dsz) +
                        sqrtf(dwx * dwx + dwy * dwy + dwz * dwz));
  float inv = fast_rcp(bodyL);

  float* o = out + ((size_t)b * NT + t) * 9;
  o[0] = (wx - shx) * inv; o[1] = (wy - shy) * inv; o[2] = (wz - shz) * inv;
  o[3] = (f1x - shx) * inv; o[4] = (f1y - shy) * inv; o[5] = (f1z - shz) * inv;
  o[6] = (f4x - shx) * inv; o[7] = (f4y - shy) * inv; o[8] = (f4z - shz) * inv;
}

// ---------------------------------------------------------------------------
extern "C" void kernel_launch(void* const* d_in, const int* in_sizes, int n_in,
                              void* d_out, int out_size, void* d_ws, size_t ws_size,
                              hipStream_t stream)
{
  fpp z     = (fpp)d_in[0];
  fpp W_fc  = (fpp)d_in[1];
  fpp b_fc  = (fpp)d_in[2];
  fpp bn_g  = (fpp)d_in[3];
  fpp bn_b  = (fpp)d_in[4];
  fpp Wih_f = (fpp)d_in[5];
  fpp Whh_f = (fpp)d_in[6];
  fpp bih_f = (fpp)d_in[7];
  fpp bhh_f = (fpp)d_in[8];
  fpp Wih_b = (fpp)d_in[9];
  fpp Whh_b = (fpp)d_in[10];
  fpp bih_b = (fpp)d_in[11];
  fpp bhh_b = (fpp)d_in[12];
  fpp aW1   = (fpp)d_in[13];
  fpp ab1   = (fpp)d_in[14];
  fpp aW2   = (fpp)d_in[15];
  fpp jW    = (fpp)d_in[16];
  fpp jb    = (fpp)d_in[17];

  float* ws     = (float*)d_ws;
  float* h0     = ws;                        // 2048*512 fp32
  float* xg_f   = h0 + 1048576;              // 2048*768 fp32
  float* xg_b   = xg_f + 1572864;            // 2048*768 fp32
  float* bns1   = xg_b + 1572864;            // 512
  float* bns2   = bns1 + 512;                // 512
  float* scores = bns2 + 512;                // 2048*60
  float* cbuf   = scores + 122880;           // 2048*512 (layout keep)
  __half* gseq    = (__half*)(cbuf + 1048576);   // 2048*60*512 fp16 (126 MB)
  __half* whh16_f = gseq + 62914560;             // 768*256
  __half* whh16_b = whh16_f + 196608;            // 768*256
  __half* w116    = whh16_b + 196608;            // 256*512
  __half* wih16_f = w116 + 131072;               // 768*512
  __half* wih16_b = wih16_f + 393216;            // 768*512
  __half* h16g    = wih16_b + 393216;            // 2048*512
  __half* jw16    = h16g + 1048576;              // 16*512
  float*  gJ      = (float*)(jw16 + 8192);       // 122880*16 fp32 (7.9 MB)

  // 0. weight conversions fp32->fp16 (incl. zero-padded jW) + BN acc zero
  convert_w<<<5152, 256, 0, stream>>>(Whh_f, Whh_b, aW1, Wih_f, Wih_b, jW,
                                      whh16_f, whh16_b, w116, wih16_f, wih16_b,
                                      jw16);
  hipMemsetAsync(bns1, 0, 1024 * sizeof(float), stream);
  // 1. fc: h0 = z @ W_fc^T + b_fc (fp32, K=100)
  gemm_fc<<<dim3(32, 8), 256, 0, stream>>>(z, W_fc, b_fc, h0,
                                           NB, ND, NDL, NDL, NDL, ND);
  // 2. batchnorm (training stats, parallel partials) + leaky relu -> fp16 h
  bn_partial<<<64, 256, 0, stream>>>(h0, bns1, bns2);
  bn_lrelu_h16<<<4096, 256, 0, stream>>>(h0, bn_g, bn_b, bns1, bns2, h16g);
  // 3. BOTH time-invariant input projections in one launch
  gemm16_dual<<<dim3(32, 12, 2), 256, 0, stream>>>(
      h16g, wih16_f, wih16_b, bih_f, bih_b, xg_f, xg_b, NG, ND);
  // 4. ENTIRE GRU recurrence: one persistent launch, 8 waves/block
  gru_persistent<<<256, 512, 0, stream>>>(xg_f, xg_b, whh16_f, whh16_b,
                                          bhh_f, bhh_b, gseq);
  // 5. attention scores + gJ (2x2 wave-partitioned MFMA)
  attn_score_mfma<<<960, 256, 0, stream>>>(gseq, w116, jw16, ab1, aW2,
                                           scores, gJ);
  // 6. fused softmax + cJ + FK
  attn_post<<<NB, 64, 0, stream>>>(scores, gJ, jb, (float*)d_out);
}